// Round 9
// baseline (198.926 us; speedup 1.0000x reference)
//
#include <hip/hip_runtime.h>
#include <hip/hip_cooperative_groups.h>
#include <math.h>

namespace cg = cooperative_groups;

#define NSAMP 32768
#define FS_F 44100.0f
#define PI_F 3.14159265358979323846f
#define T1 1024  // KS slice length (32 slices/batch)
#define T2 4096  // body slice length (8 slices/batch)

struct BParams {
  float alpha, alpha_p;
  float fr, g, s;
  int Di;
  float lc, lm, lp;
};

__device__ inline float sigmoidf_(float x) { return 1.0f / (1.0f + expf(-x)); }

__device__ inline BParams compute_params(int b, const float* __restrict__ pitch,
                                         const float* __restrict__ w1,
                                         const float* __restrict__ b1,
                                         const float* __restrict__ w2,
                                         const float* __restrict__ b2) {
  BParams P;
  float p = pitch[b];
  float h[16];
#pragma unroll
  for (int i = 0; i < 16; ++i) {
    float v = fmaf(p, w1[i], b1[i]);
    h[i] = v > 0.0f ? v : 0.0f;
  }
  float m[3];
#pragma unroll
  for (int j = 0; j < 3; ++j) {
    float acc = b2[j];
#pragma unroll
    for (int i = 0; i < 16; ++i) acc = fmaf(h[i], w2[j * 16 + i], acc);
    m[j] = acc;
  }
  P.lc = fminf(fmaxf(m[0], -2.0f), 2.5f);
  P.lm = fminf(fmaxf(m[1], -2.5f), 0.0f);
  P.lp = fminf(fmaxf(m[2], -4.0f), 4.0f);
  P.g = 0.999f * sigmoidf_(P.lc);
  P.s = sigmoidf_(P.lm);
  float f0 = fmaxf(p, 60.0f);
  float D = fminf(fmaxf(FS_F / f0, 2.0f), 735.0f);
  int Di = (int)floorf(D);
  P.fr = D - (float)Di;
  P.Di = Di;
  float mult = fminf(fmaxf(2.0f + 6.0f * (f0 - 60.0f) / 600.0f, 2.0f), 8.0f);
  float cutoff = fminf(2.0f * PI_F * f0 * mult / FS_F, PI_F * 0.9f);
  P.alpha = 1.0f - expf(-cutoff);
  float cpost = fminf(PI_F * sigmoidf_(P.lp), PI_F * 0.99f);
  P.alpha_p = 1.0f - expf(-cpost);
  return P;
}

// lane helpers (wave64)
__device__ inline float rl63(float v) {
  return __int_as_float(__builtin_amdgcn_readlane(__float_as_int(v), 63));
}
__device__ inline float rlv(float v, int l) {
  return __int_as_float(__builtin_amdgcn_readlane(__float_as_int(v), l));
}
__device__ inline float shr1(float v, float bnd) {
  return __int_as_float(__builtin_amdgcn_update_dpp(
      __float_as_int(bnd), __float_as_int(v), 0x138 /*wave_shr:1*/, 0xf, 0xf,
      false));
}

// Block barrier draining ONLY lgkmcnt (keeps global stores in flight).
__device__ inline void barrier_lgkm() {
  asm volatile("s_waitcnt lgkmcnt(0)\n\ts_barrier" ::: "memory");
}

__device__ inline void band_coef(int k, float& a1, float& a2, float& b0) {
  float fc = 80.0f * exp2f((float)k * (6.64385618977472436f / 23.0f));
  float w = 2.0f * PI_F * fc / FS_F;
  float r = expf(-PI_F * fc / (10.0f * FS_F));
  a1 = -2.0f * r * cosf(w);
  a2 = r * r;
  b0 = 1.0f - r;
}

// Exact one-pole IIR over full NSAMP (fallback path k0).
__device__ inline void lpc_scan2(const float* __restrict__ in,
                                 float* __restrict__ out, float scale, float c,
                                 int t, float* lws) {
  const int lane = t & 63, wid = t >> 6;
  float c2v = c * c, c4 = c2v * c2v, c8 = c4 * c4;
  float m1 = c8, m2 = m1 * m1, m4 = m2 * m2, m8 = m4 * m4, m16 = m8 * m8,
        m32 = m16 * m16;
  float c512 = m32 * m32;
  float c2048 = c512 * c512;
  c2048 *= c2048;
  float l2c = log2f(c);
  float c8lane = exp2f((float)(8 * lane) * l2c);
  float cgk = exp2f((float)(8 * t) * l2c);
  float vrun = 0.0f;
  const float4* in4 = (const float4*)in;
  float4* out4 = (float4*)out;
  for (int tile = 0; tile < 16; ++tile) {
    __syncthreads();
    float4 xa = in4[(tile << 9) + 2 * t];
    float4 xb = in4[(tile << 9) + 2 * t + 1];
    float S = 0.0f;
    S = fmaf(c, S, scale * xa.x); S = fmaf(c, S, scale * xa.y);
    S = fmaf(c, S, scale * xa.z); S = fmaf(c, S, scale * xa.w);
    S = fmaf(c, S, scale * xb.x); S = fmaf(c, S, scale * xb.y);
    S = fmaf(c, S, scale * xb.z); S = fmaf(c, S, scale * xb.w);
    float Sw = S, u;
    u = __shfl_up(Sw, 1);  if (lane >= 1)  Sw = fmaf(m1, u, Sw);
    u = __shfl_up(Sw, 2);  if (lane >= 2)  Sw = fmaf(m2, u, Sw);
    u = __shfl_up(Sw, 4);  if (lane >= 4)  Sw = fmaf(m4, u, Sw);
    u = __shfl_up(Sw, 8);  if (lane >= 8)  Sw = fmaf(m8, u, Sw);
    u = __shfl_up(Sw, 16); if (lane >= 16) Sw = fmaf(m16, u, Sw);
    u = __shfl_up(Sw, 32); if (lane >= 32) Sw = fmaf(m32, u, Sw);
    if (lane == 63) lws[wid] = Sw;
    __syncthreads();
    float a0 = lws[0], a1w = lws[1], a2w = lws[2], a3w = lws[3];
    float carry = (wid == 1)   ? a0
                  : (wid == 2) ? fmaf(c512, a0, a1w)
                  : (wid == 3) ? fmaf(c512, fmaf(c512, a0, a1w), a2w)
                               : 0.0f;
    float Sprev = __shfl_up(Sw, 1);
    float Sex = (lane == 0) ? 0.0f : Sprev;
    Sex = fmaf(c8lane, carry, Sex);
    float v = fmaf(cgk, vrun, Sex);
    float4 ya, yb;
    v = fmaf(c, v, scale * xa.x); ya.x = v;
    v = fmaf(c, v, scale * xa.y); ya.y = v;
    v = fmaf(c, v, scale * xa.z); ya.z = v;
    v = fmaf(c, v, scale * xa.w); ya.w = v;
    v = fmaf(c, v, scale * xb.x); yb.x = v;
    v = fmaf(c, v, scale * xb.y); yb.y = v;
    v = fmaf(c, v, scale * xb.z); yb.z = v;
    v = fmaf(c, v, scale * xb.w); yb.w = v;
    out4[(tile << 9) + 2 * t] = ya;
    out4[(tile << 9) + 2 * t + 1] = yb;
    float tS = fmaf(c512, fmaf(c512, fmaf(c512, a0, a1w), a2w), a3w);
    vrun = fmaf(c2048, vrun, tS);
  }
}

// Slice-parallel one-pole: write out[o0, o0+1024) using zero-state start at
// s0 = max(0, o0-640). One 2048-tile, 256 threads. Error <= c^640 ~ 2e-5.
__device__ inline void prelp_slice(const float* __restrict__ xg,
                                   float* __restrict__ yg, int o0, float scale,
                                   float c, int t, float* lws) {
  const int lane = t & 63, wid = t >> 6;
  int s0 = o0 - 640;
  if (s0 < 0) s0 = 0;
  float c2v = c * c, c4 = c2v * c2v, c8 = c4 * c4;
  float m1 = c8, m2 = m1 * m1, m4 = m2 * m2, m8 = m4 * m4, m16 = m8 * m8,
        m32 = m16 * m16;
  float c512 = m32 * m32;
  float l2c = log2f(c);
  float c8lane = exp2f((float)(8 * lane) * l2c);
  const int g0 = s0 + 8 * t;
  float4 xa = make_float4(0.f, 0.f, 0.f, 0.f);
  float4 xb = make_float4(0.f, 0.f, 0.f, 0.f);
  if (g0 + 3 < NSAMP) xa = *(const float4*)&xg[g0];
  if (g0 + 7 < NSAMP) xb = *(const float4*)&xg[g0 + 4];
  float S = 0.0f;
  S = fmaf(c, S, scale * xa.x); S = fmaf(c, S, scale * xa.y);
  S = fmaf(c, S, scale * xa.z); S = fmaf(c, S, scale * xa.w);
  S = fmaf(c, S, scale * xb.x); S = fmaf(c, S, scale * xb.y);
  S = fmaf(c, S, scale * xb.z); S = fmaf(c, S, scale * xb.w);
  float Sw = S, u;
  u = __shfl_up(Sw, 1);  if (lane >= 1)  Sw = fmaf(m1, u, Sw);
  u = __shfl_up(Sw, 2);  if (lane >= 2)  Sw = fmaf(m2, u, Sw);
  u = __shfl_up(Sw, 4);  if (lane >= 4)  Sw = fmaf(m4, u, Sw);
  u = __shfl_up(Sw, 8);  if (lane >= 8)  Sw = fmaf(m8, u, Sw);
  u = __shfl_up(Sw, 16); if (lane >= 16) Sw = fmaf(m16, u, Sw);
  u = __shfl_up(Sw, 32); if (lane >= 32) Sw = fmaf(m32, u, Sw);
  if (lane == 63) lws[wid] = Sw;
  __syncthreads();
  float a0 = lws[0], a1w = lws[1], a2w = lws[2];
  float carry = (wid == 1)   ? a0
                : (wid == 2) ? fmaf(c512, a0, a1w)
                : (wid == 3) ? fmaf(c512, fmaf(c512, a0, a1w), a2w)
                             : 0.0f;
  float Sprev = __shfl_up(Sw, 1);
  float v = (lane == 0) ? 0.0f : Sprev;
  v = fmaf(c8lane, carry, v);
  const int hi = o0 + 1024;
#pragma unroll
  for (int e = 0; e < 4; ++e) {
    float xi = e == 0 ? xa.x : e == 1 ? xa.y : e == 2 ? xa.z : xa.w;
    v = fmaf(c, v, scale * xi);
    int n = g0 + e;
    if (n >= o0 && n < hi) yg[n] = v;
  }
#pragma unroll
  for (int e = 0; e < 4; ++e) {
    float xi = e == 0 ? xb.x : e == 1 ? xb.y : e == 2 ? xb.z : xb.w;
    v = fmaf(c, v, scale * xi);
    int n = g0 + 4 + e;
    if (n >= o0 && n < hi) yg[n] = v;
  }
}

// One-pole scan over [s2, s2+nt*2048) from global into LDS sl[n-s2].
__device__ inline void lpc_lds(const float* __restrict__ xg,
                               float* __restrict__ sl, int s2, int nt,
                               float scale, float c, int t, float* lws) {
  const int lane = t & 63, wid = t >> 6;
  float c2v = c * c, c4 = c2v * c2v, c8 = c4 * c4;
  float m1 = c8, m2 = m1 * m1, m4 = m2 * m2, m8 = m4 * m4, m16 = m8 * m8,
        m32 = m16 * m16;
  float c512 = m32 * m32;
  float c2048 = c512 * c512;
  c2048 *= c2048;
  float l2c = log2f(c);
  float c8lane = exp2f((float)(8 * lane) * l2c);
  float cgk = exp2f((float)(8 * t) * l2c);
  float vrun = 0.0f;
  for (int tile = 0; tile < nt; ++tile) {
    __syncthreads();
    int g0 = s2 + (tile << 11) + 8 * t;
    float4 xa = make_float4(0.f, 0.f, 0.f, 0.f);
    float4 xb = make_float4(0.f, 0.f, 0.f, 0.f);
    if (g0 + 3 < NSAMP) xa = *(const float4*)&xg[g0];
    if (g0 + 7 < NSAMP) xb = *(const float4*)&xg[g0 + 4];
    float S = 0.0f;
    S = fmaf(c, S, scale * xa.x); S = fmaf(c, S, scale * xa.y);
    S = fmaf(c, S, scale * xa.z); S = fmaf(c, S, scale * xa.w);
    S = fmaf(c, S, scale * xb.x); S = fmaf(c, S, scale * xb.y);
    S = fmaf(c, S, scale * xb.z); S = fmaf(c, S, scale * xb.w);
    float Sw = S, u;
    u = __shfl_up(Sw, 1);  if (lane >= 1)  Sw = fmaf(m1, u, Sw);
    u = __shfl_up(Sw, 2);  if (lane >= 2)  Sw = fmaf(m2, u, Sw);
    u = __shfl_up(Sw, 4);  if (lane >= 4)  Sw = fmaf(m4, u, Sw);
    u = __shfl_up(Sw, 8);  if (lane >= 8)  Sw = fmaf(m8, u, Sw);
    u = __shfl_up(Sw, 16); if (lane >= 16) Sw = fmaf(m16, u, Sw);
    u = __shfl_up(Sw, 32); if (lane >= 32) Sw = fmaf(m32, u, Sw);
    if (lane == 63) lws[wid] = Sw;
    __syncthreads();
    float a0 = lws[0], a1w = lws[1], a2w = lws[2], a3w = lws[3];
    float carry = (wid == 1)   ? a0
                  : (wid == 2) ? fmaf(c512, a0, a1w)
                  : (wid == 3) ? fmaf(c512, fmaf(c512, a0, a1w), a2w)
                               : 0.0f;
    float Sprev = __shfl_up(Sw, 1);
    float Sex = (lane == 0) ? 0.0f : Sprev;
    Sex = fmaf(c8lane, carry, Sex);
    float v = fmaf(cgk, vrun, Sex);
    int o = g0 - s2;
    float4 ya, yb;
    v = fmaf(c, v, scale * xa.x); ya.x = v;
    v = fmaf(c, v, scale * xa.y); ya.y = v;
    v = fmaf(c, v, scale * xa.z); ya.z = v;
    v = fmaf(c, v, scale * xa.w); ya.w = v;
    v = fmaf(c, v, scale * xb.x); yb.x = v;
    v = fmaf(c, v, scale * xb.y); yb.y = v;
    v = fmaf(c, v, scale * xb.z); yb.z = v;
    v = fmaf(c, v, scale * xb.w); yb.w = v;
    *(float4*)&sl[o] = ya;
    *(float4*)&sl[o + 4] = yb;
    float tS = fmaf(c512, fmaf(c512, fmaf(c512, a0, a1w), a2w), a3w);
    vrun = fmaf(c2048, vrun, tS);
  }
}

// KS slice compute (R7, proven).
template <int KNUM>
__device__ void ks_slice2(const float* __restrict__ xg, float* __restrict__ yg,
                          float* xbuf, float* bnd, int t, int C, float c0w,
                          float c1w, float c2w, int s1, int n0, int end,
                          int span, int nseg) {
  const int lane = t & 63;
  const int wid = t >> 6;
  const int lq1 = (C - 1) - (KNUM - 1) * 64;

  if (KNUM <= 3) {
    float yp[KNUM], xC[KNUM], xN[KNUM];
    float p1 = 0.f, p2 = 0.f;
    int rel = 0;
#pragma unroll
    for (int k = 0; k < KNUM; ++k) { yp[k] = 0.f; xC[k] = 0.f; xN[k] = 0.f; }
    for (int s = 0; s < nseg; ++s) {
      barrier_lgkm();
      if (wid == 0) {
        if (s == 0) {
#pragma unroll
          for (int k = 0; k < KNUM; ++k) {
            int i = lane + (k << 6);
            xC[k] = xbuf[i];
            xN[k] = xbuf[C + i];
          }
        }
        int fence = (s + 1) << 11;
        if (fence > span) fence = span;
        while (rel < fence) {
          float b2v[KNUM], b3v[KNUM];
#pragma unroll
          for (int k = 0; k < KNUM; ++k)
            b2v[k] = shr1(yp[k], (k == 0) ? p1 : rl63(yp[k - 1]));
#pragma unroll
          for (int k = 0; k < KNUM; ++k)
            b3v[k] = shr1(b2v[k], (k == 0) ? p2 : rlv(yp[k - 1], 62));
          float p1n = rlv(yp[KNUM - 1], lq1);
          float p2n = rlv(b2v[KNUM - 1], lq1);
#pragma unroll
          for (int k = 0; k < KNUM; ++k)
            yp[k] = fmaf(c0w, yp[k],
                         fmaf(c2w, b3v[k], fmaf(c1w, b2v[k], xC[k])));
          p1 = p1n;
          p2 = p2n;
#pragma unroll
          for (int k = 0; k < KNUM; ++k) {
            int i = lane + (k << 6);
            int n = s1 + rel + i;
            bool okl = (k < KNUM - 1) || (lane <= lq1);
            if (okl && n >= n0 && n < end) yg[n] = yp[k];
          }
#pragma unroll
          for (int k = 0; k < KNUM; ++k) {
            xC[k] = xN[k];
            xN[k] = xbuf[(rel + 2 * C + lane + (k << 6)) & 8191];
          }
          rel += C;
        }
      }
      barrier_lgkm();
      int ls = s + 3;
      if (ls < nseg) {
        int j = (ls << 11) + 8 * t;
        float4 a = *(const float4*)&xg[j];
        float4 c4 = *(const float4*)&xg[j + 4];
        *(float4*)&xbuf[j & 8191] = a;
        *(float4*)&xbuf[(j + 4) & 8191] = c4;
      }
    }
  } else {
    constexpr int SPW = (KNUM + 3) / 4;
    const int kbase = wid * SPW;
    float yp[SPW], xC[SPW], xN[SPW];
    int rel = 0, par = 0;
#pragma unroll
    for (int kk = 0; kk < SPW; ++kk) { yp[kk] = 0.f; xC[kk] = 0.f; xN[kk] = 0.f; }
    for (int s = 0; s < nseg; ++s) {
      barrier_lgkm();
      if (s == 0) {
#pragma unroll
        for (int kk = 0; kk < SPW; ++kk) {
          int k = kbase + kk;
          if (k < KNUM) {
            int i = lane + (k << 6);
            xC[kk] = xbuf[i];
            xN[kk] = xbuf[C + i];
          }
        }
      }
      int fence = (s + 1) << 11;
      if (fence > span) fence = span;
      while (rel < fence) {
        barrier_lgkm();  // publishes previous iteration's bnd writes
        const int rb = par << 5, wb = rb ^ 32;
        float pbA = 0.f, pbB = 0.f;
        if (kbase == 0) {
          pbA = bnd[rb + 24];
          pbB = bnd[rb + 25];
        } else if (kbase < KNUM) {
          pbA = bnd[rb + (kbase - 1) * 2];
          pbB = bnd[rb + (kbase - 1) * 2 + 1];
        }
        float b2v[SPW], b3v[SPW];
#pragma unroll
        for (int kk = 0; kk < SPW; ++kk) {
          int k = kbase + kk;
          if (k < KNUM)
            b2v[kk] = shr1(yp[kk], (kk == 0) ? pbA : rl63(yp[kk - 1]));
        }
#pragma unroll
        for (int kk = 0; kk < SPW; ++kk) {
          int k = kbase + kk;
          if (k < KNUM)
            b3v[kk] = shr1(b2v[kk], (kk == 0) ? pbB : rlv(yp[kk - 1], 62));
        }
        float p1n = 0.f, p2n = 0.f;
        const bool ownLast = (KNUM - 1 >= kbase) && (KNUM - 1 < kbase + SPW);
        if (ownLast) {
          p1n = rlv(yp[KNUM - 1 - kbase], lq1);
          p2n = rlv(b2v[KNUM - 1 - kbase], lq1);
        }
#pragma unroll
        for (int kk = 0; kk < SPW; ++kk) {
          int k = kbase + kk;
          if (k < KNUM)
            yp[kk] = fmaf(c0w, yp[kk],
                          fmaf(c2w, b3v[kk], fmaf(c1w, b2v[kk], xC[kk])));
        }
#pragma unroll
        for (int kk = 0; kk < SPW; ++kk) {
          int k = kbase + kk;
          if (k < KNUM) {
            int i = lane + (k << 6);
            int n = s1 + rel + i;
            bool okl = (k < KNUM - 1) || (lane <= lq1);
            if (okl && n >= n0 && n < end) yg[n] = yp[kk];
            float h63 = rlv(yp[kk], 63);
            float h62 = rlv(yp[kk], 62);
            if (lane == 0) {
              bnd[wb + k * 2] = h63;
              bnd[wb + k * 2 + 1] = h62;
            }
          }
        }
        if (ownLast && lane == 0) {
          bnd[wb + 24] = p1n;
          bnd[wb + 25] = p2n;
        }
#pragma unroll
        for (int kk = 0; kk < SPW; ++kk) {
          int k = kbase + kk;
          if (k < KNUM) {
            xC[kk] = xN[kk];
            xN[kk] = xbuf[(rel + 2 * C + lane + (k << 6)) & 8191];
          }
        }
        rel += C;
        par ^= 1;
      }
      barrier_lgkm();
      int ls = s + 3;
      if (ls < nseg) {
        int j = (ls << 11) + 8 * t;
        float4 a = *(const float4*)&xg[j];
        float4 c4 = *(const float4*)&xg[j + 4];
        *(float4*)&xbuf[j & 8191] = a;
        *(float4*)&xbuf[(j + 4) & 8191] = c4;
      }
    }
  }
}

// KS phase driver (used by both coop phase B and standalone ks_kernel).
__device__ inline void ks_phase(int b, int q, const BParams& P,
                                const float* __restrict__ buf0,
                                float* __restrict__ buf1, float* xbuf,
                                float* bnd, int t) {
  const int C = P.Di;
  const int n0 = q << 10;
  float lg = -logf(P.g);
  int Wp = (int)ceilf(10.5f / fmaxf(lg, 1e-6f));
  if (Wp > 96) Wp = 96;
  if (Wp < 4) Wp = 4;
  int W = Wp * C;
  if (W > n0) W = n0;
  W = (W + 3) & ~3;
  const int s1 = n0 - W;
  const int span = W + T1;
  const int end = n0 + T1;
  const int nseg = (span + 2047) >> 11;
  const float* xg = buf0 + (size_t)b * NSAMP + s1;
  float* yg = buf1 + (size_t)b * NSAMP;
  for (int j = 8 * t; j < 6144; j += 2048) {
    float4 a = *(const float4*)&xg[j];
    float4 c4 = *(const float4*)&xg[j + 4];
    *(float4*)&xbuf[j] = a;
    *(float4*)&xbuf[j + 4] = c4;
  }
  if (t < 64) bnd[t] = 0.0f;
  const float c0w = P.g * (1.0f - P.s) * (1.0f - P.fr);
  const float c1w = P.g * ((1.0f - P.s) * P.fr + P.s * (1.0f - P.fr));
  const float c2w = P.g * P.s * P.fr;
  switch ((C + 63) >> 6) {
    case 2:  ks_slice2<2>(xg, yg, xbuf, bnd, t, C, c0w, c1w, c2w, s1, n0, end, span, nseg); break;
    case 3:  ks_slice2<3>(xg, yg, xbuf, bnd, t, C, c0w, c1w, c2w, s1, n0, end, span, nseg); break;
    case 4:  ks_slice2<4>(xg, yg, xbuf, bnd, t, C, c0w, c1w, c2w, s1, n0, end, span, nseg); break;
    case 5:  ks_slice2<5>(xg, yg, xbuf, bnd, t, C, c0w, c1w, c2w, s1, n0, end, span, nseg); break;
    case 6:  ks_slice2<6>(xg, yg, xbuf, bnd, t, C, c0w, c1w, c2w, s1, n0, end, span, nseg); break;
    case 7:  ks_slice2<7>(xg, yg, xbuf, bnd, t, C, c0w, c1w, c2w, s1, n0, end, span, nseg); break;
    case 8:  ks_slice2<8>(xg, yg, xbuf, bnd, t, C, c0w, c1w, c2w, s1, n0, end, span, nseg); break;
    case 9:  ks_slice2<9>(xg, yg, xbuf, bnd, t, C, c0w, c1w, c2w, s1, n0, end, span, nseg); break;
    case 10: ks_slice2<10>(xg, yg, xbuf, bnd, t, C, c0w, c1w, c2w, s1, n0, end, span, nseg); break;
    case 11: ks_slice2<11>(xg, yg, xbuf, bnd, t, C, c0w, c1w, c2w, s1, n0, end, span, nseg); break;
    default: ks_slice2<12>(xg, yg, xbuf, bnd, t, C, c0w, c1w, c2w, s1, n0, end, span, nseg); break;
  }
}

// Body phase (postLP into LDS + 24-band resonator, grouped by 8).
__device__ inline void body_phase(int b, int q, const BParams& P,
                                  const float* __restrict__ gains,
                                  const float* __restrict__ buf1,
                                  float* __restrict__ out, float* sl,
                                  float* lws, float (*lc0)[8],
                                  float (*lc1)[8], int t) {
  const int lane = t & 63, wid = t >> 6;
  const int n0 = q * T2;
  const int base = n0 - 4096;
  int s2 = base - 256;
  if (s2 < 0) s2 = 0;
  const int end = n0 + T2;
  const int nt = (end - s2 + 2047) >> 11;  // <= 5

  lpc_lds(buf1 + (size_t)b * NSAMP, sl, s2, nt, P.alpha_p, 1.0f - P.alpha_p, t,
          lws);
  __syncthreads();

  const int tb = base + 32 * t;
  float4 acc[8];
#pragma unroll
  for (int i = 0; i < 8; ++i) acc[i] = make_float4(0.f, 0.f, 0.f, 0.f);

  for (int g = 0; g < 3; ++g) {
    float A1[8], A2[8], B0[8], GN[8];
#pragma unroll
    for (int j = 0; j < 8; ++j) {
      int k = g * 8 + j;
      band_coef(k, A1[j], A2[j], B0[j]);
      GN[j] = gains[k];
    }
    float cv0[8], cv1[8];
#pragma unroll
    for (int j = 0; j < 8; ++j) cv0[j] = cv1[j] = 0.f;
    for (int i = 0; i < 8; ++i) {
      int n = tb + 4 * i;
      float4 xv = make_float4(0.f, 0.f, 0.f, 0.f);
      if (n >= 0) xv = *(const float4*)&sl[n - s2];
#pragma unroll
      for (int e = 0; e < 4; ++e) {
        float xi = e == 0 ? xv.x : e == 1 ? xv.y : e == 2 ? xv.z : xv.w;
#pragma unroll
        for (int j = 0; j < 8; ++j) {
          float nc = fmaf(B0[j], xi, -fmaf(A1[j], cv0[j], A2[j] * cv1[j]));
          cv1[j] = cv0[j];
          cv0[j] = nc;
        }
      }
    }
    float Q00[8], Q01[8], Q10[8], Q11[8];
#pragma unroll
    for (int j = 0; j < 8; ++j) {
      Q00[j] = -A1[j]; Q01[j] = -A2[j]; Q10[j] = 1.f; Q11[j] = 0.f;
    }
    for (int sq = 0; sq < 5; ++sq) {
#pragma unroll
      for (int j = 0; j < 8; ++j) {
        float n00 = fmaf(Q00[j], Q00[j], Q01[j] * Q10[j]);
        float n01 = fmaf(Q00[j], Q01[j], Q01[j] * Q11[j]);
        float n10 = fmaf(Q10[j], Q00[j], Q11[j] * Q10[j]);
        float n11 = fmaf(Q10[j], Q01[j], Q11[j] * Q11[j]);
        Q00[j] = n00; Q01[j] = n01; Q10[j] = n10; Q11[j] = n11;
      }
    }
    float T00[8], T01[8], T10[8], T11[8];
#pragma unroll
    for (int j = 0; j < 8; ++j) {
      T00[j] = Q00[j]; T01[j] = Q01[j]; T10[j] = Q10[j]; T11[j] = Q11[j];
    }
    for (int off = 1; off <= 32; off <<= 1) {
#pragma unroll
      for (int j = 0; j < 8; ++j) {
        float u0 = __shfl_up(cv0[j], off);
        float u1 = __shfl_up(cv1[j], off);
        if (lane >= off) {
          float nc0 = fmaf(Q00[j], u0, fmaf(Q01[j], u1, cv0[j]));
          float nc1 = fmaf(Q10[j], u0, fmaf(Q11[j], u1, cv1[j]));
          cv0[j] = nc0;
          cv1[j] = nc1;
        }
        float n00 = fmaf(Q00[j], Q00[j], Q01[j] * Q10[j]);
        float n01 = fmaf(Q00[j], Q01[j], Q01[j] * Q11[j]);
        float n10 = fmaf(Q10[j], Q00[j], Q11[j] * Q10[j]);
        float n11 = fmaf(Q10[j], Q01[j], Q11[j] * Q11[j]);
        Q00[j] = n00; Q01[j] = n01; Q10[j] = n10; Q11[j] = n11;
      }
    }
    __syncthreads();
    if (lane == 63) {
#pragma unroll
      for (int j = 0; j < 8; ++j) {
        lc0[wid][j] = cv0[j];
        lc1[wid][j] = cv1[j];
      }
    }
    __syncthreads();
    float car0[8], car1[8];
#pragma unroll
    for (int j = 0; j < 8; ++j) car0[j] = car1[j] = 0.f;
    for (int v = 0; v < wid; ++v) {
#pragma unroll
      for (int j = 0; j < 8; ++j) {
        float n0c = fmaf(Q00[j], car0[j], fmaf(Q01[j], car1[j], lc0[v][j]));
        float n1c = fmaf(Q10[j], car0[j], fmaf(Q11[j], car1[j], lc1[v][j]));
        car0[j] = n0c;
        car1[j] = n1c;
      }
    }
    float R00[8], R01[8], R10[8], R11[8];
#pragma unroll
    for (int j = 0; j < 8; ++j) {
      R00[j] = 1.f; R01[j] = 0.f; R10[j] = 0.f; R11[j] = 1.f;
    }
    for (int bit = 0; bit < 6; ++bit) {
      bool on = (lane >> bit) & 1;
#pragma unroll
      for (int j = 0; j < 8; ++j) {
        if (on) {
          float n00 = fmaf(T00[j], R00[j], T01[j] * R10[j]);
          float n01 = fmaf(T00[j], R01[j], T01[j] * R11[j]);
          float n10 = fmaf(T10[j], R00[j], T11[j] * R10[j]);
          float n11 = fmaf(T10[j], R01[j], T11[j] * R11[j]);
          R00[j] = n00; R01[j] = n01; R10[j] = n10; R11[j] = n11;
        }
        float s00 = fmaf(T00[j], T00[j], T01[j] * T10[j]);
        float s01 = fmaf(T00[j], T01[j], T01[j] * T11[j]);
        float s10 = fmaf(T10[j], T00[j], T11[j] * T10[j]);
        float s11 = fmaf(T10[j], T01[j], T11[j] * T11[j]);
        T00[j] = s00; T01[j] = s01; T10[j] = s10; T11[j] = s11;
      }
    }
    float y1[8], y2[8];
#pragma unroll
    for (int j = 0; j < 8; ++j) {
      float e0 = __shfl_up(cv0[j], 1);
      float e1 = __shfl_up(cv1[j], 1);
      if (lane == 0) { e0 = 0.f; e1 = 0.f; }
      y1[j] = fmaf(R00[j], car0[j], fmaf(R01[j], car1[j], e0));
      y2[j] = fmaf(R10[j], car0[j], fmaf(R11[j], car1[j], e1));
    }
    if (t >= 128) {
      for (int i = 0; i < 8; ++i) {
        float4 xv = *(const float4*)&sl[tb - s2 + 4 * i];
        float4 ov = acc[i];
#pragma unroll
        for (int e = 0; e < 4; ++e) {
          float xi = e == 0 ? xv.x : e == 1 ? xv.y : e == 2 ? xv.z : xv.w;
          float a = 0.f;
#pragma unroll
          for (int j = 0; j < 8; ++j) {
            float yv = fmaf(B0[j], xi, -fmaf(A1[j], y1[j], A2[j] * y2[j]));
            y2[j] = y1[j];
            y1[j] = yv;
            a = fmaf(GN[j], yv, a);
          }
          if (e == 0) ov.x += a;
          else if (e == 1) ov.y += a;
          else if (e == 2) ov.z += a;
          else ov.w += a;
        }
        acc[i] = ov;
      }
    }
  }
  if (t >= 128) {
    float* outb = out + (size_t)b * NSAMP;
#pragma unroll
    for (int i = 0; i < 8; ++i) *(float4*)&outb[tb + 4 * i] = acc[i];
  }
}

// ======== single cooperative kernel: preLP -> KS -> body ========
__global__ void __launch_bounds__(256, 1) guitar_coop(
    const float* __restrict__ exc, const float* __restrict__ pitch,
    const float* __restrict__ w1, const float* __restrict__ b1,
    const float* __restrict__ w2, const float* __restrict__ b2,
    const float* __restrict__ eg, const float* __restrict__ gains,
    float* __restrict__ buf0, float* __restrict__ buf1,
    float* __restrict__ out) {
  cg::grid_group grid = cg::this_grid();
  const int blk = blockIdx.x;
  const int t = threadIdx.x;
  __shared__ __align__(16) float smem[10320];

  // ---- phase A: preLP, slice-parallel (256 blocks = 8 batches x 32) ----
  const int bA = blk >> 5, qA = blk & 31;
  BParams P = compute_params(bA, pitch, w1, b1, w2, b2);
  if (blk == 0 && t < 64) {
    int bb = (t < 8) ? t : 0;
    BParams Q = compute_params(bb, pitch, w1, b1, w2, b2);
    float slc = 0.f, slm = 0.f, slp = 0.f;
    for (int i = 0; i < 8; ++i) {
      slc += rlv(Q.lc, i);
      slm += rlv(Q.lm, i);
      slp += rlv(Q.lp, i);
    }
    if (t == 0) {
      out[8 * NSAMP + 0] = slc / 8.0f;
      out[8 * NSAMP + 1] = slm / 8.0f;
      out[8 * NSAMP + 2] = slp / 8.0f;
    }
  }
  prelp_slice(exc + (size_t)bA * NSAMP, buf0 + (size_t)bA * NSAMP, qA << 10,
              eg[0] * P.alpha, 1.0f - P.alpha, t, smem);

  grid.sync();

  // ---- phase B: KS slices (256 blocks = 8 batches x 32 slices) ----
  ks_phase(bA, qA, P, buf0, buf1, smem, smem + 8192, t);

  grid.sync();

  // ---- phase C: body (blocks 0..63 = 8 batches x 8 slices) ----
  if (blk < 64) {
    const int bC = blk >> 3, qC = blk & 7;
    BParams PC = compute_params(bC, pitch, w1, b1, w2, b2);
    body_phase(bC, qC, PC, gains, buf1, out, smem, smem + 10240,
               (float(*)[8])(smem + 10248), (float(*)[8])(smem + 10280), t);
  }
}

// ======== fallback path: 3 separate kernels (R7, proven) ========
__global__ void __launch_bounds__(256) prelp_kernel(
    const float* __restrict__ exc, const float* __restrict__ pitch,
    const float* __restrict__ w1, const float* __restrict__ b1,
    const float* __restrict__ w2, const float* __restrict__ b2,
    const float* __restrict__ eg, float* __restrict__ buf0,
    float* __restrict__ out_scalars) {
  const int b = blockIdx.x, t = threadIdx.x;
  __shared__ float lws[8];
  BParams P = compute_params(b, pitch, w1, b1, w2, b2);
  if (b == 0 && t < 64) {
    int bb = (t < 8) ? t : 0;
    BParams Q = compute_params(bb, pitch, w1, b1, w2, b2);
    float slc = 0.f, slm = 0.f, slp = 0.f;
    for (int i = 0; i < 8; ++i) {
      slc += rlv(Q.lc, i);
      slm += rlv(Q.lm, i);
      slp += rlv(Q.lp, i);
    }
    if (t == 0) {
      out_scalars[0] = slc / 8.0f;
      out_scalars[1] = slm / 8.0f;
      out_scalars[2] = slp / 8.0f;
    }
  }
  lpc_scan2(exc + b * NSAMP, buf0 + b * NSAMP, eg[0] * P.alpha, 1.0f - P.alpha,
            t, lws);
}

__global__ void __launch_bounds__(256) ks_kernel(
    const float* __restrict__ pitch, const float* __restrict__ w1,
    const float* __restrict__ b1, const float* __restrict__ w2,
    const float* __restrict__ b2, const float* __restrict__ buf0,
    float* __restrict__ buf1) {
  const int blk = blockIdx.x;
  const int b = blk >> 5, q = blk & 31;
  const int t = threadIdx.x;
  __shared__ float lds[8192 + 64];
  BParams P = compute_params(b, pitch, w1, b1, w2, b2);
  ks_phase(b, q, P, buf0, buf1, lds, lds + 8192, t);
}

__global__ void __launch_bounds__(256, 1) body_kernel(
    const float* __restrict__ pitch, const float* __restrict__ w1,
    const float* __restrict__ b1, const float* __restrict__ w2,
    const float* __restrict__ b2, const float* __restrict__ gains,
    const float* __restrict__ buf1, float* __restrict__ out) {
  const int blk = blockIdx.x;
  const int b = blk >> 3, q = blk & 7;
  const int t = threadIdx.x;
  __shared__ __align__(16) float smem[10320];
  BParams P = compute_params(b, pitch, w1, b1, w2, b2);
  body_phase(b, q, P, gains, buf1, out, smem, smem + 10240,
             (float(*)[8])(smem + 10248), (float(*)[8])(smem + 10280), t);
}

extern "C" void kernel_launch(void* const* d_in, const int* in_sizes, int n_in,
                              void* d_out, int out_size, void* d_ws, size_t ws_size,
                              hipStream_t stream) {
  const float* exc = (const float*)d_in[0];
  const float* pitch = (const float*)d_in[1];
  const float* w1 = (const float*)d_in[2];
  const float* b1 = (const float*)d_in[3];
  const float* w2 = (const float*)d_in[4];
  const float* b2 = (const float*)d_in[5];
  const float* eg = (const float*)d_in[6];
  const float* bg = (const float*)d_in[7];
  float* out = (float*)d_out;
  float* buf0 = (float*)d_ws;             // 8*NSAMP + 8192 pad (preLP output)
  float* buf1 = buf0 + 8 * NSAMP + 8192;  // 8*NSAMP (KS output)

  void* args2[11];
  args2[0] = (void*)&exc;
  args2[1] = (void*)&pitch;
  args2[2] = (void*)&w1;
  args2[3] = (void*)&b1;
  args2[4] = (void*)&w2;
  args2[5] = (void*)&b2;
  args2[6] = (void*)&eg;
  args2[7] = (void*)&bg;
  args2[8] = (void*)&buf0;
  args2[9] = (void*)&buf1;
  args2[10] = (void*)&out;

  hipError_t err = hipLaunchCooperativeKernel(
      (const void*)guitar_coop, dim3(256), dim3(256), args2, 0, stream);
  if (err != hipSuccess) {
    // fallback: 3-dispatch path (identical numerics)
    hipLaunchKernelGGL(prelp_kernel, dim3(8), dim3(256), 0, stream, exc, pitch,
                       w1, b1, w2, b2, eg, buf0, out + 8 * NSAMP);
    hipLaunchKernelGGL(ks_kernel, dim3(256), dim3(256), 0, stream, pitch, w1,
                       b1, w2, b2, buf0, buf1);
    hipLaunchKernelGGL(body_kernel, dim3(64), dim3(256), 0, stream, pitch, w1,
                       b1, w2, b2, bg, buf1, out);
  }
}

// Round 10
// 142.666 us; speedup vs baseline: 1.3943x; 1.3943x over previous
//
#include <hip/hip_runtime.h>
#include <math.h>

#define NSAMP 32768
#define FS_F 44100.0f
#define PI_F 3.14159265358979323846f
#define T1 1024  // KS slice length (32 slices/batch)
#define T2 4096  // body slice length (8 slices/batch)

struct BParams {
  float alpha, alpha_p;
  float fr, g, s;
  int Di;
  float lc, lm, lp;
};

__device__ inline float sigmoidf_(float x) { return 1.0f / (1.0f + expf(-x)); }

__device__ inline BParams compute_params(int b, const float* __restrict__ pitch,
                                         const float* __restrict__ w1,
                                         const float* __restrict__ b1,
                                         const float* __restrict__ w2,
                                         const float* __restrict__ b2) {
  BParams P;
  float p = pitch[b];
  float h[16];
#pragma unroll
  for (int i = 0; i < 16; ++i) {
    float v = fmaf(p, w1[i], b1[i]);
    h[i] = v > 0.0f ? v : 0.0f;
  }
  float m[3];
#pragma unroll
  for (int j = 0; j < 3; ++j) {
    float acc = b2[j];
#pragma unroll
    for (int i = 0; i < 16; ++i) acc = fmaf(h[i], w2[j * 16 + i], acc);
    m[j] = acc;
  }
  P.lc = fminf(fmaxf(m[0], -2.0f), 2.5f);
  P.lm = fminf(fmaxf(m[1], -2.5f), 0.0f);
  P.lp = fminf(fmaxf(m[2], -4.0f), 4.0f);
  P.g = 0.999f * sigmoidf_(P.lc);
  P.s = sigmoidf_(P.lm);
  float f0 = fmaxf(p, 60.0f);
  float D = fminf(fmaxf(FS_F / f0, 2.0f), 735.0f);
  int Di = (int)floorf(D);
  P.fr = D - (float)Di;
  P.Di = Di;
  float mult = fminf(fmaxf(2.0f + 6.0f * (f0 - 60.0f) / 600.0f, 2.0f), 8.0f);
  float cutoff = fminf(2.0f * PI_F * f0 * mult / FS_F, PI_F * 0.9f);
  P.alpha = 1.0f - expf(-cutoff);
  float cpost = fminf(PI_F * sigmoidf_(P.lp), PI_F * 0.99f);
  P.alpha_p = 1.0f - expf(-cpost);
  return P;
}

// lane helpers (wave64)
__device__ inline float rl63(float v) {
  return __int_as_float(__builtin_amdgcn_readlane(__float_as_int(v), 63));
}
__device__ inline float rlv(float v, int l) {
  return __int_as_float(__builtin_amdgcn_readlane(__float_as_int(v), l));
}
__device__ inline float shr1(float v, float bnd) {
  return __int_as_float(__builtin_amdgcn_update_dpp(
      __float_as_int(bnd), __float_as_int(v), 0x138 /*wave_shr:1*/, 0xf, 0xf,
      false));
}

// Block barrier draining ONLY lgkmcnt (keeps global stores in flight).
__device__ inline void barrier_lgkm() {
  asm volatile("s_waitcnt lgkmcnt(0)\n\ts_barrier" ::: "memory");
}

__device__ inline void band_coef(int k, float& a1, float& a2, float& b0) {
  float fc = 80.0f * exp2f((float)k * (6.64385618977472436f / 23.0f));
  float w = 2.0f * PI_F * fc / FS_F;
  float r = expf(-PI_F * fc / (10.0f * FS_F));
  a1 = -2.0f * r * cosf(w);
  a2 = r * r;
  b0 = 1.0f - r;
}

// ---- on-the-fly preLP scan context (per thread registers) ----
struct SCtx {
  const float* exc_b;  // exc + b*NSAMP
  float scale, c;
  float m1, m2, m4, m8, m16, m32, c512, c2048, c8lane, cgk;
  float vrun;  // scan carry (preLP state at end of last processed tile)
  int s1;
  float* lws;  // 8 floats LDS
};

// Scan one 2048-sample tile at absolute start A = s1 + (seg<<11) (seg may be
// -1 for the state-only pre-roll). All 256 threads; 2 block barriers.
// If write: store result into xbuf ring at rel index & 8191.
__device__ inline void scan_seg(SCtx& SC, float* xbuf, int seg, bool write,
                                int t) {
  const int lane = t & 63, wid = t >> 6;
  const int rel0 = seg << 11;
  const int A = SC.s1 + rel0;
  __syncthreads();  // protect lws reuse from previous tile
  const int g0 = A + 8 * t;
  float4 xa = make_float4(0.f, 0.f, 0.f, 0.f);
  float4 xb = make_float4(0.f, 0.f, 0.f, 0.f);
  if (g0 >= 0 && g0 + 3 < NSAMP) xa = *(const float4*)&SC.exc_b[g0];
  if (g0 + 4 >= 0 && g0 + 7 < NSAMP) xb = *(const float4*)&SC.exc_b[g0 + 4];
  const float c = SC.c, scale = SC.scale;
  float S = 0.0f;
  S = fmaf(c, S, scale * xa.x); S = fmaf(c, S, scale * xa.y);
  S = fmaf(c, S, scale * xa.z); S = fmaf(c, S, scale * xa.w);
  S = fmaf(c, S, scale * xb.x); S = fmaf(c, S, scale * xb.y);
  S = fmaf(c, S, scale * xb.z); S = fmaf(c, S, scale * xb.w);
  float Sw = S, u;
  u = __shfl_up(Sw, 1);  if (lane >= 1)  Sw = fmaf(SC.m1, u, Sw);
  u = __shfl_up(Sw, 2);  if (lane >= 2)  Sw = fmaf(SC.m2, u, Sw);
  u = __shfl_up(Sw, 4);  if (lane >= 4)  Sw = fmaf(SC.m4, u, Sw);
  u = __shfl_up(Sw, 8);  if (lane >= 8)  Sw = fmaf(SC.m8, u, Sw);
  u = __shfl_up(Sw, 16); if (lane >= 16) Sw = fmaf(SC.m16, u, Sw);
  u = __shfl_up(Sw, 32); if (lane >= 32) Sw = fmaf(SC.m32, u, Sw);
  if (lane == 63) SC.lws[wid] = Sw;
  __syncthreads();
  float a0 = SC.lws[0], a1w = SC.lws[1], a2w = SC.lws[2], a3w = SC.lws[3];
  float carry = (wid == 1)   ? a0
                : (wid == 2) ? fmaf(SC.c512, a0, a1w)
                : (wid == 3) ? fmaf(SC.c512, fmaf(SC.c512, a0, a1w), a2w)
                             : 0.0f;
  float Sprev = __shfl_up(Sw, 1);
  float Sex = (lane == 0) ? 0.0f : Sprev;
  Sex = fmaf(SC.c8lane, carry, Sex);
  float v = fmaf(SC.cgk, SC.vrun, Sex);
  float4 ya, yb;
  v = fmaf(c, v, scale * xa.x); ya.x = v;
  v = fmaf(c, v, scale * xa.y); ya.y = v;
  v = fmaf(c, v, scale * xa.z); ya.z = v;
  v = fmaf(c, v, scale * xa.w); ya.w = v;
  v = fmaf(c, v, scale * xb.x); yb.x = v;
  v = fmaf(c, v, scale * xb.y); yb.y = v;
  v = fmaf(c, v, scale * xb.z); yb.z = v;
  v = fmaf(c, v, scale * xb.w); yb.w = v;
  if (write) {
    int o = (rel0 + 8 * t) & 8191;  // 8-sample group never crosses the wrap
    *(float4*)&xbuf[o] = ya;
    *(float4*)&xbuf[o + 4] = yb;
  }
  float tS = fmaf(SC.c512, fmaf(SC.c512, fmaf(SC.c512, a0, a1w), a2w), a3w);
  SC.vrun = fmaf(SC.c2048, SC.vrun, tS);
}

// KS slice compute (R7 structure, proven) with x staged via scan_seg.
template <int KNUM>
__device__ void ks_slice2(SCtx& SC, float* __restrict__ yg, float* xbuf,
                          float* bnd, int t, int C, float c0w, float c1w,
                          float c2w, int s1, int n0, int end, int span,
                          int nseg) {
  const int lane = t & 63;
  const int wid = t >> 6;
  const int lq1 = (C - 1) - (KNUM - 1) * 64;

  if (KNUM <= 3) {
    float yp[KNUM], xC[KNUM], xN[KNUM];
    float p1 = 0.f, p2 = 0.f;
    int rel = 0;
#pragma unroll
    for (int k = 0; k < KNUM; ++k) { yp[k] = 0.f; xC[k] = 0.f; xN[k] = 0.f; }
    for (int s = 0; s < nseg; ++s) {
      barrier_lgkm();
      if (wid == 0) {
        if (s == 0) {
#pragma unroll
          for (int k = 0; k < KNUM; ++k) {
            int i = lane + (k << 6);
            xC[k] = xbuf[i];
            xN[k] = xbuf[C + i];
          }
        }
        int fence = (s + 1) << 11;
        if (fence > span) fence = span;
        while (rel < fence) {
          float b2v[KNUM], b3v[KNUM];
#pragma unroll
          for (int k = 0; k < KNUM; ++k)
            b2v[k] = shr1(yp[k], (k == 0) ? p1 : rl63(yp[k - 1]));
#pragma unroll
          for (int k = 0; k < KNUM; ++k)
            b3v[k] = shr1(b2v[k], (k == 0) ? p2 : rlv(yp[k - 1], 62));
          float p1n = rlv(yp[KNUM - 1], lq1);
          float p2n = rlv(b2v[KNUM - 1], lq1);
#pragma unroll
          for (int k = 0; k < KNUM; ++k)
            yp[k] = fmaf(c0w, yp[k],
                         fmaf(c2w, b3v[k], fmaf(c1w, b2v[k], xC[k])));
          p1 = p1n;
          p2 = p2n;
#pragma unroll
          for (int k = 0; k < KNUM; ++k) {
            int i = lane + (k << 6);
            int n = s1 + rel + i;
            bool okl = (k < KNUM - 1) || (lane <= lq1);
            if (okl && n >= n0 && n < end) yg[n] = yp[k];
          }
#pragma unroll
          for (int k = 0; k < KNUM; ++k) {
            xC[k] = xN[k];
            xN[k] = xbuf[(rel + 2 * C + lane + (k << 6)) & 8191];
          }
          rel += C;
        }
      }
      barrier_lgkm();
      int ls = s + 3;
      if (ls < nseg) scan_seg(SC, xbuf, ls, true, t);
    }
  } else {
    constexpr int SPW = (KNUM + 3) / 4;
    const int kbase = wid * SPW;
    float yp[SPW], xC[SPW], xN[SPW];
    int rel = 0, par = 0;
#pragma unroll
    for (int kk = 0; kk < SPW; ++kk) { yp[kk] = 0.f; xC[kk] = 0.f; xN[kk] = 0.f; }
    for (int s = 0; s < nseg; ++s) {
      barrier_lgkm();
      if (s == 0) {
#pragma unroll
        for (int kk = 0; kk < SPW; ++kk) {
          int k = kbase + kk;
          if (k < KNUM) {
            int i = lane + (k << 6);
            xC[kk] = xbuf[i];
            xN[kk] = xbuf[C + i];
          }
        }
      }
      int fence = (s + 1) << 11;
      if (fence > span) fence = span;
      while (rel < fence) {
        barrier_lgkm();  // publishes previous iteration's bnd writes
        const int rb = par << 5, wb = rb ^ 32;
        float pbA = 0.f, pbB = 0.f;
        if (kbase == 0) {
          pbA = bnd[rb + 24];
          pbB = bnd[rb + 25];
        } else if (kbase < KNUM) {
          pbA = bnd[rb + (kbase - 1) * 2];
          pbB = bnd[rb + (kbase - 1) * 2 + 1];
        }
        float b2v[SPW], b3v[SPW];
#pragma unroll
        for (int kk = 0; kk < SPW; ++kk) {
          int k = kbase + kk;
          if (k < KNUM)
            b2v[kk] = shr1(yp[kk], (kk == 0) ? pbA : rl63(yp[kk - 1]));
        }
#pragma unroll
        for (int kk = 0; kk < SPW; ++kk) {
          int k = kbase + kk;
          if (k < KNUM)
            b3v[kk] = shr1(b2v[kk], (kk == 0) ? pbB : rlv(yp[kk - 1], 62));
        }
        float p1n = 0.f, p2n = 0.f;
        const bool ownLast = (KNUM - 1 >= kbase) && (KNUM - 1 < kbase + SPW);
        if (ownLast) {
          p1n = rlv(yp[KNUM - 1 - kbase], lq1);
          p2n = rlv(b2v[KNUM - 1 - kbase], lq1);
        }
#pragma unroll
        for (int kk = 0; kk < SPW; ++kk) {
          int k = kbase + kk;
          if (k < KNUM)
            yp[kk] = fmaf(c0w, yp[kk],
                          fmaf(c2w, b3v[kk], fmaf(c1w, b2v[kk], xC[kk])));
        }
#pragma unroll
        for (int kk = 0; kk < SPW; ++kk) {
          int k = kbase + kk;
          if (k < KNUM) {
            int i = lane + (k << 6);
            int n = s1 + rel + i;
            bool okl = (k < KNUM - 1) || (lane <= lq1);
            if (okl && n >= n0 && n < end) yg[n] = yp[kk];
            float h63 = rlv(yp[kk], 63);
            float h62 = rlv(yp[kk], 62);
            if (lane == 0) {
              bnd[wb + k * 2] = h63;
              bnd[wb + k * 2 + 1] = h62;
            }
          }
        }
        if (ownLast && lane == 0) {
          bnd[wb + 24] = p1n;
          bnd[wb + 25] = p2n;
        }
#pragma unroll
        for (int kk = 0; kk < SPW; ++kk) {
          int k = kbase + kk;
          if (k < KNUM) {
            xC[kk] = xN[kk];
            xN[kk] = xbuf[(rel + 2 * C + lane + (k << 6)) & 8191];
          }
        }
        rel += C;
        par ^= 1;
      }
      barrier_lgkm();
      int ls = s + 3;
      if (ls < nseg) scan_seg(SC, xbuf, ls, true, t);
    }
  }
}

// ---------------- k1: fused preLP + KS ----------------
// One block per (batch, slice of 1024). preLP computed on the fly from exc
// (pre-roll tile at s1-2048 establishes state, error <= c^2048 ~ 1e-15).
__global__ void __launch_bounds__(256) ks_fused_kernel(
    const float* __restrict__ exc, const float* __restrict__ pitch,
    const float* __restrict__ w1, const float* __restrict__ b1,
    const float* __restrict__ w2, const float* __restrict__ b2,
    const float* __restrict__ eg, float* __restrict__ buf1,
    float* __restrict__ out_scalars) {
  const int blk = blockIdx.x;
  const int b = blk >> 5, q = blk & 31;
  const int t = threadIdx.x;
  __shared__ __align__(16) float lds[8192 + 64 + 8];
  float* xbuf = lds;
  float* bnd = lds + 8192;
  float* lws = lds + 8256;

  BParams P = compute_params(b, pitch, w1, b1, w2, b2);
  if (blk == 0 && t < 64) {
    int bb = (t < 8) ? t : 0;
    BParams Q = compute_params(bb, pitch, w1, b1, w2, b2);
    float slc = 0.f, slm = 0.f, slp = 0.f;
    for (int i = 0; i < 8; ++i) {
      slc += rlv(Q.lc, i);
      slm += rlv(Q.lm, i);
      slp += rlv(Q.lp, i);
    }
    if (t == 0) {
      out_scalars[0] = slc / 8.0f;
      out_scalars[1] = slm / 8.0f;
      out_scalars[2] = slp / 8.0f;
    }
  }

  const int C = P.Di;
  const int n0 = q << 10;
  float lg = -logf(P.g);
  int Wp = (int)ceilf(10.5f / fmaxf(lg, 1e-6f));
  if (Wp > 96) Wp = 96;
  if (Wp < 4) Wp = 4;
  int W = Wp * C;
  if (W > n0) W = n0;
  W = (W + 3) & ~3;
  const int s1 = n0 - W;
  const int span = W + T1;
  const int end = n0 + T1;
  const int nseg = (span + 2047) >> 11;
  float* yg = buf1 + (size_t)b * NSAMP;

  SCtx SC;
  SC.exc_b = exc + (size_t)b * NSAMP;
  SC.c = 1.0f - P.alpha;
  SC.scale = eg[0] * P.alpha;
  {
    float c = SC.c;
    float c2v = c * c, c4 = c2v * c2v, c8 = c4 * c4;
    SC.m1 = c8;
    SC.m2 = SC.m1 * SC.m1;
    SC.m4 = SC.m2 * SC.m2;
    SC.m8 = SC.m4 * SC.m4;
    SC.m16 = SC.m8 * SC.m8;
    SC.m32 = SC.m16 * SC.m16;
    SC.c512 = SC.m32 * SC.m32;
    float c1024 = SC.c512 * SC.c512;
    SC.c2048 = c1024 * c1024;
    float l2c = log2f(c);
    SC.c8lane = exp2f((float)(8 * (t & 63)) * l2c);
    SC.cgk = exp2f((float)(8 * t) * l2c);
  }
  SC.vrun = 0.0f;
  SC.s1 = s1;
  SC.lws = lws;

  if (s1 > 0) scan_seg(SC, xbuf, -1, false, t);  // state-only pre-roll
  scan_seg(SC, xbuf, 0, true, t);                // preamble segments 0..2
  scan_seg(SC, xbuf, 1, true, t);
  scan_seg(SC, xbuf, 2, true, t);
  if (t < 64) bnd[t] = 0.0f;

  const float c0w = P.g * (1.0f - P.s) * (1.0f - P.fr);
  const float c1w = P.g * ((1.0f - P.s) * P.fr + P.s * (1.0f - P.fr));
  const float c2w = P.g * P.s * P.fr;
  switch ((C + 63) >> 6) {
    case 2:  ks_slice2<2>(SC, yg, xbuf, bnd, t, C, c0w, c1w, c2w, s1, n0, end, span, nseg); break;
    case 3:  ks_slice2<3>(SC, yg, xbuf, bnd, t, C, c0w, c1w, c2w, s1, n0, end, span, nseg); break;
    case 4:  ks_slice2<4>(SC, yg, xbuf, bnd, t, C, c0w, c1w, c2w, s1, n0, end, span, nseg); break;
    case 5:  ks_slice2<5>(SC, yg, xbuf, bnd, t, C, c0w, c1w, c2w, s1, n0, end, span, nseg); break;
    case 6:  ks_slice2<6>(SC, yg, xbuf, bnd, t, C, c0w, c1w, c2w, s1, n0, end, span, nseg); break;
    case 7:  ks_slice2<7>(SC, yg, xbuf, bnd, t, C, c0w, c1w, c2w, s1, n0, end, span, nseg); break;
    case 8:  ks_slice2<8>(SC, yg, xbuf, bnd, t, C, c0w, c1w, c2w, s1, n0, end, span, nseg); break;
    case 9:  ks_slice2<9>(SC, yg, xbuf, bnd, t, C, c0w, c1w, c2w, s1, n0, end, span, nseg); break;
    case 10: ks_slice2<10>(SC, yg, xbuf, bnd, t, C, c0w, c1w, c2w, s1, n0, end, span, nseg); break;
    case 11: ks_slice2<11>(SC, yg, xbuf, bnd, t, C, c0w, c1w, c2w, s1, n0, end, span, nseg); break;
    default: ks_slice2<12>(SC, yg, xbuf, bnd, t, C, c0w, c1w, c2w, s1, n0, end, span, nseg); break;
  }
}

// One-pole scan over [s2, s2+nt*2048) from global into LDS sl[n-s2] (body).
__device__ inline void lpc_lds(const float* __restrict__ xg,
                               float* __restrict__ sl, int s2, int nt,
                               float scale, float c, int t, float* lws) {
  const int lane = t & 63, wid = t >> 6;
  float c2v = c * c, c4 = c2v * c2v, c8 = c4 * c4;
  float m1 = c8, m2 = m1 * m1, m4 = m2 * m2, m8 = m4 * m4, m16 = m8 * m8,
        m32 = m16 * m16;
  float c512 = m32 * m32;
  float c2048 = c512 * c512;
  c2048 *= c2048;
  float l2c = log2f(c);
  float c8lane = exp2f((float)(8 * lane) * l2c);
  float cgk = exp2f((float)(8 * t) * l2c);
  float vrun = 0.0f;
  for (int tile = 0; tile < nt; ++tile) {
    __syncthreads();
    int g0 = s2 + (tile << 11) + 8 * t;
    float4 xa = make_float4(0.f, 0.f, 0.f, 0.f);
    float4 xb = make_float4(0.f, 0.f, 0.f, 0.f);
    if (g0 + 3 < NSAMP) xa = *(const float4*)&xg[g0];
    if (g0 + 7 < NSAMP) xb = *(const float4*)&xg[g0 + 4];
    float S = 0.0f;
    S = fmaf(c, S, scale * xa.x); S = fmaf(c, S, scale * xa.y);
    S = fmaf(c, S, scale * xa.z); S = fmaf(c, S, scale * xa.w);
    S = fmaf(c, S, scale * xb.x); S = fmaf(c, S, scale * xb.y);
    S = fmaf(c, S, scale * xb.z); S = fmaf(c, S, scale * xb.w);
    float Sw = S, u;
    u = __shfl_up(Sw, 1);  if (lane >= 1)  Sw = fmaf(m1, u, Sw);
    u = __shfl_up(Sw, 2);  if (lane >= 2)  Sw = fmaf(m2, u, Sw);
    u = __shfl_up(Sw, 4);  if (lane >= 4)  Sw = fmaf(m4, u, Sw);
    u = __shfl_up(Sw, 8);  if (lane >= 8)  Sw = fmaf(m8, u, Sw);
    u = __shfl_up(Sw, 16); if (lane >= 16) Sw = fmaf(m16, u, Sw);
    u = __shfl_up(Sw, 32); if (lane >= 32) Sw = fmaf(m32, u, Sw);
    if (lane == 63) lws[wid] = Sw;
    __syncthreads();
    float a0 = lws[0], a1w = lws[1], a2w = lws[2], a3w = lws[3];
    float carry = (wid == 1)   ? a0
                  : (wid == 2) ? fmaf(c512, a0, a1w)
                  : (wid == 3) ? fmaf(c512, fmaf(c512, a0, a1w), a2w)
                               : 0.0f;
    float Sprev = __shfl_up(Sw, 1);
    float Sex = (lane == 0) ? 0.0f : Sprev;
    Sex = fmaf(c8lane, carry, Sex);
    float v = fmaf(cgk, vrun, Sex);
    int o = g0 - s2;
    float4 ya, yb;
    v = fmaf(c, v, scale * xa.x); ya.x = v;
    v = fmaf(c, v, scale * xa.y); ya.y = v;
    v = fmaf(c, v, scale * xa.z); ya.z = v;
    v = fmaf(c, v, scale * xa.w); ya.w = v;
    v = fmaf(c, v, scale * xb.x); yb.x = v;
    v = fmaf(c, v, scale * xb.y); yb.y = v;
    v = fmaf(c, v, scale * xb.z); yb.z = v;
    v = fmaf(c, v, scale * xb.w); yb.w = v;
    *(float4*)&sl[o] = ya;
    *(float4*)&sl[o + 4] = yb;
    float tS = fmaf(c512, fmaf(c512, fmaf(c512, a0, a1w), a2w), a3w);
    vrun = fmaf(c2048, vrun, tS);
  }
}

// ---------------- k2: postLP (LDS) + 24-band body (R7, proven) ----------------
__global__ void __launch_bounds__(256, 1) body_kernel(
    const float* __restrict__ pitch, const float* __restrict__ w1,
    const float* __restrict__ b1, const float* __restrict__ w2,
    const float* __restrict__ b2, const float* __restrict__ gains,
    const float* __restrict__ buf1, float* __restrict__ out) {
  const int blk = blockIdx.x;
  const int b = blk >> 3, q = blk & 7;
  const int t = threadIdx.x;
  const int lane = t & 63, wid = t >> 6;
  __shared__ __align__(16) float sl[10240];
  __shared__ float lws[8];
  __shared__ float lc0[4][8], lc1[4][8];

  BParams P = compute_params(b, pitch, w1, b1, w2, b2);
  const int n0 = q * T2;
  const int base = n0 - 4096;
  int s2 = base - 256;
  if (s2 < 0) s2 = 0;
  const int end = n0 + T2;
  const int nt = (end - s2 + 2047) >> 11;  // <= 5

  lpc_lds(buf1 + (size_t)b * NSAMP, sl, s2, nt, P.alpha_p, 1.0f - P.alpha_p, t,
          lws);
  __syncthreads();

  const int tb = base + 32 * t;
  float4 acc[8];
#pragma unroll
  for (int i = 0; i < 8; ++i) acc[i] = make_float4(0.f, 0.f, 0.f, 0.f);

  for (int g = 0; g < 3; ++g) {
    float A1[8], A2[8], B0[8], GN[8];
#pragma unroll
    for (int j = 0; j < 8; ++j) {
      int k = g * 8 + j;
      band_coef(k, A1[j], A2[j], B0[j]);
      GN[j] = gains[k];
    }
    float cv0[8], cv1[8];
#pragma unroll
    for (int j = 0; j < 8; ++j) cv0[j] = cv1[j] = 0.f;
    for (int i = 0; i < 8; ++i) {
      int n = tb + 4 * i;
      float4 xv = make_float4(0.f, 0.f, 0.f, 0.f);
      if (n >= 0) xv = *(const float4*)&sl[n - s2];
#pragma unroll
      for (int e = 0; e < 4; ++e) {
        float xi = e == 0 ? xv.x : e == 1 ? xv.y : e == 2 ? xv.z : xv.w;
#pragma unroll
        for (int j = 0; j < 8; ++j) {
          float nc = fmaf(B0[j], xi, -fmaf(A1[j], cv0[j], A2[j] * cv1[j]));
          cv1[j] = cv0[j];
          cv0[j] = nc;
        }
      }
    }
    float Q00[8], Q01[8], Q10[8], Q11[8];
#pragma unroll
    for (int j = 0; j < 8; ++j) {
      Q00[j] = -A1[j]; Q01[j] = -A2[j]; Q10[j] = 1.f; Q11[j] = 0.f;
    }
    for (int sq = 0; sq < 5; ++sq) {
#pragma unroll
      for (int j = 0; j < 8; ++j) {
        float n00 = fmaf(Q00[j], Q00[j], Q01[j] * Q10[j]);
        float n01 = fmaf(Q00[j], Q01[j], Q01[j] * Q11[j]);
        float n10 = fmaf(Q10[j], Q00[j], Q11[j] * Q10[j]);
        float n11 = fmaf(Q10[j], Q01[j], Q11[j] * Q11[j]);
        Q00[j] = n00; Q01[j] = n01; Q10[j] = n10; Q11[j] = n11;
      }
    }
    float T00[8], T01[8], T10[8], T11[8];
#pragma unroll
    for (int j = 0; j < 8; ++j) {
      T00[j] = Q00[j]; T01[j] = Q01[j]; T10[j] = Q10[j]; T11[j] = Q11[j];
    }
    for (int off = 1; off <= 32; off <<= 1) {
#pragma unroll
      for (int j = 0; j < 8; ++j) {
        float u0 = __shfl_up(cv0[j], off);
        float u1 = __shfl_up(cv1[j], off);
        if (lane >= off) {
          float nc0 = fmaf(Q00[j], u0, fmaf(Q01[j], u1, cv0[j]));
          float nc1 = fmaf(Q10[j], u0, fmaf(Q11[j], u1, cv1[j]));
          cv0[j] = nc0;
          cv1[j] = nc1;
        }
        float n00 = fmaf(Q00[j], Q00[j], Q01[j] * Q10[j]);
        float n01 = fmaf(Q00[j], Q01[j], Q01[j] * Q11[j]);
        float n10 = fmaf(Q10[j], Q00[j], Q11[j] * Q10[j]);
        float n11 = fmaf(Q10[j], Q01[j], Q11[j] * Q11[j]);
        Q00[j] = n00; Q01[j] = n01; Q10[j] = n10; Q11[j] = n11;
      }
    }
    __syncthreads();
    if (lane == 63) {
#pragma unroll
      for (int j = 0; j < 8; ++j) {
        lc0[wid][j] = cv0[j];
        lc1[wid][j] = cv1[j];
      }
    }
    __syncthreads();
    float car0[8], car1[8];
#pragma unroll
    for (int j = 0; j < 8; ++j) car0[j] = car1[j] = 0.f;
    for (int v = 0; v < wid; ++v) {
#pragma unroll
      for (int j = 0; j < 8; ++j) {
        float n0c = fmaf(Q00[j], car0[j], fmaf(Q01[j], car1[j], lc0[v][j]));
        float n1c = fmaf(Q10[j], car0[j], fmaf(Q11[j], car1[j], lc1[v][j]));
        car0[j] = n0c;
        car1[j] = n1c;
      }
    }
    float R00[8], R01[8], R10[8], R11[8];
#pragma unroll
    for (int j = 0; j < 8; ++j) {
      R00[j] = 1.f; R01[j] = 0.f; R10[j] = 0.f; R11[j] = 1.f;
    }
    for (int bit = 0; bit < 6; ++bit) {
      bool on = (lane >> bit) & 1;
#pragma unroll
      for (int j = 0; j < 8; ++j) {
        if (on) {
          float n00 = fmaf(T00[j], R00[j], T01[j] * R10[j]);
          float n01 = fmaf(T00[j], R01[j], T01[j] * R11[j]);
          float n10 = fmaf(T10[j], R00[j], T11[j] * R10[j]);
          float n11 = fmaf(T10[j], R01[j], T11[j] * R11[j]);
          R00[j] = n00; R01[j] = n01; R10[j] = n10; R11[j] = n11;
        }
        float s00 = fmaf(T00[j], T00[j], T01[j] * T10[j]);
        float s01 = fmaf(T00[j], T01[j], T01[j] * T11[j]);
        float s10 = fmaf(T10[j], T00[j], T11[j] * T10[j]);
        float s11 = fmaf(T10[j], T01[j], T11[j] * T11[j]);
        T00[j] = s00; T01[j] = s01; T10[j] = s10; T11[j] = s11;
      }
    }
    float y1[8], y2[8];
#pragma unroll
    for (int j = 0; j < 8; ++j) {
      float e0 = __shfl_up(cv0[j], 1);
      float e1 = __shfl_up(cv1[j], 1);
      if (lane == 0) { e0 = 0.f; e1 = 0.f; }
      y1[j] = fmaf(R00[j], car0[j], fmaf(R01[j], car1[j], e0));
      y2[j] = fmaf(R10[j], car0[j], fmaf(R11[j], car1[j], e1));
    }
    if (t >= 128) {
      for (int i = 0; i < 8; ++i) {
        float4 xv = *(const float4*)&sl[tb - s2 + 4 * i];
        float4 ov = acc[i];
#pragma unroll
        for (int e = 0; e < 4; ++e) {
          float xi = e == 0 ? xv.x : e == 1 ? xv.y : e == 2 ? xv.z : xv.w;
          float a = 0.f;
#pragma unroll
          for (int j = 0; j < 8; ++j) {
            float yv = fmaf(B0[j], xi, -fmaf(A1[j], y1[j], A2[j] * y2[j]));
            y2[j] = y1[j];
            y1[j] = yv;
            a = fmaf(GN[j], yv, a);
          }
          if (e == 0) ov.x += a;
          else if (e == 1) ov.y += a;
          else if (e == 2) ov.z += a;
          else ov.w += a;
        }
        acc[i] = ov;
      }
    }
  }
  if (t >= 128) {
    float* outb = out + (size_t)b * NSAMP;
#pragma unroll
    for (int i = 0; i < 8; ++i) *(float4*)&outb[tb + 4 * i] = acc[i];
  }
}

extern "C" void kernel_launch(void* const* d_in, const int* in_sizes, int n_in,
                              void* d_out, int out_size, void* d_ws, size_t ws_size,
                              hipStream_t stream) {
  const float* exc = (const float*)d_in[0];
  const float* pitch = (const float*)d_in[1];
  const float* w1 = (const float*)d_in[2];
  const float* b1 = (const float*)d_in[3];
  const float* w2 = (const float*)d_in[4];
  const float* b2 = (const float*)d_in[5];
  const float* eg = (const float*)d_in[6];
  const float* bg = (const float*)d_in[7];
  float* out = (float*)d_out;
  float* buf1 = (float*)d_ws;  // 8*NSAMP floats (KS output)

  hipLaunchKernelGGL(ks_fused_kernel, dim3(256), dim3(256), 0, stream, exc,
                     pitch, w1, b1, w2, b2, eg, buf1, out + 8 * NSAMP);
  hipLaunchKernelGGL(body_kernel, dim3(64), dim3(256), 0, stream, pitch, w1,
                     b1, w2, b2, bg, buf1, out);
}

// Round 11
// 140.027 us; speedup vs baseline: 1.4206x; 1.0188x over previous
//
#include <hip/hip_runtime.h>
#include <math.h>

#define NSAMP 32768
#define FS_F 44100.0f
#define PI_F 3.14159265358979323846f
#define T1 1024  // KS slice length (32 slices/batch)
#define T2 4096  // body slice length (8 slices/batch)

struct BParams {
  float alpha, alpha_p;
  float fr, g, s;
  int Di;
  float lc, lm, lp;
};

__device__ inline float sigmoidf_(float x) { return 1.0f / (1.0f + expf(-x)); }

__device__ inline BParams compute_params(int b, const float* __restrict__ pitch,
                                         const float* __restrict__ w1,
                                         const float* __restrict__ b1,
                                         const float* __restrict__ w2,
                                         const float* __restrict__ b2) {
  BParams P;
  float p = pitch[b];
  float h[16];
#pragma unroll
  for (int i = 0; i < 16; ++i) {
    float v = fmaf(p, w1[i], b1[i]);
    h[i] = v > 0.0f ? v : 0.0f;
  }
  float m[3];
#pragma unroll
  for (int j = 0; j < 3; ++j) {
    float acc = b2[j];
#pragma unroll
    for (int i = 0; i < 16; ++i) acc = fmaf(h[i], w2[j * 16 + i], acc);
    m[j] = acc;
  }
  P.lc = fminf(fmaxf(m[0], -2.0f), 2.5f);
  P.lm = fminf(fmaxf(m[1], -2.5f), 0.0f);
  P.lp = fminf(fmaxf(m[2], -4.0f), 4.0f);
  P.g = 0.999f * sigmoidf_(P.lc);
  P.s = sigmoidf_(P.lm);
  float f0 = fmaxf(p, 60.0f);
  float D = fminf(fmaxf(FS_F / f0, 2.0f), 735.0f);
  int Di = (int)floorf(D);
  P.fr = D - (float)Di;
  P.Di = Di;
  float mult = fminf(fmaxf(2.0f + 6.0f * (f0 - 60.0f) / 600.0f, 2.0f), 8.0f);
  float cutoff = fminf(2.0f * PI_F * f0 * mult / FS_F, PI_F * 0.9f);
  P.alpha = 1.0f - expf(-cutoff);
  float cpost = fminf(PI_F * sigmoidf_(P.lp), PI_F * 0.99f);
  P.alpha_p = 1.0f - expf(-cpost);
  return P;
}

// lane helpers (wave64)
__device__ inline float rl63(float v) {
  return __int_as_float(__builtin_amdgcn_readlane(__float_as_int(v), 63));
}
__device__ inline float rlv(float v, int l) {
  return __int_as_float(__builtin_amdgcn_readlane(__float_as_int(v), l));
}
__device__ inline float shr1(float v, float bnd) {
  return __int_as_float(__builtin_amdgcn_update_dpp(
      __float_as_int(bnd), __float_as_int(v), 0x138 /*wave_shr:1*/, 0xf, 0xf,
      false));
}

// Block barrier draining ONLY lgkmcnt (keeps global stores in flight).
__device__ inline void barrier_lgkm() {
  asm volatile("s_waitcnt lgkmcnt(0)\n\ts_barrier" ::: "memory");
}

__device__ inline void band_coef(int k, float& a1, float& a2, float& b0) {
  float fc = 80.0f * exp2f((float)k * (6.64385618977472436f / 23.0f));
  float w = 2.0f * PI_F * fc / FS_F;
  float r = expf(-PI_F * fc / (10.0f * FS_F));
  a1 = -2.0f * r * cosf(w);
  a2 = r * r;
  b0 = 1.0f - r;
}

// ---- on-the-fly preLP scan context (per thread registers) ----
struct SCtx {
  const float* exc_b;  // exc + b*NSAMP
  float scale, c;
  float m1, m2, m4, m8, m16, m32, c512, c2048, c8lane, cgk;
  float vrun;  // scan carry (preLP state at end of last processed tile)
  int s1;
  float* lws;  // 8 floats LDS
};

// Scan one 2048-sample tile at absolute start A = s1 + (seg<<11) (seg may be
// -1 for the state-only pre-roll). All 256 threads; 2 block barriers.
__device__ inline void scan_seg(SCtx& SC, float* xbuf, int seg, bool write,
                                int t) {
  const int lane = t & 63, wid = t >> 6;
  const int rel0 = seg << 11;
  const int A = SC.s1 + rel0;
  __syncthreads();  // protect lws reuse from previous tile
  const int g0 = A + 8 * t;
  float4 xa = make_float4(0.f, 0.f, 0.f, 0.f);
  float4 xb = make_float4(0.f, 0.f, 0.f, 0.f);
  if (g0 >= 0 && g0 + 3 < NSAMP) xa = *(const float4*)&SC.exc_b[g0];
  if (g0 + 4 >= 0 && g0 + 7 < NSAMP) xb = *(const float4*)&SC.exc_b[g0 + 4];
  const float c = SC.c, scale = SC.scale;
  float S = 0.0f;
  S = fmaf(c, S, scale * xa.x); S = fmaf(c, S, scale * xa.y);
  S = fmaf(c, S, scale * xa.z); S = fmaf(c, S, scale * xa.w);
  S = fmaf(c, S, scale * xb.x); S = fmaf(c, S, scale * xb.y);
  S = fmaf(c, S, scale * xb.z); S = fmaf(c, S, scale * xb.w);
  float Sw = S, u;
  u = __shfl_up(Sw, 1);  if (lane >= 1)  Sw = fmaf(SC.m1, u, Sw);
  u = __shfl_up(Sw, 2);  if (lane >= 2)  Sw = fmaf(SC.m2, u, Sw);
  u = __shfl_up(Sw, 4);  if (lane >= 4)  Sw = fmaf(SC.m4, u, Sw);
  u = __shfl_up(Sw, 8);  if (lane >= 8)  Sw = fmaf(SC.m8, u, Sw);
  u = __shfl_up(Sw, 16); if (lane >= 16) Sw = fmaf(SC.m16, u, Sw);
  u = __shfl_up(Sw, 32); if (lane >= 32) Sw = fmaf(SC.m32, u, Sw);
  if (lane == 63) SC.lws[wid] = Sw;
  __syncthreads();
  float a0 = SC.lws[0], a1w = SC.lws[1], a2w = SC.lws[2], a3w = SC.lws[3];
  float carry = (wid == 1)   ? a0
                : (wid == 2) ? fmaf(SC.c512, a0, a1w)
                : (wid == 3) ? fmaf(SC.c512, fmaf(SC.c512, a0, a1w), a2w)
                             : 0.0f;
  float Sprev = __shfl_up(Sw, 1);
  float Sex = (lane == 0) ? 0.0f : Sprev;
  Sex = fmaf(SC.c8lane, carry, Sex);
  float v = fmaf(SC.cgk, SC.vrun, Sex);
  float4 ya, yb;
  v = fmaf(c, v, scale * xa.x); ya.x = v;
  v = fmaf(c, v, scale * xa.y); ya.y = v;
  v = fmaf(c, v, scale * xa.z); ya.z = v;
  v = fmaf(c, v, scale * xa.w); ya.w = v;
  v = fmaf(c, v, scale * xb.x); yb.x = v;
  v = fmaf(c, v, scale * xb.y); yb.y = v;
  v = fmaf(c, v, scale * xb.z); yb.z = v;
  v = fmaf(c, v, scale * xb.w); yb.w = v;
  if (write) {
    int o = (rel0 + 8 * t) & 8191;  // 8-sample group never crosses the wrap
    *(float4*)&xbuf[o] = ya;
    *(float4*)&xbuf[o + 4] = yb;
  }
  float tS = fmaf(SC.c512, fmaf(SC.c512, fmaf(SC.c512, a0, a1w), a2w), a3w);
  SC.vrun = fmaf(SC.c2048, SC.vrun, tS);
}

// KS slice compute with x staged via scan_seg. Lean warm-up loops (no global
// stores, no bounds checks) for chunks entirely before n0; 3-deep x prefetch.
template <int KNUM>
__device__ void ks_slice2(SCtx& SC, float* __restrict__ yg, float* xbuf,
                          float* bnd, int t, int C, float c0w, float c1w,
                          float c2w, int s1, int n0, int end, int span,
                          int nseg) {
  const int lane = t & 63;
  const int wid = t >> 6;
  const int lq1 = (C - 1) - (KNUM - 1) * 64;
  const int W = n0 - s1;  // warm-up length (rel < W => no stores)

  if (KNUM <= 3) {
    float yp[KNUM], xC[KNUM], xN[KNUM], xN2[KNUM];
    float p1 = 0.f, p2 = 0.f;
    int rel = 0;
#pragma unroll
    for (int k = 0; k < KNUM; ++k) {
      yp[k] = 0.f; xC[k] = 0.f; xN[k] = 0.f; xN2[k] = 0.f;
    }
    for (int s = 0; s < nseg; ++s) {
      barrier_lgkm();
      if (wid == 0) {
        if (s == 0) {
#pragma unroll
          for (int k = 0; k < KNUM; ++k) {
            int i = lane + (k << 6);
            xC[k] = xbuf[i];
            xN[k] = xbuf[C + i];
            xN2[k] = xbuf[2 * C + i];
          }
        }
        int fence = (s + 1) << 11;
        if (fence > span) fence = span;
        // ---- lean warm-up chunks: pure recurrence, no stores ----
        while (rel + C <= W && rel < fence) {
          float b2v[KNUM], b3v[KNUM];
#pragma unroll
          for (int k = 0; k < KNUM; ++k)
            b2v[k] = shr1(yp[k], (k == 0) ? p1 : rl63(yp[k - 1]));
#pragma unroll
          for (int k = 0; k < KNUM; ++k)
            b3v[k] = shr1(b2v[k], (k == 0) ? p2 : rlv(yp[k - 1], 62));
          float p1n = rlv(yp[KNUM - 1], lq1);
          float p2n = rlv(b2v[KNUM - 1], lq1);
#pragma unroll
          for (int k = 0; k < KNUM; ++k)
            yp[k] = fmaf(c0w, yp[k],
                         fmaf(c2w, b3v[k], fmaf(c1w, b2v[k], xC[k])));
          p1 = p1n;
          p2 = p2n;
#pragma unroll
          for (int k = 0; k < KNUM; ++k) {
            xC[k] = xN[k];
            xN[k] = xN2[k];
            xN2[k] = xbuf[(rel + 3 * C + lane + (k << 6)) & 8191];
          }
          rel += C;
        }
        // ---- full chunks: stores with guards ----
        while (rel < fence) {
          float b2v[KNUM], b3v[KNUM];
#pragma unroll
          for (int k = 0; k < KNUM; ++k)
            b2v[k] = shr1(yp[k], (k == 0) ? p1 : rl63(yp[k - 1]));
#pragma unroll
          for (int k = 0; k < KNUM; ++k)
            b3v[k] = shr1(b2v[k], (k == 0) ? p2 : rlv(yp[k - 1], 62));
          float p1n = rlv(yp[KNUM - 1], lq1);
          float p2n = rlv(b2v[KNUM - 1], lq1);
#pragma unroll
          for (int k = 0; k < KNUM; ++k)
            yp[k] = fmaf(c0w, yp[k],
                         fmaf(c2w, b3v[k], fmaf(c1w, b2v[k], xC[k])));
          p1 = p1n;
          p2 = p2n;
#pragma unroll
          for (int k = 0; k < KNUM; ++k) {
            int i = lane + (k << 6);
            int n = s1 + rel + i;
            bool okl = (k < KNUM - 1) || (lane <= lq1);
            if (okl && n >= n0 && n < end) yg[n] = yp[k];
          }
#pragma unroll
          for (int k = 0; k < KNUM; ++k) {
            xC[k] = xN[k];
            xN[k] = xN2[k];
            xN2[k] = xbuf[(rel + 3 * C + lane + (k << 6)) & 8191];
          }
          rel += C;
        }
      }
      barrier_lgkm();
      int ls = s + 3;
      if (ls < nseg) scan_seg(SC, xbuf, ls, true, t);
    }
  } else {
    constexpr int SPW = (KNUM + 3) / 4;
    const int kbase = wid * SPW;
    float yp[SPW], xC[SPW], xN[SPW], xN2[SPW];
    int rel = 0, par = 0;
#pragma unroll
    for (int kk = 0; kk < SPW; ++kk) {
      yp[kk] = 0.f; xC[kk] = 0.f; xN[kk] = 0.f; xN2[kk] = 0.f;
    }
    for (int s = 0; s < nseg; ++s) {
      barrier_lgkm();
      if (s == 0) {
#pragma unroll
        for (int kk = 0; kk < SPW; ++kk) {
          int k = kbase + kk;
          if (k < KNUM) {
            int i = lane + (k << 6);
            xC[kk] = xbuf[i];
            xN[kk] = xbuf[C + i];
            xN2[kk] = xbuf[2 * C + i];
          }
        }
      }
      int fence = (s + 1) << 11;
      if (fence > span) fence = span;
      while (rel < fence) {
        const bool lean = (rel + C <= W);
        barrier_lgkm();  // publishes previous iteration's bnd writes
        const int rb = par << 5, wb = rb ^ 32;
        float pbA = 0.f, pbB = 0.f;
        if (kbase == 0) {
          pbA = bnd[rb + 24];
          pbB = bnd[rb + 25];
        } else if (kbase < KNUM) {
          pbA = bnd[rb + (kbase - 1) * 2];
          pbB = bnd[rb + (kbase - 1) * 2 + 1];
        }
        float b2v[SPW], b3v[SPW];
#pragma unroll
        for (int kk = 0; kk < SPW; ++kk) {
          int k = kbase + kk;
          if (k < KNUM)
            b2v[kk] = shr1(yp[kk], (kk == 0) ? pbA : rl63(yp[kk - 1]));
        }
#pragma unroll
        for (int kk = 0; kk < SPW; ++kk) {
          int k = kbase + kk;
          if (k < KNUM)
            b3v[kk] = shr1(b2v[kk], (kk == 0) ? pbB : rlv(yp[kk - 1], 62));
        }
        float p1n = 0.f, p2n = 0.f;
        const bool ownLast = (KNUM - 1 >= kbase) && (KNUM - 1 < kbase + SPW);
        if (ownLast) {
          p1n = rlv(yp[KNUM - 1 - kbase], lq1);
          p2n = rlv(b2v[KNUM - 1 - kbase], lq1);
        }
#pragma unroll
        for (int kk = 0; kk < SPW; ++kk) {
          int k = kbase + kk;
          if (k < KNUM)
            yp[kk] = fmaf(c0w, yp[kk],
                          fmaf(c2w, b3v[kk], fmaf(c1w, b2v[kk], xC[kk])));
        }
        if (!lean) {
#pragma unroll
          for (int kk = 0; kk < SPW; ++kk) {
            int k = kbase + kk;
            if (k < KNUM) {
              int i = lane + (k << 6);
              int n = s1 + rel + i;
              bool okl = (k < KNUM - 1) || (lane <= lq1);
              if (okl && n >= n0 && n < end) yg[n] = yp[kk];
            }
          }
        }
#pragma unroll
        for (int kk = 0; kk < SPW; ++kk) {
          int k = kbase + kk;
          if (k < KNUM) {
            float h63 = rlv(yp[kk], 63);
            float h62 = rlv(yp[kk], 62);
            if (lane == 0) {
              bnd[wb + k * 2] = h63;
              bnd[wb + k * 2 + 1] = h62;
            }
          }
        }
        if (ownLast && lane == 0) {
          bnd[wb + 24] = p1n;
          bnd[wb + 25] = p2n;
        }
#pragma unroll
        for (int kk = 0; kk < SPW; ++kk) {
          int k = kbase + kk;
          if (k < KNUM) {
            xC[kk] = xN[kk];
            xN[kk] = xN2[kk];
            xN2[kk] = xbuf[(rel + 3 * C + lane + (k << 6)) & 8191];
          }
        }
        rel += C;
        par ^= 1;
      }
      barrier_lgkm();
      int ls = s + 3;
      if (ls < nseg) scan_seg(SC, xbuf, ls, true, t);
    }
  }
}

// ---------------- k1: fused preLP + KS ----------------
__global__ void __launch_bounds__(256) ks_fused_kernel(
    const float* __restrict__ exc, const float* __restrict__ pitch,
    const float* __restrict__ w1, const float* __restrict__ b1,
    const float* __restrict__ w2, const float* __restrict__ b2,
    const float* __restrict__ eg, float* __restrict__ buf1,
    float* __restrict__ out_scalars) {
  const int blk = blockIdx.x;
  const int b = blk >> 5, q = blk & 31;
  const int t = threadIdx.x;
  __shared__ __align__(16) float lds[8192 + 64 + 8];
  float* xbuf = lds;
  float* bnd = lds + 8192;
  float* lws = lds + 8256;

  BParams P = compute_params(b, pitch, w1, b1, w2, b2);
  if (blk == 0 && t < 64) {
    int bb = (t < 8) ? t : 0;
    BParams Q = compute_params(bb, pitch, w1, b1, w2, b2);
    float slc = 0.f, slm = 0.f, slp = 0.f;
    for (int i = 0; i < 8; ++i) {
      slc += rlv(Q.lc, i);
      slm += rlv(Q.lm, i);
      slp += rlv(Q.lp, i);
    }
    if (t == 0) {
      out_scalars[0] = slc / 8.0f;
      out_scalars[1] = slm / 8.0f;
      out_scalars[2] = slp / 8.0f;
    }
  }

  const int C = P.Di;
  const int n0 = q << 10;
  float lg = -logf(P.g);
  int Wp = (int)ceilf(10.5f / fmaxf(lg, 1e-6f));
  if (Wp > 96) Wp = 96;
  if (Wp < 4) Wp = 4;
  int W = Wp * C;
  if (W > n0) W = n0;
  W = (W + 3) & ~3;
  const int s1 = n0 - W;
  const int span = W + T1;
  const int end = n0 + T1;
  const int nseg = (span + 2047) >> 11;
  float* yg = buf1 + (size_t)b * NSAMP;

  SCtx SC;
  SC.exc_b = exc + (size_t)b * NSAMP;
  SC.c = 1.0f - P.alpha;
  SC.scale = eg[0] * P.alpha;
  {
    float c = SC.c;
    float c2v = c * c, c4 = c2v * c2v, c8 = c4 * c4;
    SC.m1 = c8;
    SC.m2 = SC.m1 * SC.m1;
    SC.m4 = SC.m2 * SC.m2;
    SC.m8 = SC.m4 * SC.m4;
    SC.m16 = SC.m8 * SC.m8;
    SC.m32 = SC.m16 * SC.m16;
    SC.c512 = SC.m32 * SC.m32;
    float c1024 = SC.c512 * SC.c512;
    SC.c2048 = c1024 * c1024;
    float l2c = log2f(c);
    SC.c8lane = exp2f((float)(8 * (t & 63)) * l2c);
    SC.cgk = exp2f((float)(8 * t) * l2c);
  }
  SC.vrun = 0.0f;
  SC.s1 = s1;
  SC.lws = lws;

  if (s1 > 0) scan_seg(SC, xbuf, -1, false, t);  // state-only pre-roll
  scan_seg(SC, xbuf, 0, true, t);                // preamble segments 0..2
  scan_seg(SC, xbuf, 1, true, t);
  scan_seg(SC, xbuf, 2, true, t);
  if (t < 64) bnd[t] = 0.0f;

  const float c0w = P.g * (1.0f - P.s) * (1.0f - P.fr);
  const float c1w = P.g * ((1.0f - P.s) * P.fr + P.s * (1.0f - P.fr));
  const float c2w = P.g * P.s * P.fr;
  switch ((C + 63) >> 6) {
    case 2:  ks_slice2<2>(SC, yg, xbuf, bnd, t, C, c0w, c1w, c2w, s1, n0, end, span, nseg); break;
    case 3:  ks_slice2<3>(SC, yg, xbuf, bnd, t, C, c0w, c1w, c2w, s1, n0, end, span, nseg); break;
    case 4:  ks_slice2<4>(SC, yg, xbuf, bnd, t, C, c0w, c1w, c2w, s1, n0, end, span, nseg); break;
    case 5:  ks_slice2<5>(SC, yg, xbuf, bnd, t, C, c0w, c1w, c2w, s1, n0, end, span, nseg); break;
    case 6:  ks_slice2<6>(SC, yg, xbuf, bnd, t, C, c0w, c1w, c2w, s1, n0, end, span, nseg); break;
    case 7:  ks_slice2<7>(SC, yg, xbuf, bnd, t, C, c0w, c1w, c2w, s1, n0, end, span, nseg); break;
    case 8:  ks_slice2<8>(SC, yg, xbuf, bnd, t, C, c0w, c1w, c2w, s1, n0, end, span, nseg); break;
    case 9:  ks_slice2<9>(SC, yg, xbuf, bnd, t, C, c0w, c1w, c2w, s1, n0, end, span, nseg); break;
    case 10: ks_slice2<10>(SC, yg, xbuf, bnd, t, C, c0w, c1w, c2w, s1, n0, end, span, nseg); break;
    case 11: ks_slice2<11>(SC, yg, xbuf, bnd, t, C, c0w, c1w, c2w, s1, n0, end, span, nseg); break;
    default: ks_slice2<12>(SC, yg, xbuf, bnd, t, C, c0w, c1w, c2w, s1, n0, end, span, nseg); break;
  }
}

// One-pole scan over [s2, s2+nt*2048) from global into LDS sl[n-s2] (body).
__device__ inline void lpc_lds(const float* __restrict__ xg,
                               float* __restrict__ sl, int s2, int nt,
                               float scale, float c, int t, float* lws) {
  const int lane = t & 63, wid = t >> 6;
  float c2v = c * c, c4 = c2v * c2v, c8 = c4 * c4;
  float m1 = c8, m2 = m1 * m1, m4 = m2 * m2, m8 = m4 * m4, m16 = m8 * m8,
        m32 = m16 * m16;
  float c512 = m32 * m32;
  float c2048 = c512 * c512;
  c2048 *= c2048;
  float l2c = log2f(c);
  float c8lane = exp2f((float)(8 * lane) * l2c);
  float cgk = exp2f((float)(8 * t) * l2c);
  float vrun = 0.0f;
  for (int tile = 0; tile < nt; ++tile) {
    __syncthreads();
    int g0 = s2 + (tile << 11) + 8 * t;
    float4 xa = make_float4(0.f, 0.f, 0.f, 0.f);
    float4 xb = make_float4(0.f, 0.f, 0.f, 0.f);
    if (g0 + 3 < NSAMP) xa = *(const float4*)&xg[g0];
    if (g0 + 7 < NSAMP) xb = *(const float4*)&xg[g0 + 4];
    float S = 0.0f;
    S = fmaf(c, S, scale * xa.x); S = fmaf(c, S, scale * xa.y);
    S = fmaf(c, S, scale * xa.z); S = fmaf(c, S, scale * xa.w);
    S = fmaf(c, S, scale * xb.x); S = fmaf(c, S, scale * xb.y);
    S = fmaf(c, S, scale * xb.z); S = fmaf(c, S, scale * xb.w);
    float Sw = S, u;
    u = __shfl_up(Sw, 1);  if (lane >= 1)  Sw = fmaf(m1, u, Sw);
    u = __shfl_up(Sw, 2);  if (lane >= 2)  Sw = fmaf(m2, u, Sw);
    u = __shfl_up(Sw, 4);  if (lane >= 4)  Sw = fmaf(m4, u, Sw);
    u = __shfl_up(Sw, 8);  if (lane >= 8)  Sw = fmaf(m8, u, Sw);
    u = __shfl_up(Sw, 16); if (lane >= 16) Sw = fmaf(m16, u, Sw);
    u = __shfl_up(Sw, 32); if (lane >= 32) Sw = fmaf(m32, u, Sw);
    if (lane == 63) lws[wid] = Sw;
    __syncthreads();
    float a0 = lws[0], a1w = lws[1], a2w = lws[2], a3w = lws[3];
    float carry = (wid == 1)   ? a0
                  : (wid == 2) ? fmaf(c512, a0, a1w)
                  : (wid == 3) ? fmaf(c512, fmaf(c512, a0, a1w), a2w)
                               : 0.0f;
    float Sprev = __shfl_up(Sw, 1);
    float Sex = (lane == 0) ? 0.0f : Sprev;
    Sex = fmaf(c8lane, carry, Sex);
    float v = fmaf(cgk, vrun, Sex);
    int o = g0 - s2;
    float4 ya, yb;
    v = fmaf(c, v, scale * xa.x); ya.x = v;
    v = fmaf(c, v, scale * xa.y); ya.y = v;
    v = fmaf(c, v, scale * xa.z); ya.z = v;
    v = fmaf(c, v, scale * xa.w); ya.w = v;
    v = fmaf(c, v, scale * xb.x); yb.x = v;
    v = fmaf(c, v, scale * xb.y); yb.y = v;
    v = fmaf(c, v, scale * xb.z); yb.z = v;
    v = fmaf(c, v, scale * xb.w); yb.w = v;
    *(float4*)&sl[o] = ya;
    *(float4*)&sl[o + 4] = yb;
    float tS = fmaf(c512, fmaf(c512, fmaf(c512, a0, a1w), a2w), a3w);
    vrun = fmaf(c2048, vrun, tS);
  }
}

// ---------------- k2: postLP (LDS) + 24-band body (R7, proven) ----------------
__global__ void __launch_bounds__(256, 1) body_kernel(
    const float* __restrict__ pitch, const float* __restrict__ w1,
    const float* __restrict__ b1, const float* __restrict__ w2,
    const float* __restrict__ b2, const float* __restrict__ gains,
    const float* __restrict__ buf1, float* __restrict__ out) {
  const int blk = blockIdx.x;
  const int b = blk >> 3, q = blk & 7;
  const int t = threadIdx.x;
  const int lane = t & 63, wid = t >> 6;
  __shared__ __align__(16) float sl[10240];
  __shared__ float lws[8];
  __shared__ float lc0[4][8], lc1[4][8];

  BParams P = compute_params(b, pitch, w1, b1, w2, b2);
  const int n0 = q * T2;
  const int base = n0 - 4096;
  int s2 = base - 256;
  if (s2 < 0) s2 = 0;
  const int end = n0 + T2;
  const int nt = (end - s2 + 2047) >> 11;  // <= 5

  lpc_lds(buf1 + (size_t)b * NSAMP, sl, s2, nt, P.alpha_p, 1.0f - P.alpha_p, t,
          lws);
  __syncthreads();

  const int tb = base + 32 * t;
  float4 acc[8];
#pragma unroll
  for (int i = 0; i < 8; ++i) acc[i] = make_float4(0.f, 0.f, 0.f, 0.f);

  for (int g = 0; g < 3; ++g) {
    float A1[8], A2[8], B0[8], GN[8];
#pragma unroll
    for (int j = 0; j < 8; ++j) {
      int k = g * 8 + j;
      band_coef(k, A1[j], A2[j], B0[j]);
      GN[j] = gains[k];
    }
    float cv0[8], cv1[8];
#pragma unroll
    for (int j = 0; j < 8; ++j) cv0[j] = cv1[j] = 0.f;
    for (int i = 0; i < 8; ++i) {
      int n = tb + 4 * i;
      float4 xv = make_float4(0.f, 0.f, 0.f, 0.f);
      if (n >= 0) xv = *(const float4*)&sl[n - s2];
#pragma unroll
      for (int e = 0; e < 4; ++e) {
        float xi = e == 0 ? xv.x : e == 1 ? xv.y : e == 2 ? xv.z : xv.w;
#pragma unroll
        for (int j = 0; j < 8; ++j) {
          float nc = fmaf(B0[j], xi, -fmaf(A1[j], cv0[j], A2[j] * cv1[j]));
          cv1[j] = cv0[j];
          cv0[j] = nc;
        }
      }
    }
    float Q00[8], Q01[8], Q10[8], Q11[8];
#pragma unroll
    for (int j = 0; j < 8; ++j) {
      Q00[j] = -A1[j]; Q01[j] = -A2[j]; Q10[j] = 1.f; Q11[j] = 0.f;
    }
    for (int sq = 0; sq < 5; ++sq) {
#pragma unroll
      for (int j = 0; j < 8; ++j) {
        float n00 = fmaf(Q00[j], Q00[j], Q01[j] * Q10[j]);
        float n01 = fmaf(Q00[j], Q01[j], Q01[j] * Q11[j]);
        float n10 = fmaf(Q10[j], Q00[j], Q11[j] * Q10[j]);
        float n11 = fmaf(Q10[j], Q01[j], Q11[j] * Q11[j]);
        Q00[j] = n00; Q01[j] = n01; Q10[j] = n10; Q11[j] = n11;
      }
    }
    float T00[8], T01[8], T10[8], T11[8];
#pragma unroll
    for (int j = 0; j < 8; ++j) {
      T00[j] = Q00[j]; T01[j] = Q01[j]; T10[j] = Q10[j]; T11[j] = Q11[j];
    }
    for (int off = 1; off <= 32; off <<= 1) {
#pragma unroll
      for (int j = 0; j < 8; ++j) {
        float u0 = __shfl_up(cv0[j], off);
        float u1 = __shfl_up(cv1[j], off);
        if (lane >= off) {
          float nc0 = fmaf(Q00[j], u0, fmaf(Q01[j], u1, cv0[j]));
          float nc1 = fmaf(Q10[j], u0, fmaf(Q11[j], u1, cv1[j]));
          cv0[j] = nc0;
          cv1[j] = nc1;
        }
        float n00 = fmaf(Q00[j], Q00[j], Q01[j] * Q10[j]);
        float n01 = fmaf(Q00[j], Q01[j], Q01[j] * Q11[j]);
        float n10 = fmaf(Q10[j], Q00[j], Q11[j] * Q10[j]);
        float n11 = fmaf(Q10[j], Q01[j], Q11[j] * Q11[j]);
        Q00[j] = n00; Q01[j] = n01; Q10[j] = n10; Q11[j] = n11;
      }
    }
    __syncthreads();
    if (lane == 63) {
#pragma unroll
      for (int j = 0; j < 8; ++j) {
        lc0[wid][j] = cv0[j];
        lc1[wid][j] = cv1[j];
      }
    }
    __syncthreads();
    float car0[8], car1[8];
#pragma unroll
    for (int j = 0; j < 8; ++j) car0[j] = car1[j] = 0.f;
    for (int v = 0; v < wid; ++v) {
#pragma unroll
      for (int j = 0; j < 8; ++j) {
        float n0c = fmaf(Q00[j], car0[j], fmaf(Q01[j], car1[j], lc0[v][j]));
        float n1c = fmaf(Q10[j], car0[j], fmaf(Q11[j], car1[j], lc1[v][j]));
        car0[j] = n0c;
        car1[j] = n1c;
      }
    }
    float R00[8], R01[8], R10[8], R11[8];
#pragma unroll
    for (int j = 0; j < 8; ++j) {
      R00[j] = 1.f; R01[j] = 0.f; R10[j] = 0.f; R11[j] = 1.f;
    }
    for (int bit = 0; bit < 6; ++bit) {
      bool on = (lane >> bit) & 1;
#pragma unroll
      for (int j = 0; j < 8; ++j) {
        if (on) {
          float n00 = fmaf(T00[j], R00[j], T01[j] * R10[j]);
          float n01 = fmaf(T00[j], R01[j], T01[j] * R11[j]);
          float n10 = fmaf(T10[j], R00[j], T11[j] * R10[j]);
          float n11 = fmaf(T10[j], R01[j], T11[j] * R11[j]);
          R00[j] = n00; R01[j] = n01; R10[j] = n10; R11[j] = n11;
        }
        float s00 = fmaf(T00[j], T00[j], T01[j] * T10[j]);
        float s01 = fmaf(T00[j], T01[j], T01[j] * T11[j]);
        float s10 = fmaf(T10[j], T00[j], T11[j] * T10[j]);
        float s11 = fmaf(T10[j], T01[j], T11[j] * T11[j]);
        T00[j] = s00; T01[j] = s01; T10[j] = s10; T11[j] = s11;
      }
    }
    float y1[8], y2[8];
#pragma unroll
    for (int j = 0; j < 8; ++j) {
      float e0 = __shfl_up(cv0[j], 1);
      float e1 = __shfl_up(cv1[j], 1);
      if (lane == 0) { e0 = 0.f; e1 = 0.f; }
      y1[j] = fmaf(R00[j], car0[j], fmaf(R01[j], car1[j], e0));
      y2[j] = fmaf(R10[j], car0[j], fmaf(R11[j], car1[j], e1));
    }
    if (t >= 128) {
      for (int i = 0; i < 8; ++i) {
        float4 xv = *(const float4*)&sl[tb - s2 + 4 * i];
        float4 ov = acc[i];
#pragma unroll
        for (int e = 0; e < 4; ++e) {
          float xi = e == 0 ? xv.x : e == 1 ? xv.y : e == 2 ? xv.z : xv.w;
          float a = 0.f;
#pragma unroll
          for (int j = 0; j < 8; ++j) {
            float yv = fmaf(B0[j], xi, -fmaf(A1[j], y1[j], A2[j] * y2[j]));
            y2[j] = y1[j];
            y1[j] = yv;
            a = fmaf(GN[j], yv, a);
          }
          if (e == 0) ov.x += a;
          else if (e == 1) ov.y += a;
          else if (e == 2) ov.z += a;
          else ov.w += a;
        }
        acc[i] = ov;
      }
    }
  }
  if (t >= 128) {
    float* outb = out + (size_t)b * NSAMP;
#pragma unroll
    for (int i = 0; i < 8; ++i) *(float4*)&outb[tb + 4 * i] = acc[i];
  }
}

extern "C" void kernel_launch(void* const* d_in, const int* in_sizes, int n_in,
                              void* d_out, int out_size, void* d_ws, size_t ws_size,
                              hipStream_t stream) {
  const float* exc = (const float*)d_in[0];
  const float* pitch = (const float*)d_in[1];
  const float* w1 = (const float*)d_in[2];
  const float* b1 = (const float*)d_in[3];
  const float* w2 = (const float*)d_in[4];
  const float* b2 = (const float*)d_in[5];
  const float* eg = (const float*)d_in[6];
  const float* bg = (const float*)d_in[7];
  float* out = (float*)d_out;
  float* buf1 = (float*)d_ws;  // 8*NSAMP floats (KS output)

  hipLaunchKernelGGL(ks_fused_kernel, dim3(256), dim3(256), 0, stream, exc,
                     pitch, w1, b1, w2, b2, eg, buf1, out + 8 * NSAMP);
  hipLaunchKernelGGL(body_kernel, dim3(64), dim3(256), 0, stream, pitch, w1,
                     b1, w2, b2, bg, buf1, out);
}

// Round 12
// 134.682 us; speedup vs baseline: 1.4770x; 1.0397x over previous
//
#include <hip/hip_runtime.h>
#include <math.h>

#define NSAMP 32768
#define FS_F 44100.0f
#define PI_F 3.14159265358979323846f
#define T1 1024  // KS slice length (32 slices/batch)
#define FLAG_MAGIC 0x5A5A5A5A

struct BParams {
  float alpha, alpha_p;
  float fr, g, s;
  int Di;
  float lc, lm, lp;
};

__device__ inline float sigmoidf_(float x) { return 1.0f / (1.0f + expf(-x)); }

__device__ inline BParams compute_params(int b, const float* __restrict__ pitch,
                                         const float* __restrict__ w1,
                                         const float* __restrict__ b1,
                                         const float* __restrict__ w2,
                                         const float* __restrict__ b2) {
  BParams P;
  float p = pitch[b];
  float h[16];
#pragma unroll
  for (int i = 0; i < 16; ++i) {
    float v = fmaf(p, w1[i], b1[i]);
    h[i] = v > 0.0f ? v : 0.0f;
  }
  float m[3];
#pragma unroll
  for (int j = 0; j < 3; ++j) {
    float acc = b2[j];
#pragma unroll
    for (int i = 0; i < 16; ++i) acc = fmaf(h[i], w2[j * 16 + i], acc);
    m[j] = acc;
  }
  P.lc = fminf(fmaxf(m[0], -2.0f), 2.5f);
  P.lm = fminf(fmaxf(m[1], -2.5f), 0.0f);
  P.lp = fminf(fmaxf(m[2], -4.0f), 4.0f);
  P.g = 0.999f * sigmoidf_(P.lc);
  P.s = sigmoidf_(P.lm);
  float f0 = fmaxf(p, 60.0f);
  float D = fminf(fmaxf(FS_F / f0, 2.0f), 735.0f);
  int Di = (int)floorf(D);
  P.fr = D - (float)Di;
  P.Di = Di;
  float mult = fminf(fmaxf(2.0f + 6.0f * (f0 - 60.0f) / 600.0f, 2.0f), 8.0f);
  float cutoff = fminf(2.0f * PI_F * f0 * mult / FS_F, PI_F * 0.9f);
  P.alpha = 1.0f - expf(-cutoff);
  float cpost = fminf(PI_F * sigmoidf_(P.lp), PI_F * 0.99f);
  P.alpha_p = 1.0f - expf(-cpost);
  return P;
}

// lane helpers (wave64)
__device__ inline float rl63(float v) {
  return __int_as_float(__builtin_amdgcn_readlane(__float_as_int(v), 63));
}
__device__ inline float rlv(float v, int l) {
  return __int_as_float(__builtin_amdgcn_readlane(__float_as_int(v), l));
}
__device__ inline float shr1(float v, float bnd) {
  return __int_as_float(__builtin_amdgcn_update_dpp(
      __float_as_int(bnd), __float_as_int(v), 0x138 /*wave_shr:1*/, 0xf, 0xf,
      false));
}

// Block barrier draining ONLY lgkmcnt (keeps global stores in flight).
__device__ inline void barrier_lgkm() {
  asm volatile("s_waitcnt lgkmcnt(0)\n\ts_barrier" ::: "memory");
}

__device__ inline void band_coef(int k, float& a1, float& a2, float& b0) {
  float fc = 80.0f * exp2f((float)k * (6.64385618977472436f / 23.0f));
  float w = 2.0f * PI_F * fc / FS_F;
  float r = expf(-PI_F * fc / (10.0f * FS_F));
  a1 = -2.0f * r * cosf(w);
  a2 = r * r;
  b0 = 1.0f - r;
}

// ---- on-the-fly preLP scan context ----
struct SCtx {
  const float* exc_b;
  float scale, c;
  float m1, m2, m4, m8, m16, m32, c512, c2048, c8lane, cgk;
  float vrun;
  int s1;
  float* lws;
};

__device__ inline void scan_seg(SCtx& SC, float* xbuf, int seg, bool write,
                                int t) {
  const int lane = t & 63, wid = t >> 6;
  const int rel0 = seg << 11;
  const int A = SC.s1 + rel0;
  __syncthreads();
  const int g0 = A + 8 * t;
  float4 xa = make_float4(0.f, 0.f, 0.f, 0.f);
  float4 xb = make_float4(0.f, 0.f, 0.f, 0.f);
  if (g0 >= 0 && g0 + 3 < NSAMP) xa = *(const float4*)&SC.exc_b[g0];
  if (g0 + 4 >= 0 && g0 + 7 < NSAMP) xb = *(const float4*)&SC.exc_b[g0 + 4];
  const float c = SC.c, scale = SC.scale;
  float S = 0.0f;
  S = fmaf(c, S, scale * xa.x); S = fmaf(c, S, scale * xa.y);
  S = fmaf(c, S, scale * xa.z); S = fmaf(c, S, scale * xa.w);
  S = fmaf(c, S, scale * xb.x); S = fmaf(c, S, scale * xb.y);
  S = fmaf(c, S, scale * xb.z); S = fmaf(c, S, scale * xb.w);
  float Sw = S, u;
  u = __shfl_up(Sw, 1);  if (lane >= 1)  Sw = fmaf(SC.m1, u, Sw);
  u = __shfl_up(Sw, 2);  if (lane >= 2)  Sw = fmaf(SC.m2, u, Sw);
  u = __shfl_up(Sw, 4);  if (lane >= 4)  Sw = fmaf(SC.m4, u, Sw);
  u = __shfl_up(Sw, 8);  if (lane >= 8)  Sw = fmaf(SC.m8, u, Sw);
  u = __shfl_up(Sw, 16); if (lane >= 16) Sw = fmaf(SC.m16, u, Sw);
  u = __shfl_up(Sw, 32); if (lane >= 32) Sw = fmaf(SC.m32, u, Sw);
  if (lane == 63) SC.lws[wid] = Sw;
  __syncthreads();
  float a0 = SC.lws[0], a1w = SC.lws[1], a2w = SC.lws[2], a3w = SC.lws[3];
  float carry = (wid == 1)   ? a0
                : (wid == 2) ? fmaf(SC.c512, a0, a1w)
                : (wid == 3) ? fmaf(SC.c512, fmaf(SC.c512, a0, a1w), a2w)
                             : 0.0f;
  float Sprev = __shfl_up(Sw, 1);
  float Sex = (lane == 0) ? 0.0f : Sprev;
  Sex = fmaf(SC.c8lane, carry, Sex);
  float v = fmaf(SC.cgk, SC.vrun, Sex);
  float4 ya, yb;
  v = fmaf(c, v, scale * xa.x); ya.x = v;
  v = fmaf(c, v, scale * xa.y); ya.y = v;
  v = fmaf(c, v, scale * xa.z); ya.z = v;
  v = fmaf(c, v, scale * xa.w); ya.w = v;
  v = fmaf(c, v, scale * xb.x); yb.x = v;
  v = fmaf(c, v, scale * xb.y); yb.y = v;
  v = fmaf(c, v, scale * xb.z); yb.z = v;
  v = fmaf(c, v, scale * xb.w); yb.w = v;
  if (write) {
    int o = (rel0 + 8 * t) & 8191;
    *(float4*)&xbuf[o] = ya;
    *(float4*)&xbuf[o + 4] = yb;
  }
  float tS = fmaf(SC.c512, fmaf(SC.c512, fmaf(SC.c512, a0, a1w), a2w), a3w);
  SC.vrun = fmaf(SC.c2048, SC.vrun, tS);
}

// KS slice compute (R11, proven): lean warm-up + full loops, 3-deep prefetch.
template <int KNUM>
__device__ void ks_slice2(SCtx& SC, float* __restrict__ yg, float* xbuf,
                          float* bnd, int t, int C, float c0w, float c1w,
                          float c2w, int s1, int n0, int end, int span,
                          int nseg) {
  const int lane = t & 63;
  const int wid = t >> 6;
  const int lq1 = (C - 1) - (KNUM - 1) * 64;
  const int W = n0 - s1;

  if (KNUM <= 3) {
    float yp[KNUM], xC[KNUM], xN[KNUM], xN2[KNUM];
    float p1 = 0.f, p2 = 0.f;
    int rel = 0;
#pragma unroll
    for (int k = 0; k < KNUM; ++k) {
      yp[k] = 0.f; xC[k] = 0.f; xN[k] = 0.f; xN2[k] = 0.f;
    }
    for (int s = 0; s < nseg; ++s) {
      barrier_lgkm();
      if (wid == 0) {
        if (s == 0) {
#pragma unroll
          for (int k = 0; k < KNUM; ++k) {
            int i = lane + (k << 6);
            xC[k] = xbuf[i];
            xN[k] = xbuf[C + i];
            xN2[k] = xbuf[2 * C + i];
          }
        }
        int fence = (s + 1) << 11;
        if (fence > span) fence = span;
        while (rel + C <= W && rel < fence) {
          float b2v[KNUM], b3v[KNUM];
#pragma unroll
          for (int k = 0; k < KNUM; ++k)
            b2v[k] = shr1(yp[k], (k == 0) ? p1 : rl63(yp[k - 1]));
#pragma unroll
          for (int k = 0; k < KNUM; ++k)
            b3v[k] = shr1(b2v[k], (k == 0) ? p2 : rlv(yp[k - 1], 62));
          float p1n = rlv(yp[KNUM - 1], lq1);
          float p2n = rlv(b2v[KNUM - 1], lq1);
#pragma unroll
          for (int k = 0; k < KNUM; ++k)
            yp[k] = fmaf(c0w, yp[k],
                         fmaf(c2w, b3v[k], fmaf(c1w, b2v[k], xC[k])));
          p1 = p1n;
          p2 = p2n;
#pragma unroll
          for (int k = 0; k < KNUM; ++k) {
            xC[k] = xN[k];
            xN[k] = xN2[k];
            xN2[k] = xbuf[(rel + 3 * C + lane + (k << 6)) & 8191];
          }
          rel += C;
        }
        while (rel < fence) {
          float b2v[KNUM], b3v[KNUM];
#pragma unroll
          for (int k = 0; k < KNUM; ++k)
            b2v[k] = shr1(yp[k], (k == 0) ? p1 : rl63(yp[k - 1]));
#pragma unroll
          for (int k = 0; k < KNUM; ++k)
            b3v[k] = shr1(b2v[k], (k == 0) ? p2 : rlv(yp[k - 1], 62));
          float p1n = rlv(yp[KNUM - 1], lq1);
          float p2n = rlv(b2v[KNUM - 1], lq1);
#pragma unroll
          for (int k = 0; k < KNUM; ++k)
            yp[k] = fmaf(c0w, yp[k],
                         fmaf(c2w, b3v[k], fmaf(c1w, b2v[k], xC[k])));
          p1 = p1n;
          p2 = p2n;
#pragma unroll
          for (int k = 0; k < KNUM; ++k) {
            int i = lane + (k << 6);
            int n = s1 + rel + i;
            bool okl = (k < KNUM - 1) || (lane <= lq1);
            if (okl && n >= n0 && n < end) yg[n] = yp[k];
          }
#pragma unroll
          for (int k = 0; k < KNUM; ++k) {
            xC[k] = xN[k];
            xN[k] = xN2[k];
            xN2[k] = xbuf[(rel + 3 * C + lane + (k << 6)) & 8191];
          }
          rel += C;
        }
      }
      barrier_lgkm();
      int ls = s + 3;
      if (ls < nseg) scan_seg(SC, xbuf, ls, true, t);
    }
  } else {
    constexpr int SPW = (KNUM + 3) / 4;
    const int kbase = wid * SPW;
    float yp[SPW], xC[SPW], xN[SPW], xN2[SPW];
    int rel = 0, par = 0;
#pragma unroll
    for (int kk = 0; kk < SPW; ++kk) {
      yp[kk] = 0.f; xC[kk] = 0.f; xN[kk] = 0.f; xN2[kk] = 0.f;
    }
    for (int s = 0; s < nseg; ++s) {
      barrier_lgkm();
      if (s == 0) {
#pragma unroll
        for (int kk = 0; kk < SPW; ++kk) {
          int k = kbase + kk;
          if (k < KNUM) {
            int i = lane + (k << 6);
            xC[kk] = xbuf[i];
            xN[kk] = xbuf[C + i];
            xN2[kk] = xbuf[2 * C + i];
          }
        }
      }
      int fence = (s + 1) << 11;
      if (fence > span) fence = span;
      while (rel < fence) {
        const bool lean = (rel + C <= W);
        barrier_lgkm();
        const int rb = par << 5, wb = rb ^ 32;
        float pbA = 0.f, pbB = 0.f;
        if (kbase == 0) {
          pbA = bnd[rb + 24];
          pbB = bnd[rb + 25];
        } else if (kbase < KNUM) {
          pbA = bnd[rb + (kbase - 1) * 2];
          pbB = bnd[rb + (kbase - 1) * 2 + 1];
        }
        float b2v[SPW], b3v[SPW];
#pragma unroll
        for (int kk = 0; kk < SPW; ++kk) {
          int k = kbase + kk;
          if (k < KNUM)
            b2v[kk] = shr1(yp[kk], (kk == 0) ? pbA : rl63(yp[kk - 1]));
        }
#pragma unroll
        for (int kk = 0; kk < SPW; ++kk) {
          int k = kbase + kk;
          if (k < KNUM)
            b3v[kk] = shr1(b2v[kk], (kk == 0) ? pbB : rlv(yp[kk - 1], 62));
        }
        float p1n = 0.f, p2n = 0.f;
        const bool ownLast = (KNUM - 1 >= kbase) && (KNUM - 1 < kbase + SPW);
        if (ownLast) {
          p1n = rlv(yp[KNUM - 1 - kbase], lq1);
          p2n = rlv(b2v[KNUM - 1 - kbase], lq1);
        }
#pragma unroll
        for (int kk = 0; kk < SPW; ++kk) {
          int k = kbase + kk;
          if (k < KNUM)
            yp[kk] = fmaf(c0w, yp[kk],
                          fmaf(c2w, b3v[kk], fmaf(c1w, b2v[kk], xC[kk])));
        }
        if (!lean) {
#pragma unroll
          for (int kk = 0; kk < SPW; ++kk) {
            int k = kbase + kk;
            if (k < KNUM) {
              int i = lane + (k << 6);
              int n = s1 + rel + i;
              bool okl = (k < KNUM - 1) || (lane <= lq1);
              if (okl && n >= n0 && n < end) yg[n] = yp[kk];
            }
          }
        }
#pragma unroll
        for (int kk = 0; kk < SPW; ++kk) {
          int k = kbase + kk;
          if (k < KNUM) {
            float h63 = rlv(yp[kk], 63);
            float h62 = rlv(yp[kk], 62);
            if (lane == 0) {
              bnd[wb + k * 2] = h63;
              bnd[wb + k * 2 + 1] = h62;
            }
          }
        }
        if (ownLast && lane == 0) {
          bnd[wb + 24] = p1n;
          bnd[wb + 25] = p2n;
        }
#pragma unroll
        for (int kk = 0; kk < SPW; ++kk) {
          int k = kbase + kk;
          if (k < KNUM) {
            xC[kk] = xN[kk];
            xN[kk] = xN2[kk];
            xN2[kk] = xbuf[(rel + 3 * C + lane + (k << 6)) & 8191];
          }
        }
        rel += C;
        par ^= 1;
      }
      barrier_lgkm();
      int ls = s + 3;
      if (ls < nseg) scan_seg(SC, xbuf, ls, true, t);
    }
  }
}

// One-pole scan over [s2, s2+nt*2048) from global into LDS sl[n-s2], reads
// clamped at `lim` (positions >= lim read as 0; causally unused).
__device__ inline void lpc_lds(const float* __restrict__ xg,
                               float* __restrict__ sl, int s2, int nt, int lim,
                               float scale, float c, int t, float* lws) {
  const int lane = t & 63, wid = t >> 6;
  float c2v = c * c, c4 = c2v * c2v, c8 = c4 * c4;
  float m1 = c8, m2 = m1 * m1, m4 = m2 * m2, m8 = m4 * m4, m16 = m8 * m8,
        m32 = m16 * m16;
  float c512 = m32 * m32;
  float c2048 = c512 * c512;
  c2048 *= c2048;
  float l2c = log2f(c);
  float c8lane = exp2f((float)(8 * lane) * l2c);
  float cgk = exp2f((float)(8 * t) * l2c);
  float vrun = 0.0f;
  for (int tile = 0; tile < nt; ++tile) {
    __syncthreads();
    int g0 = s2 + (tile << 11) + 8 * t;
    float4 xa = make_float4(0.f, 0.f, 0.f, 0.f);
    float4 xb = make_float4(0.f, 0.f, 0.f, 0.f);
    if (g0 + 3 < lim) xa = *(const float4*)&xg[g0];
    if (g0 + 7 < lim) xb = *(const float4*)&xg[g0 + 4];
    float S = 0.0f;
    S = fmaf(c, S, scale * xa.x); S = fmaf(c, S, scale * xa.y);
    S = fmaf(c, S, scale * xa.z); S = fmaf(c, S, scale * xa.w);
    S = fmaf(c, S, scale * xb.x); S = fmaf(c, S, scale * xb.y);
    S = fmaf(c, S, scale * xb.z); S = fmaf(c, S, scale * xb.w);
    float Sw = S, u;
    u = __shfl_up(Sw, 1);  if (lane >= 1)  Sw = fmaf(m1, u, Sw);
    u = __shfl_up(Sw, 2);  if (lane >= 2)  Sw = fmaf(m2, u, Sw);
    u = __shfl_up(Sw, 4);  if (lane >= 4)  Sw = fmaf(m4, u, Sw);
    u = __shfl_up(Sw, 8);  if (lane >= 8)  Sw = fmaf(m8, u, Sw);
    u = __shfl_up(Sw, 16); if (lane >= 16) Sw = fmaf(m16, u, Sw);
    u = __shfl_up(Sw, 32); if (lane >= 32) Sw = fmaf(m32, u, Sw);
    if (lane == 63) lws[wid] = Sw;
    __syncthreads();
    float a0 = lws[0], a1w = lws[1], a2w = lws[2], a3w = lws[3];
    float carry = (wid == 1)   ? a0
                  : (wid == 2) ? fmaf(c512, a0, a1w)
                  : (wid == 3) ? fmaf(c512, fmaf(c512, a0, a1w), a2w)
                               : 0.0f;
    float Sprev = __shfl_up(Sw, 1);
    float Sex = (lane == 0) ? 0.0f : Sprev;
    Sex = fmaf(c8lane, carry, Sex);
    float v = fmaf(cgk, vrun, Sex);
    int o = g0 - s2;
    float4 ya, yb;
    v = fmaf(c, v, scale * xa.x); ya.x = v;
    v = fmaf(c, v, scale * xa.y); ya.y = v;
    v = fmaf(c, v, scale * xa.z); ya.z = v;
    v = fmaf(c, v, scale * xa.w); ya.w = v;
    v = fmaf(c, v, scale * xb.x); yb.x = v;
    v = fmaf(c, v, scale * xb.y); yb.y = v;
    v = fmaf(c, v, scale * xb.z); yb.z = v;
    v = fmaf(c, v, scale * xb.w); yb.w = v;
    *(float4*)&sl[o] = ya;
    *(float4*)&sl[o + 4] = yb;
    float tS = fmaf(c512, fmaf(c512, fmaf(c512, a0, a1w), a2w), a3w);
    vrun = fmaf(c2048, vrun, tS);
  }
}

// ---- KS phase driver (Wp cap 80) ----
__device__ inline void ks_phase(int b, int q, const BParams& P,
                                const float* __restrict__ exc, float scale0,
                                float* __restrict__ buf1, float* xbuf,
                                float* bnd, float* lws, int t) {
  const int C = P.Di;
  const int n0 = q << 10;
  float lg = -logf(P.g);
  int Wp = (int)ceilf(10.5f / fmaxf(lg, 1e-6f));
  if (Wp > 80) Wp = 80;
  if (Wp < 4) Wp = 4;
  int W = Wp * C;
  if (W > n0) W = n0;
  W = (W + 3) & ~3;
  const int s1 = n0 - W;
  const int span = W + T1;
  const int end = n0 + T1;
  const int nseg = (span + 2047) >> 11;
  float* yg = buf1 + (size_t)b * NSAMP;

  SCtx SC;
  SC.exc_b = exc + (size_t)b * NSAMP;
  SC.c = 1.0f - P.alpha;
  SC.scale = scale0 * P.alpha;
  {
    float c = SC.c;
    float c2v = c * c, c4 = c2v * c2v, c8 = c4 * c4;
    SC.m1 = c8;
    SC.m2 = SC.m1 * SC.m1;
    SC.m4 = SC.m2 * SC.m2;
    SC.m8 = SC.m4 * SC.m4;
    SC.m16 = SC.m8 * SC.m8;
    SC.m32 = SC.m16 * SC.m16;
    SC.c512 = SC.m32 * SC.m32;
    float c1024 = SC.c512 * SC.c512;
    SC.c2048 = c1024 * c1024;
    float l2c = log2f(c);
    SC.c8lane = exp2f((float)(8 * (t & 63)) * l2c);
    SC.cgk = exp2f((float)(8 * t) * l2c);
  }
  SC.vrun = 0.0f;
  SC.s1 = s1;
  SC.lws = lws;

  if (s1 > 0) scan_seg(SC, xbuf, -1, false, t);
  scan_seg(SC, xbuf, 0, true, t);
  scan_seg(SC, xbuf, 1, true, t);
  scan_seg(SC, xbuf, 2, true, t);
  if (t < 64) bnd[t] = 0.0f;

  const float c0w = P.g * (1.0f - P.s) * (1.0f - P.fr);
  const float c1w = P.g * ((1.0f - P.s) * P.fr + P.s * (1.0f - P.fr));
  const float c2w = P.g * P.s * P.fr;
  switch ((C + 63) >> 6) {
    case 2:  ks_slice2<2>(SC, yg, xbuf, bnd, t, C, c0w, c1w, c2w, s1, n0, end, span, nseg); break;
    case 3:  ks_slice2<3>(SC, yg, xbuf, bnd, t, C, c0w, c1w, c2w, s1, n0, end, span, nseg); break;
    case 4:  ks_slice2<4>(SC, yg, xbuf, bnd, t, C, c0w, c1w, c2w, s1, n0, end, span, nseg); break;
    case 5:  ks_slice2<5>(SC, yg, xbuf, bnd, t, C, c0w, c1w, c2w, s1, n0, end, span, nseg); break;
    case 6:  ks_slice2<6>(SC, yg, xbuf, bnd, t, C, c0w, c1w, c2w, s1, n0, end, span, nseg); break;
    case 7:  ks_slice2<7>(SC, yg, xbuf, bnd, t, C, c0w, c1w, c2w, s1, n0, end, span, nseg); break;
    case 8:  ks_slice2<8>(SC, yg, xbuf, bnd, t, C, c0w, c1w, c2w, s1, n0, end, span, nseg); break;
    case 9:  ks_slice2<9>(SC, yg, xbuf, bnd, t, C, c0w, c1w, c2w, s1, n0, end, span, nseg); break;
    case 10: ks_slice2<10>(SC, yg, xbuf, bnd, t, C, c0w, c1w, c2w, s1, n0, end, span, nseg); break;
    case 11: ks_slice2<11>(SC, yg, xbuf, bnd, t, C, c0w, c1w, c2w, s1, n0, end, span, nseg); break;
    default: ks_slice2<12>(SC, yg, xbuf, bnd, t, C, c0w, c1w, c2w, s1, n0, end, span, nseg); break;
  }
}

// ---- body phase, T2=1024 (one block per (batch, 1024-slice)) ----
// window: [base, end), base = n0-4096 (zero-state warm-up), postLP warm-up
// 256 before base. Per-thread 20 samples; multiplier M^20.
__device__ inline void body_phase(int b, int q, const BParams& P,
                                  const float* __restrict__ gains,
                                  const float* __restrict__ buf1,
                                  float* __restrict__ out, float* sl,
                                  float* lws, float (*lc0)[8],
                                  float (*lc1)[8], int t) {
  const int lane = t & 63, wid = t >> 6;
  const int n0 = q << 10;
  const int base = n0 - 4096;
  int s2 = base - 256;
  if (s2 < 0) s2 = 0;
  const int end = n0 + 1024;
  const int nt = (end - s2 + 2047) >> 11;  // <= 3

  lpc_lds(buf1 + (size_t)b * NSAMP, sl, s2, nt, end, P.alpha_p,
          1.0f - P.alpha_p, t, lws);
  __syncthreads();

  const int tb = base + 20 * t;
  float4 acc[5];
#pragma unroll
  for (int i = 0; i < 5; ++i) acc[i] = make_float4(0.f, 0.f, 0.f, 0.f);

  for (int g = 0; g < 3; ++g) {
    float A1[8], A2[8], B0[8], GN[8];
#pragma unroll
    for (int j = 0; j < 8; ++j) {
      int k = g * 8 + j;
      band_coef(k, A1[j], A2[j], B0[j]);
      GN[j] = gains[k];
    }
    float cv0[8], cv1[8];
#pragma unroll
    for (int j = 0; j < 8; ++j) cv0[j] = cv1[j] = 0.f;
    for (int i = 0; i < 5; ++i) {
      int n = tb + 4 * i;
      float4 xv = make_float4(0.f, 0.f, 0.f, 0.f);
      if (n >= 0) xv = *(const float4*)&sl[n - s2];
#pragma unroll
      for (int e = 0; e < 4; ++e) {
        float xi = e == 0 ? xv.x : e == 1 ? xv.y : e == 2 ? xv.z : xv.w;
#pragma unroll
        for (int j = 0; j < 8; ++j) {
          float nc = fmaf(B0[j], xi, -fmaf(A1[j], cv0[j], A2[j] * cv1[j]));
          cv1[j] = cv0[j];
          cv0[j] = nc;
        }
      }
    }
    // Q = M^20 = M^16 * M^4 ; T snapshot
    float Q00[8], Q01[8], Q10[8], Q11[8];
    float K00[8], K01[8], K10[8], K11[8];
#pragma unroll
    for (int j = 0; j < 8; ++j) {
      Q00[j] = -A1[j]; Q01[j] = -A2[j]; Q10[j] = 1.f; Q11[j] = 0.f;
    }
    for (int sq = 0; sq < 2; ++sq) {  // -> M^4
#pragma unroll
      for (int j = 0; j < 8; ++j) {
        float n00 = fmaf(Q00[j], Q00[j], Q01[j] * Q10[j]);
        float n01 = fmaf(Q00[j], Q01[j], Q01[j] * Q11[j]);
        float n10 = fmaf(Q10[j], Q00[j], Q11[j] * Q10[j]);
        float n11 = fmaf(Q10[j], Q01[j], Q11[j] * Q11[j]);
        Q00[j] = n00; Q01[j] = n01; Q10[j] = n10; Q11[j] = n11;
      }
    }
#pragma unroll
    for (int j = 0; j < 8; ++j) {
      K00[j] = Q00[j]; K01[j] = Q01[j]; K10[j] = Q10[j]; K11[j] = Q11[j];
    }
    for (int sq = 0; sq < 2; ++sq) {  // -> M^16
#pragma unroll
      for (int j = 0; j < 8; ++j) {
        float n00 = fmaf(Q00[j], Q00[j], Q01[j] * Q10[j]);
        float n01 = fmaf(Q00[j], Q01[j], Q01[j] * Q11[j]);
        float n10 = fmaf(Q10[j], Q00[j], Q11[j] * Q10[j]);
        float n11 = fmaf(Q10[j], Q01[j], Q11[j] * Q11[j]);
        Q00[j] = n00; Q01[j] = n01; Q10[j] = n10; Q11[j] = n11;
      }
    }
    float T00[8], T01[8], T10[8], T11[8];
#pragma unroll
    for (int j = 0; j < 8; ++j) {  // M^20 = M^16 * M^4
      float n00 = fmaf(Q00[j], K00[j], Q01[j] * K10[j]);
      float n01 = fmaf(Q00[j], K01[j], Q01[j] * K11[j]);
      float n10 = fmaf(Q10[j], K00[j], Q11[j] * K10[j]);
      float n11 = fmaf(Q10[j], K01[j], Q11[j] * K11[j]);
      Q00[j] = n00; Q01[j] = n01; Q10[j] = n10; Q11[j] = n11;
      T00[j] = n00; T01[j] = n01; T10[j] = n10; T11[j] = n11;
    }
    for (int off = 1; off <= 32; off <<= 1) {
#pragma unroll
      for (int j = 0; j < 8; ++j) {
        float u0 = __shfl_up(cv0[j], off);
        float u1 = __shfl_up(cv1[j], off);
        if (lane >= off) {
          float nc0 = fmaf(Q00[j], u0, fmaf(Q01[j], u1, cv0[j]));
          float nc1 = fmaf(Q10[j], u0, fmaf(Q11[j], u1, cv1[j]));
          cv0[j] = nc0;
          cv1[j] = nc1;
        }
        float n00 = fmaf(Q00[j], Q00[j], Q01[j] * Q10[j]);
        float n01 = fmaf(Q00[j], Q01[j], Q01[j] * Q11[j]);
        float n10 = fmaf(Q10[j], Q00[j], Q11[j] * Q10[j]);
        float n11 = fmaf(Q10[j], Q01[j], Q11[j] * Q11[j]);
        Q00[j] = n00; Q01[j] = n01; Q10[j] = n10; Q11[j] = n11;
      }
    }
    __syncthreads();
    if (lane == 63) {
#pragma unroll
      for (int j = 0; j < 8; ++j) {
        lc0[wid][j] = cv0[j];
        lc1[wid][j] = cv1[j];
      }
    }
    __syncthreads();
    float car0[8], car1[8];
#pragma unroll
    for (int j = 0; j < 8; ++j) car0[j] = car1[j] = 0.f;
    for (int v = 0; v < wid; ++v) {
#pragma unroll
      for (int j = 0; j < 8; ++j) {
        float n0c = fmaf(Q00[j], car0[j], fmaf(Q01[j], car1[j], lc0[v][j]));
        float n1c = fmaf(Q10[j], car0[j], fmaf(Q11[j], car1[j], lc1[v][j]));
        car0[j] = n0c;
        car1[j] = n1c;
      }
    }
    float R00[8], R01[8], R10[8], R11[8];
#pragma unroll
    for (int j = 0; j < 8; ++j) {
      R00[j] = 1.f; R01[j] = 0.f; R10[j] = 0.f; R11[j] = 1.f;
    }
    for (int bit = 0; bit < 6; ++bit) {
      bool on = (lane >> bit) & 1;
#pragma unroll
      for (int j = 0; j < 8; ++j) {
        if (on) {
          float n00 = fmaf(T00[j], R00[j], T01[j] * R10[j]);
          float n01 = fmaf(T00[j], R01[j], T01[j] * R11[j]);
          float n10 = fmaf(T10[j], R00[j], T11[j] * R10[j]);
          float n11 = fmaf(T10[j], R01[j], T11[j] * R11[j]);
          R00[j] = n00; R01[j] = n01; R10[j] = n10; R11[j] = n11;
        }
        float s00 = fmaf(T00[j], T00[j], T01[j] * T10[j]);
        float s01 = fmaf(T00[j], T01[j], T01[j] * T11[j]);
        float s10 = fmaf(T10[j], T00[j], T11[j] * T10[j]);
        float s11 = fmaf(T10[j], T01[j], T11[j] * T11[j]);
        T00[j] = s00; T01[j] = s01; T10[j] = s10; T11[j] = s11;
      }
    }
    float y1[8], y2[8];
#pragma unroll
    for (int j = 0; j < 8; ++j) {
      float e0 = __shfl_up(cv0[j], 1);
      float e1 = __shfl_up(cv1[j], 1);
      if (lane == 0) { e0 = 0.f; e1 = 0.f; }
      y1[j] = fmaf(R00[j], car0[j], fmaf(R01[j], car1[j], e0));
      y2[j] = fmaf(R10[j], car0[j], fmaf(R11[j], car1[j], e1));
    }
    if (tb + 20 > n0) {  // this thread overlaps the output region
      for (int i = 0; i < 5; ++i) {
        float4 xv = *(const float4*)&sl[tb - s2 + 4 * i];
        float4 ov = acc[i];
#pragma unroll
        for (int e = 0; e < 4; ++e) {
          float xi = e == 0 ? xv.x : e == 1 ? xv.y : e == 2 ? xv.z : xv.w;
          float a = 0.f;
#pragma unroll
          for (int j = 0; j < 8; ++j) {
            float yv = fmaf(B0[j], xi, -fmaf(A1[j], y1[j], A2[j] * y2[j]));
            y2[j] = y1[j];
            y1[j] = yv;
            a = fmaf(GN[j], yv, a);
          }
          if (e == 0) ov.x += a;
          else if (e == 1) ov.y += a;
          else if (e == 2) ov.z += a;
          else ov.w += a;
        }
        acc[i] = ov;
      }
    }
  }
  if (tb + 20 > n0) {
    float* outb = out + (size_t)b * NSAMP;
#pragma unroll
    for (int i = 0; i < 5; ++i) {
      int n = tb + 4 * i;
      if (n >= n0) *(float4*)&outb[n] = acc[i];  // 4-aligned group guard
    }
  }
}

// ======== single kernel: 256 KS blocks + 256 body blocks, flag handoff ========
__global__ void __launch_bounds__(256, 1) synth_all(
    const float* __restrict__ exc, const float* __restrict__ pitch,
    const float* __restrict__ w1, const float* __restrict__ b1,
    const float* __restrict__ w2, const float* __restrict__ b2,
    const float* __restrict__ eg, const float* __restrict__ gains,
    float* __restrict__ buf1, int* __restrict__ flags,
    float* __restrict__ out) {
  const int blk = blockIdx.x;
  const int t = threadIdx.x;
  __shared__ __align__(16) float smem[8264];

  if (blk < 256) {
    // ---- KS producer: b = blk>>5, q = blk&31 ----
    const int b = blk >> 5, q = blk & 31;
    BParams P = compute_params(b, pitch, w1, b1, w2, b2);
    if (blk == 0 && t < 64) {
      int bb = (t < 8) ? t : 0;
      BParams Q = compute_params(bb, pitch, w1, b1, w2, b2);
      float slc = 0.f, slm = 0.f, slp = 0.f;
      for (int i = 0; i < 8; ++i) {
        slc += rlv(Q.lc, i);
        slm += rlv(Q.lm, i);
        slp += rlv(Q.lp, i);
      }
      if (t == 0) {
        out[8 * NSAMP + 0] = slc / 8.0f;
        out[8 * NSAMP + 1] = slm / 8.0f;
        out[8 * NSAMP + 2] = slp / 8.0f;
      }
    }
    ks_phase(b, q, P, exc, eg[0], buf1, smem, smem + 8192, smem + 8256, t);
    __syncthreads();  // drain all waves' global stores (vmcnt)
    if (t == 0)
      __hip_atomic_store(&flags[b * 32 + q], FLAG_MAGIC, __ATOMIC_RELEASE,
                         __HIP_MEMORY_SCOPE_AGENT);
  } else {
    // ---- body consumer: b = (blk-256)>>5, q = (blk-256)&31 ----
    const int blk2 = blk - 256;
    const int b = blk2 >> 5, q = blk2 & 31;
    const int n0 = q << 10;
    int s2 = n0 - 4096 - 256;
    if (s2 < 0) s2 = 0;
    const int qlo = s2 >> 10;
    if (t == 0) {
      for (int f = qlo; f <= q; ++f) {
        while (__hip_atomic_load(&flags[b * 32 + f], __ATOMIC_ACQUIRE,
                                 __HIP_MEMORY_SCOPE_AGENT) != FLAG_MAGIC) {
        }
      }
    }
    __syncthreads();
    BParams P = compute_params(b, pitch, w1, b1, w2, b2);
    body_phase(b, q, P, gains, buf1, out, smem, smem + 6144,
               (float(*)[8])(smem + 6152), (float(*)[8])(smem + 6184), t);
  }
}

extern "C" void kernel_launch(void* const* d_in, const int* in_sizes, int n_in,
                              void* d_out, int out_size, void* d_ws, size_t ws_size,
                              hipStream_t stream) {
  const float* exc = (const float*)d_in[0];
  const float* pitch = (const float*)d_in[1];
  const float* w1 = (const float*)d_in[2];
  const float* b1 = (const float*)d_in[3];
  const float* w2 = (const float*)d_in[4];
  const float* b2 = (const float*)d_in[5];
  const float* eg = (const float*)d_in[6];
  const float* bg = (const float*)d_in[7];
  float* out = (float*)d_out;
  float* buf1 = (float*)d_ws;                  // 8*NSAMP floats (KS output)
  int* flags = (int*)(buf1 + 8 * NSAMP);       // 256 flags (poison != MAGIC)

  hipLaunchKernelGGL(synth_all, dim3(512), dim3(256), 0, stream, exc, pitch,
                     w1, b1, w2, b2, eg, bg, buf1, flags, out);
}

// Round 13
// 134.483 us; speedup vs baseline: 1.4792x; 1.0015x over previous
//
#include <hip/hip_runtime.h>
#include <math.h>

#define NSAMP 32768
#define FS_F 44100.0f
#define PI_F 3.14159265358979323846f
#define T1 1024  // KS slice length (32 slices/batch)
#define FLAG_MAGIC 0x5A5A5A5A

struct BParams {
  float alpha, alpha_p;
  float fr, g, s;
  int Di;
  float lc, lm, lp;
};

__device__ inline float sigmoidf_(float x) { return 1.0f / (1.0f + expf(-x)); }

__device__ inline BParams compute_params(int b, const float* __restrict__ pitch,
                                         const float* __restrict__ w1,
                                         const float* __restrict__ b1,
                                         const float* __restrict__ w2,
                                         const float* __restrict__ b2) {
  BParams P;
  float p = pitch[b];
  float h[16];
#pragma unroll
  for (int i = 0; i < 16; ++i) {
    float v = fmaf(p, w1[i], b1[i]);
    h[i] = v > 0.0f ? v : 0.0f;
  }
  float m[3];
#pragma unroll
  for (int j = 0; j < 3; ++j) {
    float acc = b2[j];
#pragma unroll
    for (int i = 0; i < 16; ++i) acc = fmaf(h[i], w2[j * 16 + i], acc);
    m[j] = acc;
  }
  P.lc = fminf(fmaxf(m[0], -2.0f), 2.5f);
  P.lm = fminf(fmaxf(m[1], -2.5f), 0.0f);
  P.lp = fminf(fmaxf(m[2], -4.0f), 4.0f);
  P.g = 0.999f * sigmoidf_(P.lc);
  P.s = sigmoidf_(P.lm);
  float f0 = fmaxf(p, 60.0f);
  float D = fminf(fmaxf(FS_F / f0, 2.0f), 735.0f);
  int Di = (int)floorf(D);
  P.fr = D - (float)Di;
  P.Di = Di;
  float mult = fminf(fmaxf(2.0f + 6.0f * (f0 - 60.0f) / 600.0f, 2.0f), 8.0f);
  float cutoff = fminf(2.0f * PI_F * f0 * mult / FS_F, PI_F * 0.9f);
  P.alpha = 1.0f - expf(-cutoff);
  float cpost = fminf(PI_F * sigmoidf_(P.lp), PI_F * 0.99f);
  P.alpha_p = 1.0f - expf(-cpost);
  return P;
}

// lane helpers (wave64)
__device__ inline float rl63(float v) {
  return __int_as_float(__builtin_amdgcn_readlane(__float_as_int(v), 63));
}
__device__ inline float rlv(float v, int l) {
  return __int_as_float(__builtin_amdgcn_readlane(__float_as_int(v), l));
}
__device__ inline float shr1(float v, float bnd) {
  return __int_as_float(__builtin_amdgcn_update_dpp(
      __float_as_int(bnd), __float_as_int(v), 0x138 /*wave_shr:1*/, 0xf, 0xf,
      false));
}

// Block barrier draining ONLY lgkmcnt (keeps global stores in flight).
__device__ inline void barrier_lgkm() {
  asm volatile("s_waitcnt lgkmcnt(0)\n\ts_barrier" ::: "memory");
}

__device__ inline void band_coef(int k, float& a1, float& a2, float& b0) {
  float fc = 80.0f * exp2f((float)k * (6.64385618977472436f / 23.0f));
  float w = 2.0f * PI_F * fc / FS_F;
  float r = expf(-PI_F * fc / (10.0f * FS_F));
  a1 = -2.0f * r * cosf(w);
  a2 = r * r;
  b0 = 1.0f - r;
}

// ---- on-the-fly preLP scan context ----
struct SCtx {
  const float* exc_b;
  float scale, c;
  float m1, m2, m4, m8, m16, m32, c512, c2048, c8lane, cgk;
  float vrun;
  int s1;
  float* lws;
};

__device__ inline void scan_seg(SCtx& SC, float* xbuf, int seg, bool write,
                                int t) {
  const int lane = t & 63, wid = t >> 6;
  const int rel0 = seg << 11;
  const int A = SC.s1 + rel0;
  __syncthreads();
  const int g0 = A + 8 * t;
  float4 xa = make_float4(0.f, 0.f, 0.f, 0.f);
  float4 xb = make_float4(0.f, 0.f, 0.f, 0.f);
  if (g0 >= 0 && g0 + 3 < NSAMP) xa = *(const float4*)&SC.exc_b[g0];
  if (g0 + 4 >= 0 && g0 + 7 < NSAMP) xb = *(const float4*)&SC.exc_b[g0 + 4];
  const float c = SC.c, scale = SC.scale;
  float S = 0.0f;
  S = fmaf(c, S, scale * xa.x); S = fmaf(c, S, scale * xa.y);
  S = fmaf(c, S, scale * xa.z); S = fmaf(c, S, scale * xa.w);
  S = fmaf(c, S, scale * xb.x); S = fmaf(c, S, scale * xb.y);
  S = fmaf(c, S, scale * xb.z); S = fmaf(c, S, scale * xb.w);
  float Sw = S, u;
  u = __shfl_up(Sw, 1);  if (lane >= 1)  Sw = fmaf(SC.m1, u, Sw);
  u = __shfl_up(Sw, 2);  if (lane >= 2)  Sw = fmaf(SC.m2, u, Sw);
  u = __shfl_up(Sw, 4);  if (lane >= 4)  Sw = fmaf(SC.m4, u, Sw);
  u = __shfl_up(Sw, 8);  if (lane >= 8)  Sw = fmaf(SC.m8, u, Sw);
  u = __shfl_up(Sw, 16); if (lane >= 16) Sw = fmaf(SC.m16, u, Sw);
  u = __shfl_up(Sw, 32); if (lane >= 32) Sw = fmaf(SC.m32, u, Sw);
  if (lane == 63) SC.lws[wid] = Sw;
  __syncthreads();
  float a0 = SC.lws[0], a1w = SC.lws[1], a2w = SC.lws[2], a3w = SC.lws[3];
  float carry = (wid == 1)   ? a0
                : (wid == 2) ? fmaf(SC.c512, a0, a1w)
                : (wid == 3) ? fmaf(SC.c512, fmaf(SC.c512, a0, a1w), a2w)
                             : 0.0f;
  float Sprev = __shfl_up(Sw, 1);
  float Sex = (lane == 0) ? 0.0f : Sprev;
  Sex = fmaf(SC.c8lane, carry, Sex);
  float v = fmaf(SC.cgk, SC.vrun, Sex);
  float4 ya, yb;
  v = fmaf(c, v, scale * xa.x); ya.x = v;
  v = fmaf(c, v, scale * xa.y); ya.y = v;
  v = fmaf(c, v, scale * xa.z); ya.z = v;
  v = fmaf(c, v, scale * xa.w); ya.w = v;
  v = fmaf(c, v, scale * xb.x); yb.x = v;
  v = fmaf(c, v, scale * xb.y); yb.y = v;
  v = fmaf(c, v, scale * xb.z); yb.z = v;
  v = fmaf(c, v, scale * xb.w); yb.w = v;
  if (write) {
    int o = (rel0 + 8 * t) & 8191;
    *(float4*)&xbuf[o] = ya;
    *(float4*)&xbuf[o + 4] = yb;
  }
  float tS = fmaf(SC.c512, fmaf(SC.c512, fmaf(SC.c512, a0, a1w), a2w), a3w);
  SC.vrun = fmaf(SC.c2048, SC.vrun, tS);
}

// KS slice compute (R11, proven): lean warm-up + full loops, 3-deep prefetch.
template <int KNUM>
__device__ void ks_slice2(SCtx& SC, float* __restrict__ yg, float* xbuf,
                          float* bnd, int t, int C, float c0w, float c1w,
                          float c2w, int s1, int n0, int end, int span,
                          int nseg) {
  const int lane = t & 63;
  const int wid = t >> 6;
  const int lq1 = (C - 1) - (KNUM - 1) * 64;
  const int W = n0 - s1;

  if (KNUM <= 3) {
    float yp[KNUM], xC[KNUM], xN[KNUM], xN2[KNUM];
    float p1 = 0.f, p2 = 0.f;
    int rel = 0;
#pragma unroll
    for (int k = 0; k < KNUM; ++k) {
      yp[k] = 0.f; xC[k] = 0.f; xN[k] = 0.f; xN2[k] = 0.f;
    }
    for (int s = 0; s < nseg; ++s) {
      barrier_lgkm();
      if (wid == 0) {
        if (s == 0) {
#pragma unroll
          for (int k = 0; k < KNUM; ++k) {
            int i = lane + (k << 6);
            xC[k] = xbuf[i];
            xN[k] = xbuf[C + i];
            xN2[k] = xbuf[2 * C + i];
          }
        }
        int fence = (s + 1) << 11;
        if (fence > span) fence = span;
        while (rel + C <= W && rel < fence) {
          float b2v[KNUM], b3v[KNUM];
#pragma unroll
          for (int k = 0; k < KNUM; ++k)
            b2v[k] = shr1(yp[k], (k == 0) ? p1 : rl63(yp[k - 1]));
#pragma unroll
          for (int k = 0; k < KNUM; ++k)
            b3v[k] = shr1(b2v[k], (k == 0) ? p2 : rlv(yp[k - 1], 62));
          float p1n = rlv(yp[KNUM - 1], lq1);
          float p2n = rlv(b2v[KNUM - 1], lq1);
#pragma unroll
          for (int k = 0; k < KNUM; ++k)
            yp[k] = fmaf(c0w, yp[k],
                         fmaf(c2w, b3v[k], fmaf(c1w, b2v[k], xC[k])));
          p1 = p1n;
          p2 = p2n;
#pragma unroll
          for (int k = 0; k < KNUM; ++k) {
            xC[k] = xN[k];
            xN[k] = xN2[k];
            xN2[k] = xbuf[(rel + 3 * C + lane + (k << 6)) & 8191];
          }
          rel += C;
        }
        while (rel < fence) {
          float b2v[KNUM], b3v[KNUM];
#pragma unroll
          for (int k = 0; k < KNUM; ++k)
            b2v[k] = shr1(yp[k], (k == 0) ? p1 : rl63(yp[k - 1]));
#pragma unroll
          for (int k = 0; k < KNUM; ++k)
            b3v[k] = shr1(b2v[k], (k == 0) ? p2 : rlv(yp[k - 1], 62));
          float p1n = rlv(yp[KNUM - 1], lq1);
          float p2n = rlv(b2v[KNUM - 1], lq1);
#pragma unroll
          for (int k = 0; k < KNUM; ++k)
            yp[k] = fmaf(c0w, yp[k],
                         fmaf(c2w, b3v[k], fmaf(c1w, b2v[k], xC[k])));
          p1 = p1n;
          p2 = p2n;
#pragma unroll
          for (int k = 0; k < KNUM; ++k) {
            int i = lane + (k << 6);
            int n = s1 + rel + i;
            bool okl = (k < KNUM - 1) || (lane <= lq1);
            if (okl && n >= n0 && n < end) yg[n] = yp[k];
          }
#pragma unroll
          for (int k = 0; k < KNUM; ++k) {
            xC[k] = xN[k];
            xN[k] = xN2[k];
            xN2[k] = xbuf[(rel + 3 * C + lane + (k << 6)) & 8191];
          }
          rel += C;
        }
      }
      barrier_lgkm();
      int ls = s + 3;
      if (ls < nseg) scan_seg(SC, xbuf, ls, true, t);
    }
  } else {
    constexpr int SPW = (KNUM + 3) / 4;
    const int kbase = wid * SPW;
    float yp[SPW], xC[SPW], xN[SPW], xN2[SPW];
    int rel = 0, par = 0;
#pragma unroll
    for (int kk = 0; kk < SPW; ++kk) {
      yp[kk] = 0.f; xC[kk] = 0.f; xN[kk] = 0.f; xN2[kk] = 0.f;
    }
    for (int s = 0; s < nseg; ++s) {
      barrier_lgkm();
      if (s == 0) {
#pragma unroll
        for (int kk = 0; kk < SPW; ++kk) {
          int k = kbase + kk;
          if (k < KNUM) {
            int i = lane + (k << 6);
            xC[kk] = xbuf[i];
            xN[kk] = xbuf[C + i];
            xN2[kk] = xbuf[2 * C + i];
          }
        }
      }
      int fence = (s + 1) << 11;
      if (fence > span) fence = span;
      while (rel < fence) {
        const bool lean = (rel + C <= W);
        barrier_lgkm();
        const int rb = par << 5, wb = rb ^ 32;
        float pbA = 0.f, pbB = 0.f;
        if (kbase == 0) {
          pbA = bnd[rb + 24];
          pbB = bnd[rb + 25];
        } else if (kbase < KNUM) {
          pbA = bnd[rb + (kbase - 1) * 2];
          pbB = bnd[rb + (kbase - 1) * 2 + 1];
        }
        float b2v[SPW], b3v[SPW];
#pragma unroll
        for (int kk = 0; kk < SPW; ++kk) {
          int k = kbase + kk;
          if (k < KNUM)
            b2v[kk] = shr1(yp[kk], (kk == 0) ? pbA : rl63(yp[kk - 1]));
        }
#pragma unroll
        for (int kk = 0; kk < SPW; ++kk) {
          int k = kbase + kk;
          if (k < KNUM)
            b3v[kk] = shr1(b2v[kk], (kk == 0) ? pbB : rlv(yp[kk - 1], 62));
        }
        float p1n = 0.f, p2n = 0.f;
        const bool ownLast = (KNUM - 1 >= kbase) && (KNUM - 1 < kbase + SPW);
        if (ownLast) {
          p1n = rlv(yp[KNUM - 1 - kbase], lq1);
          p2n = rlv(b2v[KNUM - 1 - kbase], lq1);
        }
#pragma unroll
        for (int kk = 0; kk < SPW; ++kk) {
          int k = kbase + kk;
          if (k < KNUM)
            yp[kk] = fmaf(c0w, yp[kk],
                          fmaf(c2w, b3v[kk], fmaf(c1w, b2v[kk], xC[kk])));
        }
        if (!lean) {
#pragma unroll
          for (int kk = 0; kk < SPW; ++kk) {
            int k = kbase + kk;
            if (k < KNUM) {
              int i = lane + (k << 6);
              int n = s1 + rel + i;
              bool okl = (k < KNUM - 1) || (lane <= lq1);
              if (okl && n >= n0 && n < end) yg[n] = yp[kk];
            }
          }
        }
#pragma unroll
        for (int kk = 0; kk < SPW; ++kk) {
          int k = kbase + kk;
          if (k < KNUM) {
            float h63 = rlv(yp[kk], 63);
            float h62 = rlv(yp[kk], 62);
            if (lane == 0) {
              bnd[wb + k * 2] = h63;
              bnd[wb + k * 2 + 1] = h62;
            }
          }
        }
        if (ownLast && lane == 0) {
          bnd[wb + 24] = p1n;
          bnd[wb + 25] = p2n;
        }
#pragma unroll
        for (int kk = 0; kk < SPW; ++kk) {
          int k = kbase + kk;
          if (k < KNUM) {
            xC[kk] = xN[kk];
            xN[kk] = xN2[kk];
            xN2[kk] = xbuf[(rel + 3 * C + lane + (k << 6)) & 8191];
          }
        }
        rel += C;
        par ^= 1;
      }
      barrier_lgkm();
      int ls = s + 3;
      if (ls < nseg) scan_seg(SC, xbuf, ls, true, t);
    }
  }
}

// One-pole scan over [s2, s2+nt*2048) from global into LDS sl[n-s2], reads
// clamped at `lim` (positions >= lim read as 0; causally unused).
__device__ inline void lpc_lds(const float* __restrict__ xg,
                               float* __restrict__ sl, int s2, int nt, int lim,
                               float scale, float c, int t, float* lws) {
  const int lane = t & 63, wid = t >> 6;
  float c2v = c * c, c4 = c2v * c2v, c8 = c4 * c4;
  float m1 = c8, m2 = m1 * m1, m4 = m2 * m2, m8 = m4 * m4, m16 = m8 * m8,
        m32 = m16 * m16;
  float c512 = m32 * m32;
  float c2048 = c512 * c512;
  c2048 *= c2048;
  float l2c = log2f(c);
  float c8lane = exp2f((float)(8 * lane) * l2c);
  float cgk = exp2f((float)(8 * t) * l2c);
  float vrun = 0.0f;
  for (int tile = 0; tile < nt; ++tile) {
    __syncthreads();
    int g0 = s2 + (tile << 11) + 8 * t;
    float4 xa = make_float4(0.f, 0.f, 0.f, 0.f);
    float4 xb = make_float4(0.f, 0.f, 0.f, 0.f);
    if (g0 + 3 < lim) xa = *(const float4*)&xg[g0];
    if (g0 + 7 < lim) xb = *(const float4*)&xg[g0 + 4];
    float S = 0.0f;
    S = fmaf(c, S, scale * xa.x); S = fmaf(c, S, scale * xa.y);
    S = fmaf(c, S, scale * xa.z); S = fmaf(c, S, scale * xa.w);
    S = fmaf(c, S, scale * xb.x); S = fmaf(c, S, scale * xb.y);
    S = fmaf(c, S, scale * xb.z); S = fmaf(c, S, scale * xb.w);
    float Sw = S, u;
    u = __shfl_up(Sw, 1);  if (lane >= 1)  Sw = fmaf(m1, u, Sw);
    u = __shfl_up(Sw, 2);  if (lane >= 2)  Sw = fmaf(m2, u, Sw);
    u = __shfl_up(Sw, 4);  if (lane >= 4)  Sw = fmaf(m4, u, Sw);
    u = __shfl_up(Sw, 8);  if (lane >= 8)  Sw = fmaf(m8, u, Sw);
    u = __shfl_up(Sw, 16); if (lane >= 16) Sw = fmaf(m16, u, Sw);
    u = __shfl_up(Sw, 32); if (lane >= 32) Sw = fmaf(m32, u, Sw);
    if (lane == 63) lws[wid] = Sw;
    __syncthreads();
    float a0 = lws[0], a1w = lws[1], a2w = lws[2], a3w = lws[3];
    float carry = (wid == 1)   ? a0
                  : (wid == 2) ? fmaf(c512, a0, a1w)
                  : (wid == 3) ? fmaf(c512, fmaf(c512, a0, a1w), a2w)
                               : 0.0f;
    float Sprev = __shfl_up(Sw, 1);
    float Sex = (lane == 0) ? 0.0f : Sprev;
    Sex = fmaf(c8lane, carry, Sex);
    float v = fmaf(cgk, vrun, Sex);
    int o = g0 - s2;
    float4 ya, yb;
    v = fmaf(c, v, scale * xa.x); ya.x = v;
    v = fmaf(c, v, scale * xa.y); ya.y = v;
    v = fmaf(c, v, scale * xa.z); ya.z = v;
    v = fmaf(c, v, scale * xa.w); ya.w = v;
    v = fmaf(c, v, scale * xb.x); yb.x = v;
    v = fmaf(c, v, scale * xb.y); yb.y = v;
    v = fmaf(c, v, scale * xb.z); yb.z = v;
    v = fmaf(c, v, scale * xb.w); yb.w = v;
    *(float4*)&sl[o] = ya;
    *(float4*)&sl[o + 4] = yb;
    float tS = fmaf(c512, fmaf(c512, fmaf(c512, a0, a1w), a2w), a3w);
    vrun = fmaf(c2048, vrun, tS);
  }
}

// ---- KS phase driver (Wp cap 64) ----
__device__ inline void ks_phase(int b, int q, const BParams& P,
                                const float* __restrict__ exc, float scale0,
                                float* __restrict__ buf1, float* xbuf,
                                float* bnd, float* lws, int t) {
  const int C = P.Di;
  const int n0 = q << 10;
  float lg = -logf(P.g);
  int Wp = (int)ceilf(10.5f / fmaxf(lg, 1e-6f));
  if (Wp > 64) Wp = 64;
  if (Wp < 4) Wp = 4;
  int W = Wp * C;
  if (W > n0) W = n0;
  W = (W + 3) & ~3;
  const int s1 = n0 - W;
  const int span = W + T1;
  const int end = n0 + T1;
  const int nseg = (span + 2047) >> 11;
  float* yg = buf1 + (size_t)b * NSAMP;

  SCtx SC;
  SC.exc_b = exc + (size_t)b * NSAMP;
  SC.c = 1.0f - P.alpha;
  SC.scale = scale0 * P.alpha;
  {
    float c = SC.c;
    float c2v = c * c, c4 = c2v * c2v, c8 = c4 * c4;
    SC.m1 = c8;
    SC.m2 = SC.m1 * SC.m1;
    SC.m4 = SC.m2 * SC.m2;
    SC.m8 = SC.m4 * SC.m4;
    SC.m16 = SC.m8 * SC.m8;
    SC.m32 = SC.m16 * SC.m16;
    SC.c512 = SC.m32 * SC.m32;
    float c1024 = SC.c512 * SC.c512;
    SC.c2048 = c1024 * c1024;
    float l2c = log2f(c);
    SC.c8lane = exp2f((float)(8 * (t & 63)) * l2c);
    SC.cgk = exp2f((float)(8 * t) * l2c);
  }
  SC.vrun = 0.0f;
  SC.s1 = s1;
  SC.lws = lws;

  if (s1 > 0) scan_seg(SC, xbuf, -1, false, t);
  scan_seg(SC, xbuf, 0, true, t);
  scan_seg(SC, xbuf, 1, true, t);
  scan_seg(SC, xbuf, 2, true, t);
  if (t < 64) bnd[t] = 0.0f;

  const float c0w = P.g * (1.0f - P.s) * (1.0f - P.fr);
  const float c1w = P.g * ((1.0f - P.s) * P.fr + P.s * (1.0f - P.fr));
  const float c2w = P.g * P.s * P.fr;
  switch ((C + 63) >> 6) {
    case 2:  ks_slice2<2>(SC, yg, xbuf, bnd, t, C, c0w, c1w, c2w, s1, n0, end, span, nseg); break;
    case 3:  ks_slice2<3>(SC, yg, xbuf, bnd, t, C, c0w, c1w, c2w, s1, n0, end, span, nseg); break;
    case 4:  ks_slice2<4>(SC, yg, xbuf, bnd, t, C, c0w, c1w, c2w, s1, n0, end, span, nseg); break;
    case 5:  ks_slice2<5>(SC, yg, xbuf, bnd, t, C, c0w, c1w, c2w, s1, n0, end, span, nseg); break;
    case 6:  ks_slice2<6>(SC, yg, xbuf, bnd, t, C, c0w, c1w, c2w, s1, n0, end, span, nseg); break;
    case 7:  ks_slice2<7>(SC, yg, xbuf, bnd, t, C, c0w, c1w, c2w, s1, n0, end, span, nseg); break;
    case 8:  ks_slice2<8>(SC, yg, xbuf, bnd, t, C, c0w, c1w, c2w, s1, n0, end, span, nseg); break;
    case 9:  ks_slice2<9>(SC, yg, xbuf, bnd, t, C, c0w, c1w, c2w, s1, n0, end, span, nseg); break;
    case 10: ks_slice2<10>(SC, yg, xbuf, bnd, t, C, c0w, c1w, c2w, s1, n0, end, span, nseg); break;
    case 11: ks_slice2<11>(SC, yg, xbuf, bnd, t, C, c0w, c1w, c2w, s1, n0, end, span, nseg); break;
    default: ks_slice2<12>(SC, yg, xbuf, bnd, t, C, c0w, c1w, c2w, s1, n0, end, span, nseg); break;
  }
}

// ---- body phase, T2=1024 (one block per (batch, 1024-slice)) ----
__device__ inline void body_phase(int b, int q, const BParams& P,
                                  const float* __restrict__ gains,
                                  const float* __restrict__ buf1,
                                  float* __restrict__ out, float* sl,
                                  float* lws, float (*lc0)[8],
                                  float (*lc1)[8], int t) {
  const int lane = t & 63, wid = t >> 6;
  const int n0 = q << 10;
  const int base = n0 - 4096;
  int s2 = base - 256;
  if (s2 < 0) s2 = 0;
  const int end = n0 + 1024;
  const int nt = (end - s2 + 2047) >> 11;  // <= 3

  lpc_lds(buf1 + (size_t)b * NSAMP, sl, s2, nt, end, P.alpha_p,
          1.0f - P.alpha_p, t, lws);
  __syncthreads();

  const int tb = base + 20 * t;
  float4 acc[5];
#pragma unroll
  for (int i = 0; i < 5; ++i) acc[i] = make_float4(0.f, 0.f, 0.f, 0.f);

  for (int g = 0; g < 3; ++g) {
    float A1[8], A2[8], B0[8], GN[8];
#pragma unroll
    for (int j = 0; j < 8; ++j) {
      int k = g * 8 + j;
      band_coef(k, A1[j], A2[j], B0[j]);
      GN[j] = gains[k];
    }
    float cv0[8], cv1[8];
#pragma unroll
    for (int j = 0; j < 8; ++j) cv0[j] = cv1[j] = 0.f;
    for (int i = 0; i < 5; ++i) {
      int n = tb + 4 * i;
      float4 xv = make_float4(0.f, 0.f, 0.f, 0.f);
      if (n >= 0) xv = *(const float4*)&sl[n - s2];
#pragma unroll
      for (int e = 0; e < 4; ++e) {
        float xi = e == 0 ? xv.x : e == 1 ? xv.y : e == 2 ? xv.z : xv.w;
#pragma unroll
        for (int j = 0; j < 8; ++j) {
          float nc = fmaf(B0[j], xi, -fmaf(A1[j], cv0[j], A2[j] * cv1[j]));
          cv1[j] = cv0[j];
          cv0[j] = nc;
        }
      }
    }
    // Q = M^20 = M^16 * M^4 ; T snapshot
    float Q00[8], Q01[8], Q10[8], Q11[8];
    float K00[8], K01[8], K10[8], K11[8];
#pragma unroll
    for (int j = 0; j < 8; ++j) {
      Q00[j] = -A1[j]; Q01[j] = -A2[j]; Q10[j] = 1.f; Q11[j] = 0.f;
    }
    for (int sq = 0; sq < 2; ++sq) {  // -> M^4
#pragma unroll
      for (int j = 0; j < 8; ++j) {
        float n00 = fmaf(Q00[j], Q00[j], Q01[j] * Q10[j]);
        float n01 = fmaf(Q00[j], Q01[j], Q01[j] * Q11[j]);
        float n10 = fmaf(Q10[j], Q00[j], Q11[j] * Q10[j]);
        float n11 = fmaf(Q10[j], Q01[j], Q11[j] * Q11[j]);
        Q00[j] = n00; Q01[j] = n01; Q10[j] = n10; Q11[j] = n11;
      }
    }
#pragma unroll
    for (int j = 0; j < 8; ++j) {
      K00[j] = Q00[j]; K01[j] = Q01[j]; K10[j] = Q10[j]; K11[j] = Q11[j];
    }
    for (int sq = 0; sq < 2; ++sq) {  // -> M^16
#pragma unroll
      for (int j = 0; j < 8; ++j) {
        float n00 = fmaf(Q00[j], Q00[j], Q01[j] * Q10[j]);
        float n01 = fmaf(Q00[j], Q01[j], Q01[j] * Q11[j]);
        float n10 = fmaf(Q10[j], Q00[j], Q11[j] * Q10[j]);
        float n11 = fmaf(Q10[j], Q01[j], Q11[j] * Q11[j]);
        Q00[j] = n00; Q01[j] = n01; Q10[j] = n10; Q11[j] = n11;
      }
    }
    float T00[8], T01[8], T10[8], T11[8];
#pragma unroll
    for (int j = 0; j < 8; ++j) {  // M^20 = M^16 * M^4
      float n00 = fmaf(Q00[j], K00[j], Q01[j] * K10[j]);
      float n01 = fmaf(Q00[j], K01[j], Q01[j] * K11[j]);
      float n10 = fmaf(Q10[j], K00[j], Q11[j] * K10[j]);
      float n11 = fmaf(Q10[j], K01[j], Q11[j] * K11[j]);
      Q00[j] = n00; Q01[j] = n01; Q10[j] = n10; Q11[j] = n11;
      T00[j] = n00; T01[j] = n01; T10[j] = n10; T11[j] = n11;
    }
    for (int off = 1; off <= 32; off <<= 1) {
#pragma unroll
      for (int j = 0; j < 8; ++j) {
        float u0 = __shfl_up(cv0[j], off);
        float u1 = __shfl_up(cv1[j], off);
        if (lane >= off) {
          float nc0 = fmaf(Q00[j], u0, fmaf(Q01[j], u1, cv0[j]));
          float nc1 = fmaf(Q10[j], u0, fmaf(Q11[j], u1, cv1[j]));
          cv0[j] = nc0;
          cv1[j] = nc1;
        }
        float n00 = fmaf(Q00[j], Q00[j], Q01[j] * Q10[j]);
        float n01 = fmaf(Q00[j], Q01[j], Q01[j] * Q11[j]);
        float n10 = fmaf(Q10[j], Q00[j], Q11[j] * Q10[j]);
        float n11 = fmaf(Q10[j], Q01[j], Q11[j] * Q11[j]);
        Q00[j] = n00; Q01[j] = n01; Q10[j] = n10; Q11[j] = n11;
      }
    }
    __syncthreads();
    if (lane == 63) {
#pragma unroll
      for (int j = 0; j < 8; ++j) {
        lc0[wid][j] = cv0[j];
        lc1[wid][j] = cv1[j];
      }
    }
    __syncthreads();
    float car0[8], car1[8];
#pragma unroll
    for (int j = 0; j < 8; ++j) car0[j] = car1[j] = 0.f;
    for (int v = 0; v < wid; ++v) {
#pragma unroll
      for (int j = 0; j < 8; ++j) {
        float n0c = fmaf(Q00[j], car0[j], fmaf(Q01[j], car1[j], lc0[v][j]));
        float n1c = fmaf(Q10[j], car0[j], fmaf(Q11[j], car1[j], lc1[v][j]));
        car0[j] = n0c;
        car1[j] = n1c;
      }
    }
    float R00[8], R01[8], R10[8], R11[8];
#pragma unroll
    for (int j = 0; j < 8; ++j) {
      R00[j] = 1.f; R01[j] = 0.f; R10[j] = 0.f; R11[j] = 1.f;
    }
    for (int bit = 0; bit < 6; ++bit) {
      bool on = (lane >> bit) & 1;
#pragma unroll
      for (int j = 0; j < 8; ++j) {
        if (on) {
          float n00 = fmaf(T00[j], R00[j], T01[j] * R10[j]);
          float n01 = fmaf(T00[j], R01[j], T01[j] * R11[j]);
          float n10 = fmaf(T10[j], R00[j], T11[j] * R10[j]);
          float n11 = fmaf(T10[j], R01[j], T11[j] * R11[j]);
          R00[j] = n00; R01[j] = n01; R10[j] = n10; R11[j] = n11;
        }
        float s00 = fmaf(T00[j], T00[j], T01[j] * T10[j]);
        float s01 = fmaf(T00[j], T01[j], T01[j] * T11[j]);
        float s10 = fmaf(T10[j], T00[j], T11[j] * T10[j]);
        float s11 = fmaf(T10[j], T01[j], T11[j] * T11[j]);
        T00[j] = s00; T01[j] = s01; T10[j] = s10; T11[j] = s11;
      }
    }
    float y1[8], y2[8];
#pragma unroll
    for (int j = 0; j < 8; ++j) {
      float e0 = __shfl_up(cv0[j], 1);
      float e1 = __shfl_up(cv1[j], 1);
      if (lane == 0) { e0 = 0.f; e1 = 0.f; }
      y1[j] = fmaf(R00[j], car0[j], fmaf(R01[j], car1[j], e0));
      y2[j] = fmaf(R10[j], car0[j], fmaf(R11[j], car1[j], e1));
    }
    if (tb + 20 > n0) {
      for (int i = 0; i < 5; ++i) {
        float4 xv = *(const float4*)&sl[tb - s2 + 4 * i];
        float4 ov = acc[i];
#pragma unroll
        for (int e = 0; e < 4; ++e) {
          float xi = e == 0 ? xv.x : e == 1 ? xv.y : e == 2 ? xv.z : xv.w;
          float a = 0.f;
#pragma unroll
          for (int j = 0; j < 8; ++j) {
            float yv = fmaf(B0[j], xi, -fmaf(A1[j], y1[j], A2[j] * y2[j]));
            y2[j] = y1[j];
            y1[j] = yv;
            a = fmaf(GN[j], yv, a);
          }
          if (e == 0) ov.x += a;
          else if (e == 1) ov.y += a;
          else if (e == 2) ov.z += a;
          else ov.w += a;
        }
        acc[i] = ov;
      }
    }
  }
  if (tb + 20 > n0) {
    float* outb = out + (size_t)b * NSAMP;
#pragma unroll
    for (int i = 0; i < 5; ++i) {
      int n = tb + 4 * i;
      if (n >= n0) *(float4*)&outb[n] = acc[i];
    }
  }
}

// ======== single kernel: 256 KS blocks + 256 body blocks, flag handoff ========
__global__ void __launch_bounds__(256, 1) synth_all(
    const float* __restrict__ exc, const float* __restrict__ pitch,
    const float* __restrict__ w1, const float* __restrict__ b1,
    const float* __restrict__ w2, const float* __restrict__ b2,
    const float* __restrict__ eg, const float* __restrict__ gains,
    float* __restrict__ buf1, int* __restrict__ flags,
    float* __restrict__ out) {
  const int blk = blockIdx.x;
  const int t = threadIdx.x;
  __shared__ __align__(16) float smem[8264];

  if (blk < 256) {
    // ---- KS producer: b = blk>>5, q = blk&31 ----
    const int b = blk >> 5, q = blk & 31;
    BParams P = compute_params(b, pitch, w1, b1, w2, b2);
    if (blk == 0 && t < 64) {
      int bb = (t < 8) ? t : 0;
      BParams Q = compute_params(bb, pitch, w1, b1, w2, b2);
      float slc = 0.f, slm = 0.f, slp = 0.f;
      for (int i = 0; i < 8; ++i) {
        slc += rlv(Q.lc, i);
        slm += rlv(Q.lm, i);
        slp += rlv(Q.lp, i);
      }
      if (t == 0) {
        out[8 * NSAMP + 0] = slc / 8.0f;
        out[8 * NSAMP + 1] = slm / 8.0f;
        out[8 * NSAMP + 2] = slp / 8.0f;
      }
    }
    ks_phase(b, q, P, exc, eg[0], buf1, smem, smem + 8192, smem + 8256, t);
    __syncthreads();  // drain all waves' global stores (vmcnt)
    if (t == 0)
      __hip_atomic_store(&flags[b * 32 + q], FLAG_MAGIC, __ATOMIC_RELEASE,
                         __HIP_MEMORY_SCOPE_AGENT);
  } else {
    // ---- body consumer: b = (blk-256)>>5, q = (blk-256)&31 ----
    const int blk2 = blk - 256;
    const int b = blk2 >> 5, q = blk2 & 31;
    const int n0 = q << 10;
    int s2 = n0 - 4096 - 256;
    if (s2 < 0) s2 = 0;
    const int qlo = s2 >> 10;
    if (t == 0) {
      for (int f = qlo; f <= q; ++f) {
        while (__hip_atomic_load(&flags[b * 32 + f], __ATOMIC_ACQUIRE,
                                 __HIP_MEMORY_SCOPE_AGENT) != FLAG_MAGIC) {
          __builtin_amdgcn_s_sleep(32);  // ~2k cyc backoff: don't hammer L2
        }
      }
    }
    __syncthreads();
    BParams P = compute_params(b, pitch, w1, b1, w2, b2);
    body_phase(b, q, P, gains, buf1, out, smem, smem + 6144,
               (float(*)[8])(smem + 6152), (float(*)[8])(smem + 6184), t);
  }
}

extern "C" void kernel_launch(void* const* d_in, const int* in_sizes, int n_in,
                              void* d_out, int out_size, void* d_ws, size_t ws_size,
                              hipStream_t stream) {
  const float* exc = (const float*)d_in[0];
  const float* pitch = (const float*)d_in[1];
  const float* w1 = (const float*)d_in[2];
  const float* b1 = (const float*)d_in[3];
  const float* w2 = (const float*)d_in[4];
  const float* b2 = (const float*)d_in[5];
  const float* eg = (const float*)d_in[6];
  const float* bg = (const float*)d_in[7];
  float* out = (float*)d_out;
  float* buf1 = (float*)d_ws;                  // 8*NSAMP floats (KS output)
  int* flags = (int*)(buf1 + 8 * NSAMP);       // 256 flags (poison != MAGIC)

  hipLaunchKernelGGL(synth_all, dim3(512), dim3(256), 0, stream, exc, pitch,
                     w1, b1, w2, b2, eg, bg, buf1, flags, out);
}

// Round 14
// 132.296 us; speedup vs baseline: 1.5036x; 1.0165x over previous
//
#include <hip/hip_runtime.h>
#include <math.h>

#define NSAMP 32768
#define FS_F 44100.0f
#define PI_F 3.14159265358979323846f
#define T1 1024  // KS slice length (32 slices/batch)
#define FLAG_MAGIC 0x5A5A5A5A

struct BParams {
  float alpha, alpha_p;
  float fr, g, s;
  int Di;
  float lc, lm, lp;
};

__device__ inline float sigmoidf_(float x) { return 1.0f / (1.0f + expf(-x)); }

__device__ inline BParams compute_params(int b, const float* __restrict__ pitch,
                                         const float* __restrict__ w1,
                                         const float* __restrict__ b1,
                                         const float* __restrict__ w2,
                                         const float* __restrict__ b2) {
  BParams P;
  float p = pitch[b];
  float h[16];
#pragma unroll
  for (int i = 0; i < 16; ++i) {
    float v = fmaf(p, w1[i], b1[i]);
    h[i] = v > 0.0f ? v : 0.0f;
  }
  float m[3];
#pragma unroll
  for (int j = 0; j < 3; ++j) {
    float acc = b2[j];
#pragma unroll
    for (int i = 0; i < 16; ++i) acc = fmaf(h[i], w2[j * 16 + i], acc);
    m[j] = acc;
  }
  P.lc = fminf(fmaxf(m[0], -2.0f), 2.5f);
  P.lm = fminf(fmaxf(m[1], -2.5f), 0.0f);
  P.lp = fminf(fmaxf(m[2], -4.0f), 4.0f);
  P.g = 0.999f * sigmoidf_(P.lc);
  P.s = sigmoidf_(P.lm);
  float f0 = fmaxf(p, 60.0f);
  float D = fminf(fmaxf(FS_F / f0, 2.0f), 735.0f);
  int Di = (int)floorf(D);
  P.fr = D - (float)Di;
  P.Di = Di;
  float mult = fminf(fmaxf(2.0f + 6.0f * (f0 - 60.0f) / 600.0f, 2.0f), 8.0f);
  float cutoff = fminf(2.0f * PI_F * f0 * mult / FS_F, PI_F * 0.9f);
  P.alpha = 1.0f - expf(-cutoff);
  float cpost = fminf(PI_F * sigmoidf_(P.lp), PI_F * 0.99f);
  P.alpha_p = 1.0f - expf(-cpost);
  return P;
}

// lane helpers (wave64)
__device__ inline float rl63(float v) {
  return __int_as_float(__builtin_amdgcn_readlane(__float_as_int(v), 63));
}
__device__ inline float rlv(float v, int l) {
  return __int_as_float(__builtin_amdgcn_readlane(__float_as_int(v), l));
}
__device__ inline float shr1(float v, float bnd) {
  return __int_as_float(__builtin_amdgcn_update_dpp(
      __float_as_int(bnd), __float_as_int(v), 0x138 /*wave_shr:1*/, 0xf, 0xf,
      false));
}

// Block barrier draining ONLY lgkmcnt (keeps global stores in flight).
__device__ inline void barrier_lgkm() {
  asm volatile("s_waitcnt lgkmcnt(0)\n\ts_barrier" ::: "memory");
}

__device__ inline void band_coef(int k, float& a1, float& a2, float& b0) {
  float fc = 80.0f * exp2f((float)k * (6.64385618977472436f / 23.0f));
  float w = 2.0f * PI_F * fc / FS_F;
  float r = expf(-PI_F * fc / (10.0f * FS_F));
  a1 = -2.0f * r * cosf(w);
  a2 = r * r;
  b0 = 1.0f - r;
}

// ---- on-the-fly preLP scan context ----
struct SCtx {
  const float* exc_b;
  float scale, c;
  float m1, m2, m4, m8, m16, m32, c512, c2048, c8lane, cgk;
  float vrun;
  int s1;
  float* lws;
};

__device__ inline void scan_seg(SCtx& SC, float* xbuf, int seg, bool write,
                                int t) {
  const int lane = t & 63, wid = t >> 6;
  const int rel0 = seg << 11;
  const int A = SC.s1 + rel0;
  __syncthreads();
  const int g0 = A + 8 * t;
  float4 xa = make_float4(0.f, 0.f, 0.f, 0.f);
  float4 xb = make_float4(0.f, 0.f, 0.f, 0.f);
  if (g0 >= 0 && g0 + 3 < NSAMP) xa = *(const float4*)&SC.exc_b[g0];
  if (g0 + 4 >= 0 && g0 + 7 < NSAMP) xb = *(const float4*)&SC.exc_b[g0 + 4];
  const float c = SC.c, scale = SC.scale;
  float S = 0.0f;
  S = fmaf(c, S, scale * xa.x); S = fmaf(c, S, scale * xa.y);
  S = fmaf(c, S, scale * xa.z); S = fmaf(c, S, scale * xa.w);
  S = fmaf(c, S, scale * xb.x); S = fmaf(c, S, scale * xb.y);
  S = fmaf(c, S, scale * xb.z); S = fmaf(c, S, scale * xb.w);
  float Sw = S, u;
  u = __shfl_up(Sw, 1);  if (lane >= 1)  Sw = fmaf(SC.m1, u, Sw);
  u = __shfl_up(Sw, 2);  if (lane >= 2)  Sw = fmaf(SC.m2, u, Sw);
  u = __shfl_up(Sw, 4);  if (lane >= 4)  Sw = fmaf(SC.m4, u, Sw);
  u = __shfl_up(Sw, 8);  if (lane >= 8)  Sw = fmaf(SC.m8, u, Sw);
  u = __shfl_up(Sw, 16); if (lane >= 16) Sw = fmaf(SC.m16, u, Sw);
  u = __shfl_up(Sw, 32); if (lane >= 32) Sw = fmaf(SC.m32, u, Sw);
  if (lane == 63) SC.lws[wid] = Sw;
  __syncthreads();
  float a0 = SC.lws[0], a1w = SC.lws[1], a2w = SC.lws[2], a3w = SC.lws[3];
  float carry = (wid == 1)   ? a0
                : (wid == 2) ? fmaf(SC.c512, a0, a1w)
                : (wid == 3) ? fmaf(SC.c512, fmaf(SC.c512, a0, a1w), a2w)
                             : 0.0f;
  float Sprev = __shfl_up(Sw, 1);
  float Sex = (lane == 0) ? 0.0f : Sprev;
  Sex = fmaf(SC.c8lane, carry, Sex);
  float v = fmaf(SC.cgk, SC.vrun, Sex);
  float4 ya, yb;
  v = fmaf(c, v, scale * xa.x); ya.x = v;
  v = fmaf(c, v, scale * xa.y); ya.y = v;
  v = fmaf(c, v, scale * xa.z); ya.z = v;
  v = fmaf(c, v, scale * xa.w); ya.w = v;
  v = fmaf(c, v, scale * xb.x); yb.x = v;
  v = fmaf(c, v, scale * xb.y); yb.y = v;
  v = fmaf(c, v, scale * xb.z); yb.z = v;
  v = fmaf(c, v, scale * xb.w); yb.w = v;
  if (write) {
    int o = (rel0 + 8 * t) & 8191;
    *(float4*)&xbuf[o] = ya;
    *(float4*)&xbuf[o + 4] = yb;
  }
  float tS = fmaf(SC.c512, fmaf(SC.c512, fmaf(SC.c512, a0, a1w), a2w), a3w);
  SC.vrun = fmaf(SC.c2048, SC.vrun, tS);
}

// KS slice compute (R11, proven): lean warm-up + full loops, 3-deep prefetch.
template <int KNUM>
__device__ void ks_slice2(SCtx& SC, float* __restrict__ yg, float* xbuf,
                          float* bnd, int t, int C, float c0w, float c1w,
                          float c2w, int s1, int n0, int end, int span,
                          int nseg) {
  const int lane = t & 63;
  const int wid = t >> 6;
  const int lq1 = (C - 1) - (KNUM - 1) * 64;
  const int W = n0 - s1;

  if (KNUM <= 3) {
    float yp[KNUM], xC[KNUM], xN[KNUM], xN2[KNUM];
    float p1 = 0.f, p2 = 0.f;
    int rel = 0;
#pragma unroll
    for (int k = 0; k < KNUM; ++k) {
      yp[k] = 0.f; xC[k] = 0.f; xN[k] = 0.f; xN2[k] = 0.f;
    }
    for (int s = 0; s < nseg; ++s) {
      barrier_lgkm();
      if (wid == 0) {
        if (s == 0) {
#pragma unroll
          for (int k = 0; k < KNUM; ++k) {
            int i = lane + (k << 6);
            xC[k] = xbuf[i];
            xN[k] = xbuf[C + i];
            xN2[k] = xbuf[2 * C + i];
          }
        }
        int fence = (s + 1) << 11;
        if (fence > span) fence = span;
        while (rel + C <= W && rel < fence) {
          float b2v[KNUM], b3v[KNUM];
#pragma unroll
          for (int k = 0; k < KNUM; ++k)
            b2v[k] = shr1(yp[k], (k == 0) ? p1 : rl63(yp[k - 1]));
#pragma unroll
          for (int k = 0; k < KNUM; ++k)
            b3v[k] = shr1(b2v[k], (k == 0) ? p2 : rlv(yp[k - 1], 62));
          float p1n = rlv(yp[KNUM - 1], lq1);
          float p2n = rlv(b2v[KNUM - 1], lq1);
#pragma unroll
          for (int k = 0; k < KNUM; ++k)
            yp[k] = fmaf(c0w, yp[k],
                         fmaf(c2w, b3v[k], fmaf(c1w, b2v[k], xC[k])));
          p1 = p1n;
          p2 = p2n;
#pragma unroll
          for (int k = 0; k < KNUM; ++k) {
            xC[k] = xN[k];
            xN[k] = xN2[k];
            xN2[k] = xbuf[(rel + 3 * C + lane + (k << 6)) & 8191];
          }
          rel += C;
        }
        while (rel < fence) {
          float b2v[KNUM], b3v[KNUM];
#pragma unroll
          for (int k = 0; k < KNUM; ++k)
            b2v[k] = shr1(yp[k], (k == 0) ? p1 : rl63(yp[k - 1]));
#pragma unroll
          for (int k = 0; k < KNUM; ++k)
            b3v[k] = shr1(b2v[k], (k == 0) ? p2 : rlv(yp[k - 1], 62));
          float p1n = rlv(yp[KNUM - 1], lq1);
          float p2n = rlv(b2v[KNUM - 1], lq1);
#pragma unroll
          for (int k = 0; k < KNUM; ++k)
            yp[k] = fmaf(c0w, yp[k],
                         fmaf(c2w, b3v[k], fmaf(c1w, b2v[k], xC[k])));
          p1 = p1n;
          p2 = p2n;
#pragma unroll
          for (int k = 0; k < KNUM; ++k) {
            int i = lane + (k << 6);
            int n = s1 + rel + i;
            bool okl = (k < KNUM - 1) || (lane <= lq1);
            if (okl && n >= n0 && n < end) yg[n] = yp[k];
          }
#pragma unroll
          for (int k = 0; k < KNUM; ++k) {
            xC[k] = xN[k];
            xN[k] = xN2[k];
            xN2[k] = xbuf[(rel + 3 * C + lane + (k << 6)) & 8191];
          }
          rel += C;
        }
      }
      barrier_lgkm();
      int ls = s + 3;
      if (ls < nseg) scan_seg(SC, xbuf, ls, true, t);
    }
  } else {
    constexpr int SPW = (KNUM + 3) / 4;
    const int kbase = wid * SPW;
    float yp[SPW], xC[SPW], xN[SPW], xN2[SPW];
    int rel = 0, par = 0;
#pragma unroll
    for (int kk = 0; kk < SPW; ++kk) {
      yp[kk] = 0.f; xC[kk] = 0.f; xN[kk] = 0.f; xN2[kk] = 0.f;
    }
    for (int s = 0; s < nseg; ++s) {
      barrier_lgkm();
      if (s == 0) {
#pragma unroll
        for (int kk = 0; kk < SPW; ++kk) {
          int k = kbase + kk;
          if (k < KNUM) {
            int i = lane + (k << 6);
            xC[kk] = xbuf[i];
            xN[kk] = xbuf[C + i];
            xN2[kk] = xbuf[2 * C + i];
          }
        }
      }
      int fence = (s + 1) << 11;
      if (fence > span) fence = span;
      while (rel < fence) {
        const bool lean = (rel + C <= W);
        barrier_lgkm();
        const int rb = par << 5, wb = rb ^ 32;
        float pbA = 0.f, pbB = 0.f;
        if (kbase == 0) {
          pbA = bnd[rb + 24];
          pbB = bnd[rb + 25];
        } else if (kbase < KNUM) {
          pbA = bnd[rb + (kbase - 1) * 2];
          pbB = bnd[rb + (kbase - 1) * 2 + 1];
        }
        float b2v[SPW], b3v[SPW];
#pragma unroll
        for (int kk = 0; kk < SPW; ++kk) {
          int k = kbase + kk;
          if (k < KNUM)
            b2v[kk] = shr1(yp[kk], (kk == 0) ? pbA : rl63(yp[kk - 1]));
        }
#pragma unroll
        for (int kk = 0; kk < SPW; ++kk) {
          int k = kbase + kk;
          if (k < KNUM)
            b3v[kk] = shr1(b2v[kk], (kk == 0) ? pbB : rlv(yp[kk - 1], 62));
        }
        float p1n = 0.f, p2n = 0.f;
        const bool ownLast = (KNUM - 1 >= kbase) && (KNUM - 1 < kbase + SPW);
        if (ownLast) {
          p1n = rlv(yp[KNUM - 1 - kbase], lq1);
          p2n = rlv(b2v[KNUM - 1 - kbase], lq1);
        }
#pragma unroll
        for (int kk = 0; kk < SPW; ++kk) {
          int k = kbase + kk;
          if (k < KNUM)
            yp[kk] = fmaf(c0w, yp[kk],
                          fmaf(c2w, b3v[kk], fmaf(c1w, b2v[kk], xC[kk])));
        }
        if (!lean) {
#pragma unroll
          for (int kk = 0; kk < SPW; ++kk) {
            int k = kbase + kk;
            if (k < KNUM) {
              int i = lane + (k << 6);
              int n = s1 + rel + i;
              bool okl = (k < KNUM - 1) || (lane <= lq1);
              if (okl && n >= n0 && n < end) yg[n] = yp[kk];
            }
          }
        }
#pragma unroll
        for (int kk = 0; kk < SPW; ++kk) {
          int k = kbase + kk;
          if (k < KNUM) {
            float h63 = rlv(yp[kk], 63);
            float h62 = rlv(yp[kk], 62);
            if (lane == 0) {
              bnd[wb + k * 2] = h63;
              bnd[wb + k * 2 + 1] = h62;
            }
          }
        }
        if (ownLast && lane == 0) {
          bnd[wb + 24] = p1n;
          bnd[wb + 25] = p2n;
        }
#pragma unroll
        for (int kk = 0; kk < SPW; ++kk) {
          int k = kbase + kk;
          if (k < KNUM) {
            xC[kk] = xN[kk];
            xN[kk] = xN2[kk];
            xN2[kk] = xbuf[(rel + 3 * C + lane + (k << 6)) & 8191];
          }
        }
        rel += C;
        par ^= 1;
      }
      barrier_lgkm();
      int ls = s + 3;
      if (ls < nseg) scan_seg(SC, xbuf, ls, true, t);
    }
  }
}

// One-pole scan over [s2, s2+nt*2048) from global into LDS sl[n-s2], reads
// clamped at `lim`.
__device__ inline void lpc_lds(const float* __restrict__ xg,
                               float* __restrict__ sl, int s2, int nt, int lim,
                               float scale, float c, int t, float* lws) {
  const int lane = t & 63, wid = t >> 6;
  float c2v = c * c, c4 = c2v * c2v, c8 = c4 * c4;
  float m1 = c8, m2 = m1 * m1, m4 = m2 * m2, m8 = m4 * m4, m16 = m8 * m8,
        m32 = m16 * m16;
  float c512 = m32 * m32;
  float c2048 = c512 * c512;
  c2048 *= c2048;
  float l2c = log2f(c);
  float c8lane = exp2f((float)(8 * lane) * l2c);
  float cgk = exp2f((float)(8 * t) * l2c);
  float vrun = 0.0f;
  for (int tile = 0; tile < nt; ++tile) {
    __syncthreads();
    int g0 = s2 + (tile << 11) + 8 * t;
    float4 xa = make_float4(0.f, 0.f, 0.f, 0.f);
    float4 xb = make_float4(0.f, 0.f, 0.f, 0.f);
    if (g0 + 3 < lim) xa = *(const float4*)&xg[g0];
    if (g0 + 7 < lim) xb = *(const float4*)&xg[g0 + 4];
    float S = 0.0f;
    S = fmaf(c, S, scale * xa.x); S = fmaf(c, S, scale * xa.y);
    S = fmaf(c, S, scale * xa.z); S = fmaf(c, S, scale * xa.w);
    S = fmaf(c, S, scale * xb.x); S = fmaf(c, S, scale * xb.y);
    S = fmaf(c, S, scale * xb.z); S = fmaf(c, S, scale * xb.w);
    float Sw = S, u;
    u = __shfl_up(Sw, 1);  if (lane >= 1)  Sw = fmaf(m1, u, Sw);
    u = __shfl_up(Sw, 2);  if (lane >= 2)  Sw = fmaf(m2, u, Sw);
    u = __shfl_up(Sw, 4);  if (lane >= 4)  Sw = fmaf(m4, u, Sw);
    u = __shfl_up(Sw, 8);  if (lane >= 8)  Sw = fmaf(m8, u, Sw);
    u = __shfl_up(Sw, 16); if (lane >= 16) Sw = fmaf(m16, u, Sw);
    u = __shfl_up(Sw, 32); if (lane >= 32) Sw = fmaf(m32, u, Sw);
    if (lane == 63) lws[wid] = Sw;
    __syncthreads();
    float a0 = lws[0], a1w = lws[1], a2w = lws[2], a3w = lws[3];
    float carry = (wid == 1)   ? a0
                  : (wid == 2) ? fmaf(c512, a0, a1w)
                  : (wid == 3) ? fmaf(c512, fmaf(c512, a0, a1w), a2w)
                               : 0.0f;
    float Sprev = __shfl_up(Sw, 1);
    float Sex = (lane == 0) ? 0.0f : Sprev;
    Sex = fmaf(c8lane, carry, Sex);
    float v = fmaf(cgk, vrun, Sex);
    int o = g0 - s2;
    float4 ya, yb;
    v = fmaf(c, v, scale * xa.x); ya.x = v;
    v = fmaf(c, v, scale * xa.y); ya.y = v;
    v = fmaf(c, v, scale * xa.z); ya.z = v;
    v = fmaf(c, v, scale * xa.w); ya.w = v;
    v = fmaf(c, v, scale * xb.x); yb.x = v;
    v = fmaf(c, v, scale * xb.y); yb.y = v;
    v = fmaf(c, v, scale * xb.z); yb.z = v;
    v = fmaf(c, v, scale * xb.w); yb.w = v;
    *(float4*)&sl[o] = ya;
    *(float4*)&sl[o + 4] = yb;
    float tS = fmaf(c512, fmaf(c512, fmaf(c512, a0, a1w), a2w), a3w);
    vrun = fmaf(c2048, vrun, tS);
  }
}

// ---- KS phase driver (Wp cap 64) ----
__device__ inline void ks_phase(int b, int q, const BParams& P,
                                const float* __restrict__ exc, float scale0,
                                float* __restrict__ buf1, float* xbuf,
                                float* bnd, float* lws, int t) {
  const int C = P.Di;
  const int n0 = q << 10;
  float lg = -logf(P.g);
  int Wp = (int)ceilf(10.5f / fmaxf(lg, 1e-6f));
  if (Wp > 64) Wp = 64;
  if (Wp < 4) Wp = 4;
  int W = Wp * C;
  if (W > n0) W = n0;
  W = (W + 3) & ~3;
  const int s1 = n0 - W;
  const int span = W + T1;
  const int end = n0 + T1;
  const int nseg = (span + 2047) >> 11;
  float* yg = buf1 + (size_t)b * NSAMP;

  SCtx SC;
  SC.exc_b = exc + (size_t)b * NSAMP;
  SC.c = 1.0f - P.alpha;
  SC.scale = scale0 * P.alpha;
  {
    float c = SC.c;
    float c2v = c * c, c4 = c2v * c2v, c8 = c4 * c4;
    SC.m1 = c8;
    SC.m2 = SC.m1 * SC.m1;
    SC.m4 = SC.m2 * SC.m2;
    SC.m8 = SC.m4 * SC.m4;
    SC.m16 = SC.m8 * SC.m8;
    SC.m32 = SC.m16 * SC.m16;
    SC.c512 = SC.m32 * SC.m32;
    float c1024 = SC.c512 * SC.c512;
    SC.c2048 = c1024 * c1024;
    float l2c = log2f(c);
    SC.c8lane = exp2f((float)(8 * (t & 63)) * l2c);
    SC.cgk = exp2f((float)(8 * t) * l2c);
  }
  SC.vrun = 0.0f;
  SC.s1 = s1;
  SC.lws = lws;

  if (s1 > 0) scan_seg(SC, xbuf, -1, false, t);
  scan_seg(SC, xbuf, 0, true, t);
  scan_seg(SC, xbuf, 1, true, t);
  scan_seg(SC, xbuf, 2, true, t);
  if (t < 64) bnd[t] = 0.0f;

  const float c0w = P.g * (1.0f - P.s) * (1.0f - P.fr);
  const float c1w = P.g * ((1.0f - P.s) * P.fr + P.s * (1.0f - P.fr));
  const float c2w = P.g * P.s * P.fr;
  switch ((C + 63) >> 6) {
    case 2:  ks_slice2<2>(SC, yg, xbuf, bnd, t, C, c0w, c1w, c2w, s1, n0, end, span, nseg); break;
    case 3:  ks_slice2<3>(SC, yg, xbuf, bnd, t, C, c0w, c1w, c2w, s1, n0, end, span, nseg); break;
    case 4:  ks_slice2<4>(SC, yg, xbuf, bnd, t, C, c0w, c1w, c2w, s1, n0, end, span, nseg); break;
    case 5:  ks_slice2<5>(SC, yg, xbuf, bnd, t, C, c0w, c1w, c2w, s1, n0, end, span, nseg); break;
    case 6:  ks_slice2<6>(SC, yg, xbuf, bnd, t, C, c0w, c1w, c2w, s1, n0, end, span, nseg); break;
    case 7:  ks_slice2<7>(SC, yg, xbuf, bnd, t, C, c0w, c1w, c2w, s1, n0, end, span, nseg); break;
    case 8:  ks_slice2<8>(SC, yg, xbuf, bnd, t, C, c0w, c1w, c2w, s1, n0, end, span, nseg); break;
    case 9:  ks_slice2<9>(SC, yg, xbuf, bnd, t, C, c0w, c1w, c2w, s1, n0, end, span, nseg); break;
    case 10: ks_slice2<10>(SC, yg, xbuf, bnd, t, C, c0w, c1w, c2w, s1, n0, end, span, nseg); break;
    case 11: ks_slice2<11>(SC, yg, xbuf, bnd, t, C, c0w, c1w, c2w, s1, n0, end, span, nseg); break;
    default: ks_slice2<12>(SC, yg, xbuf, bnd, t, C, c0w, c1w, c2w, s1, n0, end, span, nseg); break;
  }
}

// ---- body phase, T2=1024 (R12/R13, proven) ----
__device__ inline void body_phase(int b, int q, const BParams& P,
                                  const float* __restrict__ gains,
                                  const float* __restrict__ buf1,
                                  float* __restrict__ out, float* sl,
                                  float* lws, float (*lc0)[8],
                                  float (*lc1)[8], int t) {
  const int lane = t & 63, wid = t >> 6;
  const int n0 = q << 10;
  const int base = n0 - 4096;
  int s2 = base - 256;
  if (s2 < 0) s2 = 0;
  const int end = n0 + 1024;
  const int nt = (end - s2 + 2047) >> 11;  // <= 3

  lpc_lds(buf1 + (size_t)b * NSAMP, sl, s2, nt, end, P.alpha_p,
          1.0f - P.alpha_p, t, lws);
  __syncthreads();

  const int tb = base + 20 * t;
  float4 acc[5];
#pragma unroll
  for (int i = 0; i < 5; ++i) acc[i] = make_float4(0.f, 0.f, 0.f, 0.f);

  for (int g = 0; g < 3; ++g) {
    float A1[8], A2[8], B0[8], GN[8];
#pragma unroll
    for (int j = 0; j < 8; ++j) {
      int k = g * 8 + j;
      band_coef(k, A1[j], A2[j], B0[j]);
      GN[j] = gains[k];
    }
    float cv0[8], cv1[8];
#pragma unroll
    for (int j = 0; j < 8; ++j) cv0[j] = cv1[j] = 0.f;
    for (int i = 0; i < 5; ++i) {
      int n = tb + 4 * i;
      float4 xv = make_float4(0.f, 0.f, 0.f, 0.f);
      if (n >= 0) xv = *(const float4*)&sl[n - s2];
#pragma unroll
      for (int e = 0; e < 4; ++e) {
        float xi = e == 0 ? xv.x : e == 1 ? xv.y : e == 2 ? xv.z : xv.w;
#pragma unroll
        for (int j = 0; j < 8; ++j) {
          float nc = fmaf(B0[j], xi, -fmaf(A1[j], cv0[j], A2[j] * cv1[j]));
          cv1[j] = cv0[j];
          cv0[j] = nc;
        }
      }
    }
    // Q = M^20 = M^16 * M^4 ; T snapshot
    float Q00[8], Q01[8], Q10[8], Q11[8];
    float K00[8], K01[8], K10[8], K11[8];
#pragma unroll
    for (int j = 0; j < 8; ++j) {
      Q00[j] = -A1[j]; Q01[j] = -A2[j]; Q10[j] = 1.f; Q11[j] = 0.f;
    }
    for (int sq = 0; sq < 2; ++sq) {
#pragma unroll
      for (int j = 0; j < 8; ++j) {
        float n00 = fmaf(Q00[j], Q00[j], Q01[j] * Q10[j]);
        float n01 = fmaf(Q00[j], Q01[j], Q01[j] * Q11[j]);
        float n10 = fmaf(Q10[j], Q00[j], Q11[j] * Q10[j]);
        float n11 = fmaf(Q10[j], Q01[j], Q11[j] * Q11[j]);
        Q00[j] = n00; Q01[j] = n01; Q10[j] = n10; Q11[j] = n11;
      }
    }
#pragma unroll
    for (int j = 0; j < 8; ++j) {
      K00[j] = Q00[j]; K01[j] = Q01[j]; K10[j] = Q10[j]; K11[j] = Q11[j];
    }
    for (int sq = 0; sq < 2; ++sq) {
#pragma unroll
      for (int j = 0; j < 8; ++j) {
        float n00 = fmaf(Q00[j], Q00[j], Q01[j] * Q10[j]);
        float n01 = fmaf(Q00[j], Q01[j], Q01[j] * Q11[j]);
        float n10 = fmaf(Q10[j], Q00[j], Q11[j] * Q10[j]);
        float n11 = fmaf(Q10[j], Q01[j], Q11[j] * Q11[j]);
        Q00[j] = n00; Q01[j] = n01; Q10[j] = n10; Q11[j] = n11;
      }
    }
    float T00[8], T01[8], T10[8], T11[8];
#pragma unroll
    for (int j = 0; j < 8; ++j) {
      float n00 = fmaf(Q00[j], K00[j], Q01[j] * K10[j]);
      float n01 = fmaf(Q00[j], K01[j], Q01[j] * K11[j]);
      float n10 = fmaf(Q10[j], K00[j], Q11[j] * K10[j]);
      float n11 = fmaf(Q10[j], K01[j], Q11[j] * K11[j]);
      Q00[j] = n00; Q01[j] = n01; Q10[j] = n10; Q11[j] = n11;
      T00[j] = n00; T01[j] = n01; T10[j] = n10; T11[j] = n11;
    }
    for (int off = 1; off <= 32; off <<= 1) {
#pragma unroll
      for (int j = 0; j < 8; ++j) {
        float u0 = __shfl_up(cv0[j], off);
        float u1 = __shfl_up(cv1[j], off);
        if (lane >= off) {
          float nc0 = fmaf(Q00[j], u0, fmaf(Q01[j], u1, cv0[j]));
          float nc1 = fmaf(Q10[j], u0, fmaf(Q11[j], u1, cv1[j]));
          cv0[j] = nc0;
          cv1[j] = nc1;
        }
        float n00 = fmaf(Q00[j], Q00[j], Q01[j] * Q10[j]);
        float n01 = fmaf(Q00[j], Q01[j], Q01[j] * Q11[j]);
        float n10 = fmaf(Q10[j], Q00[j], Q11[j] * Q10[j]);
        float n11 = fmaf(Q10[j], Q01[j], Q11[j] * Q11[j]);
        Q00[j] = n00; Q01[j] = n01; Q10[j] = n10; Q11[j] = n11;
      }
    }
    __syncthreads();
    if (lane == 63) {
#pragma unroll
      for (int j = 0; j < 8; ++j) {
        lc0[wid][j] = cv0[j];
        lc1[wid][j] = cv1[j];
      }
    }
    __syncthreads();
    float car0[8], car1[8];
#pragma unroll
    for (int j = 0; j < 8; ++j) car0[j] = car1[j] = 0.f;
    for (int v = 0; v < wid; ++v) {
#pragma unroll
      for (int j = 0; j < 8; ++j) {
        float n0c = fmaf(Q00[j], car0[j], fmaf(Q01[j], car1[j], lc0[v][j]));
        float n1c = fmaf(Q10[j], car0[j], fmaf(Q11[j], car1[j], lc1[v][j]));
        car0[j] = n0c;
        car1[j] = n1c;
      }
    }
    float R00[8], R01[8], R10[8], R11[8];
#pragma unroll
    for (int j = 0; j < 8; ++j) {
      R00[j] = 1.f; R01[j] = 0.f; R10[j] = 0.f; R11[j] = 1.f;
    }
    for (int bit = 0; bit < 6; ++bit) {
      bool on = (lane >> bit) & 1;
#pragma unroll
      for (int j = 0; j < 8; ++j) {
        if (on) {
          float n00 = fmaf(T00[j], R00[j], T01[j] * R10[j]);
          float n01 = fmaf(T00[j], R01[j], T01[j] * R11[j]);
          float n10 = fmaf(T10[j], R00[j], T11[j] * R10[j]);
          float n11 = fmaf(T10[j], R01[j], T11[j] * R11[j]);
          R00[j] = n00; R01[j] = n01; R10[j] = n10; R11[j] = n11;
        }
        float s00 = fmaf(T00[j], T00[j], T01[j] * T10[j]);
        float s01 = fmaf(T00[j], T01[j], T01[j] * T11[j]);
        float s10 = fmaf(T10[j], T00[j], T11[j] * T10[j]);
        float s11 = fmaf(T10[j], T01[j], T11[j] * T11[j]);
        T00[j] = s00; T01[j] = s01; T10[j] = s10; T11[j] = s11;
      }
    }
    float y1[8], y2[8];
#pragma unroll
    for (int j = 0; j < 8; ++j) {
      float e0 = __shfl_up(cv0[j], 1);
      float e1 = __shfl_up(cv1[j], 1);
      if (lane == 0) { e0 = 0.f; e1 = 0.f; }
      y1[j] = fmaf(R00[j], car0[j], fmaf(R01[j], car1[j], e0));
      y2[j] = fmaf(R10[j], car0[j], fmaf(R11[j], car1[j], e1));
    }
    if (tb + 20 > n0) {
      for (int i = 0; i < 5; ++i) {
        float4 xv = *(const float4*)&sl[tb - s2 + 4 * i];
        float4 ov = acc[i];
#pragma unroll
        for (int e = 0; e < 4; ++e) {
          float xi = e == 0 ? xv.x : e == 1 ? xv.y : e == 2 ? xv.z : xv.w;
          float a = 0.f;
#pragma unroll
          for (int j = 0; j < 8; ++j) {
            float yv = fmaf(B0[j], xi, -fmaf(A1[j], y1[j], A2[j] * y2[j]));
            y2[j] = y1[j];
            y1[j] = yv;
            a = fmaf(GN[j], yv, a);
          }
          if (e == 0) ov.x += a;
          else if (e == 1) ov.y += a;
          else if (e == 2) ov.z += a;
          else ov.w += a;
        }
        acc[i] = ov;
      }
    }
  }
  if (tb + 20 > n0) {
    float* outb = out + (size_t)b * NSAMP;
#pragma unroll
    for (int i = 0; i < 5; ++i) {
      int n = tb + 4 * i;
      if (n >= n0) *(float4*)&outb[n] = acc[i];
    }
  }
}

// ======== single kernel, 256 blocks: block (b,q) does KS slice q THEN its
// own body slice q (waits only on same-batch neighbors q-5..q-1, which have
// equal-or-shorter chains -> ~zero wait). 1 block/CU. ========
__global__ void __launch_bounds__(256, 1) synth_all(
    const float* __restrict__ exc, const float* __restrict__ pitch,
    const float* __restrict__ w1, const float* __restrict__ b1,
    const float* __restrict__ w2, const float* __restrict__ b2,
    const float* __restrict__ eg, const float* __restrict__ gains,
    float* __restrict__ buf1, int* __restrict__ flags,
    float* __restrict__ out) {
  const int blk = blockIdx.x;
  const int b = blk >> 5, q = blk & 31;
  const int t = threadIdx.x;
  __shared__ __align__(16) float smem[8264];

  BParams P = compute_params(b, pitch, w1, b1, w2, b2);
  if (blk == 0 && t < 64) {
    int bb = (t < 8) ? t : 0;
    BParams Q = compute_params(bb, pitch, w1, b1, w2, b2);
    float slc = 0.f, slm = 0.f, slp = 0.f;
    for (int i = 0; i < 8; ++i) {
      slc += rlv(Q.lc, i);
      slm += rlv(Q.lm, i);
      slp += rlv(Q.lp, i);
    }
    if (t == 0) {
      out[8 * NSAMP + 0] = slc / 8.0f;
      out[8 * NSAMP + 1] = slm / 8.0f;
      out[8 * NSAMP + 2] = slp / 8.0f;
    }
  }

  // ---- phase 1: KS slice q (writes buf1[n0, n0+1024)) ----
  ks_phase(b, q, P, exc, eg[0], buf1, smem, smem + 8192, smem + 8256, t);
  __syncthreads();  // drain all waves' global stores (vmcnt)

  // ---- handoff: publish own flag, wait for same-batch predecessors ----
  const int n0 = q << 10;
  int s2 = n0 - 4096 - 256;
  if (s2 < 0) s2 = 0;
  const int qlo = s2 >> 10;
  if (t == 0) {
    __hip_atomic_store(&flags[blk], FLAG_MAGIC, __ATOMIC_RELEASE,
                       __HIP_MEMORY_SCOPE_AGENT);
    for (int f = qlo; f < q; ++f) {
      while (__hip_atomic_load(&flags[b * 32 + f], __ATOMIC_ACQUIRE,
                               __HIP_MEMORY_SCOPE_AGENT) != FLAG_MAGIC) {
        __builtin_amdgcn_s_sleep(8);
      }
    }
  }
  __syncthreads();

  // ---- phase 2: body slice q (LDS reused) ----
  body_phase(b, q, P, gains, buf1, out, smem, smem + 6144,
             (float(*)[8])(smem + 6152), (float(*)[8])(smem + 6184), t);
}

extern "C" void kernel_launch(void* const* d_in, const int* in_sizes, int n_in,
                              void* d_out, int out_size, void* d_ws, size_t ws_size,
                              hipStream_t stream) {
  const float* exc = (const float*)d_in[0];
  const float* pitch = (const float*)d_in[1];
  const float* w1 = (const float*)d_in[2];
  const float* b1 = (const float*)d_in[3];
  const float* w2 = (const float*)d_in[4];
  const float* b2 = (const float*)d_in[5];
  const float* eg = (const float*)d_in[6];
  const float* bg = (const float*)d_in[7];
  float* out = (float*)d_out;
  float* buf1 = (float*)d_ws;             // 8*NSAMP floats (KS output)
  int* flags = (int*)(buf1 + 8 * NSAMP);  // 256 flags (poison != MAGIC)

  hipLaunchKernelGGL(synth_all, dim3(256), dim3(256), 0, stream, exc, pitch,
                     w1, b1, w2, b2, eg, bg, buf1, flags, out);
}